// Round 5
// baseline (524.291 us; speedup 1.0000x reference)
//
#include <hip/hip_runtime.h>
#include <math.h>

#define PI_F 3.14159265358979323846f

// ---- static config ----
// B=2, HRV=32, WRV=1024, CRV=64; CB=256, HB=200, WB=200
// D=128, COUT=128, HEADS=8, POINTS=6, DH=16; M=65536, NV=40000
//
// Hard-won rules (rounds 1-8):
//  - >=8-16 waves/CU or latency kills you (grid/256 * waves_per_block).
//  - fp32: FMA per LDS-float >= 4 (LDS 32 fl/cyc vs 128 FMA/cyc per CU).
//  - LDS row stride: pick so consecutive rows land on distinct bank groups;
//    keep 16B alignment for b128 (bf16 rows padded to 40 elems = 80 B).
//  - conv is MFMA-shaped; bf16 error is attenuated ~1000x before y. Value
//    path needs ~fp32 ACCURACY, not fp32 ARITHMETIC: bf16x2 split (hi/lo,
//    3 MFMA products) keeps ~2^-17 rel error.
//  - (round 7) msda: replicate softmax/addr math 4x not 16x; float4 loads.
//  - (round 8) raw s_barrier + counted vmcnt + direct B-frags + 2x occupancy:
//    value gemm UNCHANGED at 65us, MfmaUtil 9%, all idle. Schedule is not
//    the limiter.
//  - (round 9) remaining shared element: strided 256-B-segment reads of
//    bev [k][n] at 160KB stride, effective 1.27 TB/s. -> dedicated
//    transpose kernel (coalesced both sides) + barrier-free LDS-free GEMM
//    with all-direct 16B frag loads. bvh/bvl alias h1..q1 (dead until after
//    value path); value path launches first.
//  - (round 10) round-9 bench died to a container flake (no counters, no
//    kernel error); aliasing/bounds/alignment re-audited clean -> resubmit.

typedef __attribute__((ext_vector_type(8))) short bf16x8;
typedef __attribute__((ext_vector_type(4))) float f32x4;

__device__ __forceinline__ float gelu_f(float x) {
    return 0.5f * x * (1.0f + erff(x * 0.70710678118654752440f));
}

__device__ __forceinline__ unsigned short f2bf(float x) {
    unsigned int u = __float_as_uint(x);
    u += 0x7fffu + ((u >> 16) & 1u);  // RNE
    return (unsigned short)(u >> 16);
}

__device__ __forceinline__ float bf2f(unsigned short h) {
    return __uint_as_float((unsigned int)h << 16);
}

// ---------------- fused weight prep (+ az table + bf16 conv weights) -------
// r<256 emits the value-path weight (pv_w@vp_w) pre-split into bf16 hi/lo
// AND pre-transposed to [d][k] so value_gemm_mfma loads B-frags as straight
// 16B chunks directly from L2 (no LDS staging).
__global__ void prep_weights(const float* __restrict__ pv_w, const float* __restrict__ pv_b,
                             const float* __restrict__ vp_w, const float* __restrict__ vp_b,
                             const float* __restrict__ op_w, const float* __restrict__ op_b,
                             const float* __restrict__ po_w, const float* __restrict__ po_b,
                             const float* __restrict__ pq_w, const float* __restrict__ pq_b,
                             const float* __restrict__ qs_w1, const float* __restrict__ qs_b1,
                             const float* __restrict__ qs_w2, const float* __restrict__ qs_b2,
                             const float* __restrict__ so_w, const float* __restrict__ so_b,
                             const float* __restrict__ aw_w, const float* __restrict__ aw_b,
                             const float* __restrict__ rh_w2,
                             unsigned short* __restrict__ wvh, unsigned short* __restrict__ wvl,
                             float* __restrict__ pvvp_b,
                             float* __restrict__ oppo_w, float* __restrict__ oppo_b,
                             float* __restrict__ pqqs_w, float* __restrict__ pqqs_b,
                             float* __restrict__ qsso_w, float* __restrict__ qsso_b,
                             float* __restrict__ qsaw_w, float* __restrict__ qsaw_b,
                             unsigned short* __restrict__ wtb,
                             float2* __restrict__ azsc) {
    int r = blockIdx.x;
    int d = threadIdx.x; // 0..127
    if (r < 256) {
        float s = 0.f;
        for (int k = 0; k < 128; ++k) s += pv_w[r * 128 + k] * vp_w[k * 128 + d];
        unsigned short h = f2bf(s);
        wvh[d * 256 + r] = h;
        wvl[d * 256 + r] = f2bf(s - bf2f(h));
    } else if (r == 256) {
        float s = vp_b[d];
        for (int k = 0; k < 128; ++k) s += pv_b[k] * vp_w[k * 128 + d];
        pvvp_b[d] = s;
    } else if (r < 385) {
        int rr = r - 257;
        float s = 0.f;
        for (int k = 0; k < 128; ++k) s += op_w[rr * 128 + k] * po_w[k * 128 + d];
        oppo_w[rr * 128 + d] = s;
    } else if (r == 385) {
        float s = po_b[d];
        for (int k = 0; k < 128; ++k) s += op_b[k] * po_w[k * 128 + d];
        oppo_b[d] = s;
    } else if (r < 450) {
        int rr = r - 386;
        float s = 0.f;
        for (int k = 0; k < 128; ++k) s += pq_w[rr * 128 + k] * qs_w1[k * 128 + d];
        pqqs_w[rr * 128 + d] = s;
    } else if (r == 450) {
        float s = qs_b1[d];
        for (int k = 0; k < 128; ++k) s += pq_b[k] * qs_w1[k * 128 + d];
        pqqs_b[d] = s;
    } else if (r < 459) {
        int w = (r - 451) * 128 + d;
        float az = -PI_F + (float)w * (6.283185307179586f / 1024.0f);
        azsc[w] = make_float2(sinf(az), cosf(az));
    } else if (r < 587) {
        int rr = r - 459;
        if (d < 96) {
            float s = 0.f;
            for (int k = 0; k < 128; ++k) s += qs_w2[rr * 128 + k] * so_w[k * 96 + d];
            qsso_w[rr * 96 + d] = s;
        }
    } else if (r == 587) {
        if (d < 96) {
            float s = so_b[d];
            for (int k = 0; k < 128; ++k) s += qs_b2[k] * so_w[k * 96 + d];
            qsso_b[d] = s;
        }
    } else if (r < 716) {
        int rr = r - 588;
        if (d < 48) {
            float s = 0.f;
            for (int k = 0; k < 128; ++k) s += qs_w2[rr * 128 + k] * aw_w[k * 48 + d];
            qsaw_w[rr * 48 + d] = s;
        }
    } else if (r == 716) {
        if (d < 48) {
            float s = aw_b[d];
            for (int k = 0; k < 128; ++k) s += qs_b2[k] * aw_w[k * 48 + d];
            qsaw_b[d] = s;
        }
    } else {
        // conv weights -> bf16, transposed: wtb[tap][cc4][o][ci]
        int idx = (r - 717) * 128 + d;   // 0 .. 73727
        int ci = idx & 31;
        int o = (idx >> 5) & 63;
        int cc4i = (idx >> 11) & 3;
        int tap = idx >> 13;
        float w = rh_w2[((size_t)tap * 128 + cc4i * 32 + ci) * 64 + o];
        wtb[idx] = f2bf(w);
    }
}

// ---------------- bev transpose + bf16 hi/lo split (round 9) ----------------
// bev[b][k][n] fp32 -> bvh/bvl[b][n][k] bf16. Tile 32k x 256n, 256 threads.
// Reads: 1KB contiguous per wave-instr (full k-row segments). LDS pitch 257
// (fp32): stage-in writes conflict-free, column reads 2-way (free). Writes:
// 64B-contiguous full sectors per row.
__global__ __launch_bounds__(256) void bev_transpose(
    const float* __restrict__ bev,
    unsigned short* __restrict__ bvh, unsigned short* __restrict__ bvl) {
    __shared__ float T[32 * 257];
    const int t = threadIdx.x;
    const int wave = t >> 6, lane = t & 63;
    const int n0 = blockIdx.x * 256;
    const int k0 = blockIdx.y * 32;
    const int b = blockIdx.z;
    const float* src = bev + (size_t)b * 256 * 40000;
#pragma unroll
    for (int i = 0; i < 8; ++i) {
        int kk = i * 4 + wave;
        int nl = n0 + lane * 4;
        if (nl > 39996) nl = 39996;   // edge tile clamp (stores guarded)
        float4 v = *(const float4*)(src + (size_t)(k0 + kk) * 40000 + nl);
        *(float4*)&T[kk * 257 + lane * 4] = v;
    }
    __syncthreads();
    const int kp = t & 3;        // k-octet piece (8 k each)
    const int nr0 = t >> 2;      // n-row within pass (0..63)
#pragma unroll
    for (int p = 0; p < 4; ++p) {
        int nrow = p * 64 + nr0;
        int n = n0 + nrow;
        float f[8];
#pragma unroll
        for (int j = 0; j < 8; ++j) f[j] = T[(kp * 8 + j) * 257 + nrow];
        unsigned hh[4], ll[4];
#pragma unroll
        for (int q = 0; q < 4; ++q) {
            unsigned u0 = __float_as_uint(f[2 * q]), u1 = __float_as_uint(f[2 * q + 1]);
            hh[q] = __builtin_amdgcn_perm(u1, u0, 0x07060302);  // trunc-bf16 pair
            float l0 = f[2 * q] - __uint_as_float(u0 & 0xffff0000u);
            float l1 = f[2 * q + 1] - __uint_as_float(u1 & 0xffff0000u);
            asm("v_cvt_pk_bf16_f32 %0, %1, %2" : "=v"(ll[q]) : "v"(l0), "v"(l1));
        }
        if (n < 40000) {
            size_t o = ((size_t)b * 40000 + n) * 256 + k0 + kp * 8;
            *(uint4*)(bvh + o) = make_uint4(hh[0], hh[1], hh[2], hh[3]);
            *(uint4*)(bvl + o) = make_uint4(ll[0], ll[1], ll[2], ll[3]);
        }
    }
}

// ---------------- MT=128 GEMM, 8x8 micro, 2*NT threads ----------------
template <int NT, bool STATS>
__global__ __launch_bounds__(2 * NT) void gemm_v3(
    const float* __restrict__ A, int lda,
    const float* __restrict__ W,
    const float* __restrict__ bias,
    float* __restrict__ C, int K,
    const float2* __restrict__ azsc,
    const float* __restrict__ extra2,
    const float* __restrict__ extra_w,
    int emode, int do_gelu, float* __restrict__ stats1) {
    constexpr int NTH = 2 * NT;
    constexpr int NTO = NT / 8;
    __shared__ float As[32][140];   // 140 % 32 = 12 -> conflict-free scatter
    __shared__ float Ws[32][NT];
    __shared__ float sred[8][2];
    const int tid = threadIdx.x;
    const int tn = tid % NTO;
    const int tm = tid / NTO;   // 0..15
    const int m0 = blockIdx.x * 128;
    if (STATS && tid < 16) sred[tid >> 1][tid & 1] = 0.f;
    float acc[8][8];
#pragma unroll
    for (int i = 0; i < 8; ++i)
#pragma unroll
        for (int j = 0; j < 8; ++j) acc[i][j] = 0.f;

    for (int k0 = 0; k0 < K; k0 += 32) {
        __syncthreads();
        for (int f = tid; f < 1024; f += NTH) {
            int r = f >> 3, c4 = f & 7;
            float4 v = *(const float4*)(A + (size_t)(m0 + r) * lda + k0 + c4 * 4);
            As[c4 * 4 + 0][r] = v.x;
            As[c4 * 4 + 1][r] = v.y;
            As[c4 * 4 + 2][r] = v.z;
            As[c4 * 4 + 3][r] = v.w;
        }
        for (int f = tid; f < 8 * NT; f += NTH) {
            int kk = f / (NT / 4), n4 = f % (NT / 4);
            *(float4*)&Ws[kk][n4 * 4] = *(const float4*)(W + (size_t)(k0 + kk) * NT + n4 * 4);
        }
        __syncthreads();
#pragma unroll 2
        for (int k = 0; k < 32; ++k) {
            const float4 a0 = *(const float4*)&As[k][tm * 8];
            const float4 a1 = *(const float4*)&As[k][tm * 8 + 4];
            const float4 w0 = *(const float4*)&Ws[k][tn * 8];
            const float4 w1 = *(const float4*)&Ws[k][tn * 8 + 4];
            const float av[8] = {a0.x, a0.y, a0.z, a0.w, a1.x, a1.y, a1.z, a1.w};
            const float wv[8] = {w0.x, w0.y, w0.z, w0.w, w1.x, w1.y, w1.z, w1.w};
#pragma unroll
            for (int i = 0; i < 8; ++i)
#pragma unroll
                for (int j = 0; j < 8; ++j) acc[i][j] += av[i] * wv[j];
        }
    }
    float bv[8], e0w[8], e1w[8];
#pragma unroll
    for (int j = 0; j < 8; ++j) bv[j] = bias[tn * 8 + j];
    if (emode) {
#pragma unroll
        for (int j = 0; j < 8; ++j) {
            e0w[j] = extra_w[tn * 8 + j];
            e1w[j] = extra_w[NT + tn * 8 + j];
        }
    }
    float ts = 0.f, ts2 = 0.f;
#pragma unroll
    for (int i = 0; i < 8; ++i) {
        int m = m0 + tm * 8 + i;
        float e0 = 0.f, e1 = 0.f;
        if (emode == 1) {
            float2 sc = azsc[m & 1023];
            e0 = sc.x; e1 = sc.y;
        } else if (emode == 2) {
            e0 = extra2[2 * (size_t)m];
            e1 = extra2[2 * (size_t)m + 1];
        }
        float o[8];
#pragma unroll
        for (int j = 0; j < 8; ++j) {
            float v = acc[i][j] + bv[j];
            if (emode) v += e0 * e0w[j] + e1 * e1w[j];
            if (do_gelu) v = gelu_f(v);
            if (STATS) { ts += v; ts2 += v * v; }
            o[j] = v;
        }
        *(float4*)(C + (size_t)m * NT + tn * 8) = make_float4(o[0], o[1], o[2], o[3]);
        *(float4*)(C + (size_t)m * NT + tn * 8 + 4) = make_float4(o[4], o[5], o[6], o[7]);
    }
    if (STATS) {  // C=128, CPG=16: thread's 8 cols lie in group tn>>1
        atomicAdd(&sred[tn >> 1][0], ts);
        atomicAdd(&sred[tn >> 1][1], ts2);
        __syncthreads();
        if (tid < 8) {
            int b = m0 >> 15;
            atomicAdd(&stats1[(b * 8 + tid) * 2 + 0], sred[tid][0]);
            atomicAdd(&stats1[(b * 8 + tid) * 2 + 1], sred[tid][1]);
        }
    }
}

// ---------------- small-NT GEMM (8x4 micro) for attw ----------------
template <int MT, int NT, int NTH>
__global__ __launch_bounds__(NTH) void gemm_rn(
    const float* __restrict__ A, int lda,
    const float* __restrict__ W, int ldw,
    const float* __restrict__ bias,
    float* __restrict__ C, int ldc, int K) {
    static_assert(NTH == (MT / 8) * (NT / 4), "thread count mismatch");
    __shared__ float As[32][MT + 12];
    __shared__ float Ws[32][NT];
    constexpr int NTN = NT / 4;
    const int tid = threadIdx.x;
    const int tn = tid % NTN;
    const int tm = tid / NTN;
    const int m0 = blockIdx.x * MT;
    float acc[8][4];
#pragma unroll
    for (int i = 0; i < 8; ++i)
#pragma unroll
        for (int j = 0; j < 4; ++j) acc[i][j] = 0.f;

    for (int k0 = 0; k0 < K; k0 += 32) {
        __syncthreads();
        for (int f = tid; f < MT * 8; f += NTH) {
            int r = f >> 3, c4 = f & 7;
            float4 v = *(const float4*)(A + (size_t)(m0 + r) * lda + k0 + c4 * 4);
            As[c4 * 4 + 0][r] = v.x;
            As[c4 * 4 + 1][r] = v.y;
            As[c4 * 4 + 2][r] = v.z;
            As[c4 * 4 + 3][r] = v.w;
        }
        for (int f = tid; f < 8 * NT; f += NTH) {
            int kk = f / NTN, n4 = f % NTN;
            *(float4*)&Ws[kk][n4 * 4] = *(const float4*)(W + (size_t)(k0 + kk) * ldw + n4 * 4);
        }
        __syncthreads();
#pragma unroll 4
        for (int k = 0; k < 32; ++k) {
            const float4 a0 = *(const float4*)&As[k][tm * 8];
            const float4 a1 = *(const float4*)&As[k][tm * 8 + 4];
            const float4 wv = *(const float4*)&Ws[k][tn * 4];
            acc[0][0] += a0.x * wv.x; acc[0][1] += a0.x * wv.y; acc[0][2] += a0.x * wv.z; acc[0][3] += a0.x * wv.w;
            acc[1][0] += a0.y * wv.x; acc[1][1] += a0.y * wv.y; acc[1][2] += a0.y * wv.z; acc[1][3] += a0.y * wv.w;
            acc[2][0] += a0.z * wv.x; acc[2][1] += a0.z * wv.y; acc[2][2] += a0.z * wv.z; acc[2][3] += a0.z * wv.w;
            acc[3][0] += a0.w * wv.x; acc[3][1] += a0.w * wv.y; acc[3][2] += a0.w * wv.z; acc[3][3] += a0.w * wv.w;
            acc[4][0] += a1.x * wv.x; acc[4][1] += a1.x * wv.y; acc[4][2] += a1.x * wv.z; acc[4][3] += a1.x * wv.w;
            acc[5][0] += a1.y * wv.x; acc[5][1] += a1.y * wv.y; acc[5][2] += a1.y * wv.z; acc[5][3] += a1.y * wv.w;
            acc[6][0] += a1.z * wv.x; acc[6][1] += a1.z * wv.y; acc[6][2] += a1.z * wv.z; acc[6][3] += a1.z * wv.w;
            acc[7][0] += a1.w * wv.x; acc[7][1] += a1.w * wv.y; acc[7][2] += a1.w * wv.z; acc[7][3] += a1.w * wv.w;
        }
    }
#pragma unroll
    for (int i = 0; i < 8; ++i) {
        int m = m0 + tm * 8 + i;
        float4 o;
        o.x = acc[i][0] + bias[tn * 4 + 0];
        o.y = acc[i][1] + bias[tn * 4 + 1];
        o.z = acc[i][2] + bias[tn * 4 + 2];
        o.w = acc[i][3] + bias[tn * 4 + 3];
        *(float4*)(C + (size_t)m * ldc + tn * 4) = o;
    }
}

// ---------------- value GEMM: LDS-free, barrier-free (round 9) ----------------
// V[b][n][d] = sum_k bevT[b][n][k] * W[k][d] + bias[d], K=256.
// A = bvh/bvl [n][256] bf16 (from bev_transpose), B = wvh/wvl [d][256].
// Every fragment is ONE 16-B contiguous per-lane load; 2-deep register
// pipeline (static names, no runtime indexing); compiler emits counted
// vmcnt. Tile 64n x 128d, 4 waves 2x2, grid 625x2 (exact).
__global__ __launch_bounds__(256) void value_gemm_mfma(
    const unsigned short* __restrict__ Ah, const unsigned short* __restrict__ Al,
    const unsigned short* __restrict__ Wh, const unsigned short* __restrict__ Wl,
    const float* __restrict__ bf, float* __restrict__ V) {
    const int tid = threadIdx.x;
    const int wid = tid >> 6;
    const int lane = tid & 63;
    const int m = lane & 15;
    const int quad = lane >> 4;
    const int n0 = blockIdx.x * 64;
    const int b = blockIdx.y;
    const int wr = (wid >> 1) * 32;   // wave row block (n): 0 or 32
    const int wc = (wid & 1) * 64;    // wave col block (d): 0 or 64
    f32x4 acc[2][4];
#pragma unroll
    for (int i = 0; i < 2; ++i)
#pragma unroll
        for (int j = 0; j < 4; ++j) acc[i][j] = (f32x4){0.f, 0.f, 0.f, 0.f};

    size_t aoff[2], boff[4];
#pragma unroll
    for (int i = 0; i < 2; ++i)
        aoff[i] = ((size_t)b * 40000 + n0 + wr + i * 16 + m) * 256 + quad * 8;
#pragma unroll
    for (int j = 0; j < 4; ++j)
        boff[j] = (size_t)(wc + j * 16 + m) * 256 + quad * 8;

    bf16x8 a0h[2], a0l[2], b0h[4], b0l[4];
    bf16x8 a1h[2], a1l[2], b1h[4], b1l[4];

#define LOADSET(AH, AL, BH, BL, K0)                              \
    {                                                            \
        _Pragma("unroll")                                        \
        for (int i_ = 0; i_ < 2; ++i_) {                         \
            AH[i_] = *(const bf16x8*)(Ah + aoff[i_] + (K0));     \
            AL[i_] = *(const bf16x8*)(Al + aoff[i_] + (K0));     \
        }                                                        \
        _Pragma("unroll")                                        \
        for (int j_ = 0; j_ < 4; ++j_) {                         \
            BH[j_] = *(const bf16x8*)(Wh + boff[j_] + (K0));     \
            BL[j_] = *(const bf16x8*)(Wl + boff[j_] + (K0));     \
        }                                                        \
    }
#define MFMASET(AH, AL, BH, BL)                                                              \
    {                                                                                        \
        _Pragma("unroll")                                                                    \
        for (int i_ = 0; i_ < 2; ++i_)                                                       \
        _Pragma("unroll")                                                                    \
        for (int j_ = 0; j_ < 4; ++j_) {                                                     \
            acc[i_][j_] = __builtin_amdgcn_mfma_f32_16x16x32_bf16(AH[i_], BH[j_], acc[i_][j_], 0, 0, 0); \
            acc[i_][j_] = __builtin_amdgcn_mfma_f32_16x16x32_bf16(AH[i_], BL[j_], acc[i_][j_], 0, 0, 0); \
            acc[i_][j_] = __builtin_amdgcn_mfma_f32_16x16x32_bf16(AL[i_], BH[j_], acc[i_][j_], 0, 0, 0); \
        }                                                                                    \
    }

    LOADSET(a0h, a0l, b0h, b0l, 0);
    LOADSET(a1h, a1l, b1h, b1l, 32);
#pragma unroll
    for (int tt = 0; tt < 4; ++tt) {
        MFMASET(a0h, a0l, b0h, b0l);
        if (tt < 3) LOADSET(a0h, a0l, b0h, b0l, tt * 64 + 64);
        MFMASET(a1h, a1l, b1h, b1l);
        if (tt < 3) LOADSET(a1h, a1l, b1h, b1l, tt * 64 + 96);
    }
#undef LOADSET
#undef MFMASET
    // epilogue: D row = quad*4 + r (n), col = m (d); add fused bias
    float bv[4];
#pragma unroll
    for (int j = 0; j < 4; ++j) bv[j] = bf[wc + j * 16 + m];
#pragma unroll
    for (int i = 0; i < 2; ++i) {
        int nbase = n0 + wr + i * 16 + quad * 4;
#pragma unroll
        for (int r = 0; r < 4; ++r) {
            int n = nbase + r;
            float* vp = V + ((size_t)b * 40000 + n) * 128 + wc + m;
#pragma unroll
            for (int j = 0; j < 4; ++j) vp[j * 16] = acc[i][j][r] + bv[j];
        }
    }
}

// ---------------- GN1 apply + GELU -> bf16 ----------------
__global__ __launch_bounds__(256) void gn1_bf16(
    const float* __restrict__ X, const float* __restrict__ stats,
    const float* __restrict__ g1, const float* __restrict__ be1,
    unsigned short* __restrict__ Ob) {
    size_t i4 = (size_t)blockIdx.x * 256 + threadIdx.x;
    size_t base = i4 * 4;
    int c = (int)(base & 127);
    int mrow = (int)(base >> 7);
    int b = mrow >> 15;
    int g = c >> 4;
    float mean = stats[(b * 8 + g) * 2 + 0] * (1.0f / 524288.0f);
    float var = stats[(b * 8 + g) * 2 + 1] * (1.0f / 524288.0f) - mean * mean;
    float rs = 1.0f / sqrtf(var + 1e-5f);
    float4 x = *(const float4*)(X + base);
    float4 gm = *(const float4*)(g1 + c);
    float4 bt = *(const float4*)(be1 + c);
    ushort4 o;
    o.x = f2bf(gelu_f((x.x - mean) * rs * gm.x + bt.x));
    o.y = f2bf(gelu_f((x.y - mean) * rs * gm.y + bt.y));
    o.z = f2bf(gelu_f((x.z - mean) * rs * gm.z + bt.z));
    o.w = f2bf(gelu_f((x.w - mean) * rs * gm.w + bt.w));
    *(ushort4*)(Ob + base) = o;
}

// ---------------- 3x3 circular conv via bf16 MFMA ----------------
__global__ __launch_bounds__(256, 4) void conv3x3_mfma(
    const unsigned short* __restrict__ H1b,  // [2][32][1024][128] bf16
    const unsigned short* __restrict__ Wtb,  // [9][4][64][32] bf16
    float* __restrict__ Y,                   // [2][32][1024][64]
    float* __restrict__ stats2) {
    __shared__ short As_s[66 * 40];      // [xx][ci_chunk] 5.2 KB
    __shared__ short Ws_s[3 * 64 * 40];  // [dx][o][ci_chunk] 15.4 KB
    __shared__ float sred[8][2];
    const int tid = threadIdx.x;
    const int wid = tid >> 6;
    const int lane = tid & 63;
    const int m = lane & 15;
    const int quad = lane >> 4;
    const int x0 = blockIdx.x * 64;
    const int y = blockIdx.y;
    const int b = blockIdx.z;
    if (tid < 16) sred[tid >> 1][tid & 1] = 0.f;
    f32x4 acc[4];
#pragma unroll
    for (int oq = 0; oq < 4; ++oq) acc[oq] = (f32x4){0.f, 0.f, 0.f, 0.f};

    const unsigned short* Hb = H1b + (size_t)b * 32 * 1024 * 128;
    for (int ry = 0; ry < 3; ++ry) {
        const int gy = (y + ry + 31) & 31;
        const unsigned short* Hrow = Hb + (size_t)gy * 1024 * 128;
        for (int cc4 = 0; cc4 < 4; ++cc4) {
            __syncthreads();
            // A: 66 xx-rows x 4 octets of 8 bf16 = 264 16B chunks
            for (int f = tid; f < 264; f += 256) {
                int xx = f >> 2, cq = f & 3;
                int gx = (x0 + xx + 1023) & 1023;
                uint4 v = *(const uint4*)(Hrow + (size_t)gx * 128 + cc4 * 32 + cq * 8);
                *(uint4*)&As_s[xx * 40 + cq * 8] = v;
            }
            // W: 3 dx x 64 o x 4 octets = 768 16B chunks
            for (int f = tid; f < 768; f += 256) {
                int cq = f & 3, o = (f >> 2) & 63, dx = f >> 8;
                int tap = ry * 3 + dx;
                uint4 v = *(const uint4*)(Wtb + ((size_t)(tap * 4 + cc4) * 64 + o) * 32 + cq * 8);
                *(uint4*)&Ws_s[(dx * 64 + o) * 40 + cq * 8] = v;
            }
            __syncthreads();
            const int arow = wid * 16 + m;
#pragma unroll
            for (int dx = 0; dx < 3; ++dx) {
                bf16x8 a = *(const bf16x8*)&As_s[(arow + dx) * 40 + quad * 8];
#pragma unroll
                for (int oq = 0; oq < 4; ++oq) {
                    bf16x8 bfr = *(const bf16x8*)&Ws_s[(dx * 64 + oq * 16 + m) * 40 + quad * 8];
                    acc[oq] = __builtin_amdgcn_mfma_f32_16x16x32_bf16(a, bfr, acc[oq], 0, 0, 0);
                }
            }
        }
    }
    // GN2 stats: lane's frag oq covers o = oq*16 + m -> group oq*2 + (m>>3)
    float sv[4], qv[4];
#pragma unroll
    for (int oq = 0; oq < 4; ++oq) {
        sv[oq] = acc[oq].x + acc[oq].y + acc[oq].z + acc[oq].w;
        qv[oq] = acc[oq].x * acc[oq].x + acc[oq].y * acc[oq].y +
                 acc[oq].z * acc[oq].z + acc[oq].w * acc[oq].w;
    }
    const int masks[5] = {1, 2, 4, 16, 32};  // reduce over all but bit3
#pragma unroll
    for (int mi = 0; mi < 5; ++mi) {
#pragma unroll
        for (int oq = 0; oq < 4; ++oq) {
            sv[oq] += __shfl_xor(sv[oq], masks[mi]);
            qv[oq] += __shfl_xor(qv[oq], masks[mi]);
        }
    }
    if ((lane & 55) == 0) {  // lanes 0, 8
        int gb = (lane >> 3) & 1;
#pragma unroll
        for (int oq = 0; oq < 4; ++oq) {
            atomicAdd(&sred[oq * 2 + gb][0], sv[oq]);
            atomicAdd(&sred[oq * 2 + gb][1], qv[oq]);
        }
    }
    // store: D row = quad*4 + r (px), col = o
    const int pxb = x0 + wid * 16 + quad * 4;
    float* Yb = Y + ((size_t)(b * 32 + y) * 1024 + pxb) * 64;
#pragma unroll
    for (int oq = 0; oq < 4; ++oq) {
        const float av[4] = {acc[oq].x, acc[oq].y, acc[oq].z, acc[oq].w};
#pragma unroll
        for (int r = 0; r < 4; ++r) Yb[(size_t)r * 64 + oq * 16 + m] = av[r];
    }
    __syncthreads();
    if (tid < 16)
        atomicAdd(&stats2[(b * 8 + (tid >> 1)) * 2 + (tid & 1)], sred[tid >> 1][tid & 1]);
}

// ---------------- fused GN2-apply + GELU + rh3 head ----------------
__global__ __launch_bounds__(256) void rh3_kernel(
    const float* __restrict__ H2, const float* __restrict__ stats,
    const float* __restrict__ gamma, const float* __restrict__ beta, float inv_cnt,
    const float* __restrict__ w3, const float* __restrict__ b3,
    const float2* __restrict__ azsc,
    float2* __restrict__ refxy, float2* __restrict__ sigf) {
    const int tid = threadIdx.x;
    const int lane = tid & 15;
    const int m = blockIdx.x * 16 + (tid >> 4);
    const int b = m >> 15;
    const int c = lane * 4;
    const int g = c >> 3;
    float mean = stats[(b * 8 + g) * 2 + 0] * inv_cnt;
    float var = stats[(b * 8 + g) * 2 + 1] * inv_cnt - mean * mean;
    float rs = 1.0f / sqrtf(var + 1e-5f);
    float4 v = *(const float4*)(H2 + (size_t)m * 64 + c);
    float hv[4];
    hv[0] = gelu_f((v.x - mean) * rs * gamma[c + 0] + beta[c + 0]);
    hv[1] = gelu_f((v.y - mean) * rs * gamma[c + 1] + beta[c + 1]);
    hv[2] = gelu_f((v.z - mean) * rs * gamma[c + 2] + beta[c + 2]);
    hv[3] = gelu_f((v.w - mean) * rs * gamma[c + 3] + beta[c + 3]);
    float d0 = 0.f, d1 = 0.f;
#pragma unroll
    for (int k = 0; k < 4; ++k) {
        d0 += hv[k] * w3[(c + k) * 2 + 0];
        d1 += hv[k] * w3[(c + k) * 2 + 1];
    }
#pragma unroll
    for (int s = 1; s < 16; s <<= 1) {
        d0 += __shfl_xor(d0, s, 16);
        d1 += __shfl_xor(d1, s, 16);
    }
    if (lane == 0) {
        float mu = fminf(fmaxf(d0 + b3[0], 0.f), 55.f);
        float ls = fminf(fmaxf(d1 + b3[1], -5.f), 3.f);
        float sg = expf(ls);
        float2 sc = azsc[m & 1023];
        float rx = fminf(fmaxf(mu * sc.y * 0.01f + 0.5f, 0.f), 1.f);
        float ry = fminf(fmaxf(mu * sc.x * 0.01f + 0.5f, 0.f), 1.f);
        refxy[m] = make_float2(rx, ry);
        sigf[m] = make_float2(ls, 1.f / (sg + 1e-6f));
    }
}

// ---------------- MSDA bilinear sampling ----------------
__global__ __launch_bounds__(256) void msda_kernel(
    const float* __restrict__ V, const float2* __restrict__ refxy,
    const float* __restrict__ offs, const float* __restrict__ aw,
    float* __restrict__ out) {
    const int tid = threadIdx.x;
    const int l4 = tid & 3;         // dh quarter
    const int grp = tid >> 2;       // 0..63: 8 m x 8 heads
    const int m = blockIdx.x * 8 + (grp >> 3);
    const int head = grp & 7;
    const int b = m >> 15;
    float2 r = refxy[m];
    const float* lg = aw + (size_t)m * 48 + head * 6;
    float l[6];
#pragma unroll
    for (int p = 0; p < 6; ++p) l[p] = lg[p];
    float mx = l[0];
#pragma unroll
    for (int p = 1; p < 6; ++p) mx = fmaxf(mx, l[p]);
    float s = 0.f;
#pragma unroll
    for (int p = 0; p < 6; ++p) { l[p] = expf(l[p] - mx); s += l[p]; }
    float inv = 1.f / s;
#pragma unroll
    for (int p = 0; p < 6; ++p) l[p] *= inv;   // fold softmax into weights
    const float* of = offs + (size_t)m * 96 + head * 12;
    const float* Vb = V + (size_t)b * 40000 * 128 + head * 16 + l4 * 4;
    const float bx = r.x * 200.f - 0.5f;
    const float by = r.y * 200.f - 0.5f;
    f32x4 acc = (f32x4){0.f, 0.f, 0.f, 0.f};
#pragma unroll
    for (int p = 0; p < 6; ++p) {
        float px = bx + of[p * 2 + 0];
        float py = by + of[p * 2 + 1];
        float fx = floorf(px), fy = floorf(py);
        int x0 = (int)fx, y0 = (int)fy;
        float wx = px - fx, wy = py - fy;
        // clamped addresses (always in range); invalid corners get weight 0
        int xc0 = min(max(x0, 0), 199), xc1 = min(max(x0 + 1, 0), 199);
        int yc0 = min(max(y0, 0), 199), yc1 = min(max(y0 + 1, 0), 199);
        bool vx0 = ((unsigned)x0 < 200u), vx1 = ((unsigned)(x0 + 1) < 200u);
        bool vy0 = ((unsigned)y0 < 200u), vy1 = ((unsigned)(y0 + 1) < 200u);
        const f32x4 v00 = *(const f32x4*)(Vb + ((size_t)(yc0 * 200 + xc0)) * 128);
        const f32x4 v10 = *(const f32x4*)(Vb + ((size_t)(yc0 * 200 + xc1)) * 128);
        const f32x4 v01 = *(const f32x4*)(Vb + ((size_t)(yc1 * 200 + xc0)) * 128);
        const f32x4 v11 = *(const f32x4*)(Vb + ((size_t)(yc1 * 200 + xc1)) * 128);
        float w = l[p];
        float w00 = (vx0 && vy0) ? w * (1.f - wx) * (1.f - wy) : 0.f;
        float w10 = (vx1 && vy0) ? w * wx * (1.f - wy) : 0.f;
        float w01 = (vx0 && vy1) ? w * (1.f - wx) * wy : 0.f;
        float w11 = (vx1 && vy1) ? w * wx * wy : 0.f;
        acc += v00 * w00;
        acc += v10 * w10;
        acc += v01 * w01;
        acc += v11 * w11;
    }
    *(f32x4*)(out + (size_t)m * 128 + head * 16 + l4 * 4) = acc;
}

// ---------------- launch ----------------
extern "C" void kernel_launch(void* const* d_in, const int* in_sizes, int n_in,
                              void* d_out, int out_size, void* d_ws, size_t ws_size,
                              hipStream_t stream) {
    const float* x_rv = (const float*)d_in[0];
    const float* bev = (const float*)d_in[1];
    const float* pq_w = (const float*)d_in[2];
    const float* pq_b = (const float*)d_in[3];
    const float* pv_w = (const float*)d_in[4];
    const float* pv_b = (const float*)d_in[5];
    const float* po_w = (const float*)d_in[6];
    const float* po_b = (const float*)d_in[7];
    const float* qs_w1 = (const float*)d_in[8];
    const float* qs_b1 = (const float*)d_in[9];
    const float* qs_w2 = (const float*)d_in[10];
    const float* qs_b2 = (const float*)d_in[11];
    const float* rh_w1 = (const float*)d_in[12];
    const float* rh_b1 = (const float*)d_in[13];
    const float* rh_g1 = (const float*)d_in[14];
    const float* rh_be1 = (const float*)d_in[15];
    const float* rh_w2 = (const float*)d_in[16];
    const float* rh_g2 = (const float*)d_in[17];
    const float* rh_be2 = (const float*)d_in[18];
    const float* rh_w3 = (const float*)d_in[19];
    const float* rh_b3 = (const float*)d_in[20];
    const float* so_w = (const float*)d_in[21];
    const float* so_b = (const float*)d_in[22];
    const float* aw_w = (const float*)d_in[23];
    const float* aw_b = (const float*)d_in[24];
    const float* vp_w = (const float*)d_in[25];
    const float* vp_b = (const float*)d_in[26];
    const float* op_w = (const float*)d_in[27];
    const float* op_b = (const float*)d_in[28];

    const int M = 65536;

    float* ws = (float*)d_ws;
    float* azsc = ws;    ws += 2048;
    unsigned short* wvh = (unsigned short*)ws; ws += 16384;  // 256x128 bf16-hi [d][k]
    unsigned short* wvl = (unsigned short*)ws; ws += 16384;  // 256x128 bf16-lo [d][k]
    float* pvvp_b = ws;  ws += 128;
    float* oppo_w = ws;  ws += 128 * 128;
    float* oppo_b = ws;  ws += 128;
    float* pqqs_w = ws;  ws += 64 * 128;
    float* pqqs_b = ws;  ws += 128;
    float* qsso_w = ws;  ws += 128 * 96;
    float* qsso_b = ws;  ws += 128;
    float* qsaw_w = ws;  ws += 128 * 48;
    float* qsaw_b = ws;  ws += 64;
    float* stats = ws;   ws += 64;   // [0:32) GN1, [32:64) GN2
    unsigned short* wtb = (unsigned short*)ws;  ws += 36864;   // 73728 bf16
    unsigned short* h1b = (unsigned short*)ws;  ws += (size_t)M * 64;  // M*128 bf16
    float* Vv = ws;      ws += (size_t)80000 * 128;
    float* h1 = ws;      ws += (size_t)M * 128;
    float* h2 = ws;      ws += (size_t)M * 64;
    float* q1 = ws;      ws += (size_t)M * 128;
    float* refxy = ws;   ws += (size_t)M * 2;
    float* sigf = ws;    ws += (size_t)M * 2;
    size_t need_bytes = (size_t)(ws - (float*)d_ws) * sizeof(float);
    if (ws_size < need_bytes) return;
    float* offs = h1;   // h1 (raw rh1) dead after gn1_bf16
    float* attw = h2;   // h2 dead after rh3
    float* mo = q1;     // q1 dead after offs/attw GEMMs
    // bvh/bvl (2x40000x256 bf16 = 10.24M floats each) alias [h1, h1+20.48M),
    // i.e. h1+h2+part of q1 (20.97M contiguous). Dead before rh1 writes h1:
    // the value path (transpose + value_gemm) launches FIRST.
    unsigned short* bvh = (unsigned short*)h1;
    unsigned short* bvl = (unsigned short*)(h1 + 10240000);

    float2* azsc2 = (float2*)azsc;
    float2* refxy2 = (float2*)refxy;
    float2* sigf2 = (float2*)sigf;

    prep_weights<<<1293, 128, 0, stream>>>(
        pv_w, pv_b, vp_w, vp_b, op_w, op_b, po_w, po_b, pq_w, pq_b,
        qs_w1, qs_b1, qs_w2, qs_b2, so_w, so_b, aw_w, aw_b, rh_w2,
        wvh, wvl, pvvp_b, oppo_w, oppo_b, pqqs_w, pqqs_b,
        qsso_w, qsso_b, qsaw_w, qsaw_b, wtb, azsc2);
    hipMemsetAsync(stats, 0, 64 * sizeof(float), stream);

    // bev [k][n] -> bvh/bvl [n][k] bf16 hi/lo (coalesced both sides)
    bev_transpose<<<dim3(157, 8, 2), 256, 0, stream>>>(bev, bvh, bvl);

    // value = bevT @ (pv_w@vp_w) + fused bias, bf16x2-split MFMA (no LDS)
    value_gemm_mfma<<<dim3(625, 2), 256, 0, stream>>>(bvh, bvl, wvh, wvl, pvvp_b, Vv);

    // h1 = raw rh1 (x_rv(+az) @ rh_w1 + b); fused GN1 stats  (clobbers bvh)
    gemm_v3<128, true><<<M / 128, 256, 0, stream>>>(
        x_rv, 64, rh_w1, rh_b1, h1, 64, azsc2, nullptr, rh_w1 + 64 * 128, 1, 0, stats);

    // GN1 apply + gelu -> bf16
    gn1_bf16<<<8192, 256, 0, stream>>>(h1, stats, rh_g1, rh_be1, h1b);

    // conv via bf16 MFMA; GN2 stats in epilogue
    conv3x3_mfma<<<dim3(16, 32, 2), 256, 0, stream>>>(h1b, wtb, h2, stats + 32);

    // fused GN2-apply + gelu + rh3 head
    rh3_kernel<<<4096, 256, 0, stream>>>(h2, stats + 32, rh_g2, rh_be2, 1.0f / 262144.0f,
                                         rh_w3, rh_b3, azsc2, refxy2, sigf2);

    // q1 = gelu(x_rv @ (pq_w@qs_w1a) + sigf extras + fused bias) (clobbers bvl)
    gemm_v3<128, false><<<M / 128, 256, 0, stream>>>(
        x_rv, 64, pqqs_w, pqqs_b, q1, 64, nullptr, sigf, qs_w1 + 128 * 128, 2, 1, nullptr);

    // offs = q1 @ (qs_w2@so_w) + folded bias
    gemm_v3<96, false><<<M / 128, 192, 0, stream>>>(
        q1, 128, qsso_w, qsso_b, offs, 128, nullptr, nullptr, nullptr, 0, 0, nullptr);

    // attw logits = q1 @ (qs_w2@aw_w) + folded bias
    gemm_rn<128, 48, 192><<<M / 128, 192, 0, stream>>>(
        q1, 128, qsaw_w, 48, qsaw_b, attw, 48, 128);

    // MSDA sampling (into q1)
    msda_kernel<<<M / 8, 256, 0, stream>>>(Vv, refxy2, offs, attw, mo);

    // y = mo @ (op_w@po_w) + fused bias -> d_out
    gemm_v3<128, false><<<M / 128, 256, 0, stream>>>(
        mo, 128, oppo_w, oppo_b, (float*)d_out, 128, nullptr, nullptr, nullptr, 0, 0, nullptr);
}

// Round 6
// 488.726 us; speedup vs baseline: 1.0728x; 1.0728x over previous
//
#include <hip/hip_runtime.h>
#include <math.h>

#define PI_F 3.14159265358979323846f

// ---- static config ----
// B=2, HRV=32, WRV=1024, CRV=64; CB=256, HB=200, WB=200
// D=128, COUT=128, HEADS=8, POINTS=6, DH=16; M=65536, NV=40000
//
// Hard-won rules (rounds 1-11):
//  - >=8-16 waves/CU or latency kills you (grid/256 * waves_per_block).
//  - conv is MFMA-shaped; value path needs ~fp32 ACCURACY, not fp32
//    ARITHMETIC: bf16x2 split (hi/lo, 3 MFMA products) ~2^-17 rel error.
//  - (round 7) msda: replicate softmax/addr math 4x not 16x; float4 loads.
//  - (rounds 8-10) value gemm pinned at 63-67us across 3 structurally
//    different schedules (LDS+syncthreads / raw-barrier counted-vmcnt /
//    LDS-free barrier-free). Schedule & input streaming are NOT the limiter.
//  - (round 11) the real limiter: per-lane 16B frag loads at 512B lane
//    stride = 64 sectors/wave-instr, 16B used of each 64B sector -> ~31TB/s
//    L2 sector traffic ~ the 34.5TB/s ceiling. FIX: fragment-major layout
//    [tile16][kchunk][lane][8] so a frag load is base+lane*16B = one
//    contiguous 1KB wave transaction (16 fully-used sectors).

typedef __attribute__((ext_vector_type(8))) short bf16x8;
typedef __attribute__((ext_vector_type(4))) float f32x4;

__device__ __forceinline__ float gelu_f(float x) {
    return 0.5f * x * (1.0f + erff(x * 0.70710678118654752440f));
}

__device__ __forceinline__ unsigned short f2bf(float x) {
    unsigned int u = __float_as_uint(x);
    u += 0x7fffu + ((u >> 16) & 1u);  // RNE
    return (unsigned short)(u >> 16);
}

__device__ __forceinline__ float bf2f(unsigned short h) {
    return __uint_as_float((unsigned int)h << 16);
}

// ---------------- fused weight prep (+ az table + bf16 conv weights) -------
// r<256 emits the value-path weight (pv_w@vp_w) split bf16 hi/lo in
// FRAGMENT-MAJOR order: wv[dt(8)][kc(8)][lane(64)][j(8)], where
// d = dt*16 + (lane&15), k = kc*32 + (lane>>4)*8 + j. A B-fragment load in
// value_gemm_mfma is then base + lane*16B (coalesced 1KB).
__global__ void prep_weights(const float* __restrict__ pv_w, const float* __restrict__ pv_b,
                             const float* __restrict__ vp_w, const float* __restrict__ vp_b,
                             const float* __restrict__ op_w, const float* __restrict__ op_b,
                             const float* __restrict__ po_w, const float* __restrict__ po_b,
                             const float* __restrict__ pq_w, const float* __restrict__ pq_b,
                             const float* __restrict__ qs_w1, const float* __restrict__ qs_b1,
                             const float* __restrict__ qs_w2, const float* __restrict__ qs_b2,
                             const float* __restrict__ so_w, const float* __restrict__ so_b,
                             const float* __restrict__ aw_w, const float* __restrict__ aw_b,
                             const float* __restrict__ rh_w2,
                             unsigned short* __restrict__ wvh, unsigned short* __restrict__ wvl,
                             float* __restrict__ pvvp_b,
                             float* __restrict__ oppo_w, float* __restrict__ oppo_b,
                             float* __restrict__ pqqs_w, float* __restrict__ pqqs_b,
                             float* __restrict__ qsso_w, float* __restrict__ qsso_b,
                             float* __restrict__ qsaw_w, float* __restrict__ qsaw_b,
                             unsigned short* __restrict__ wtb,
                             float2* __restrict__ azsc) {
    int r = blockIdx.x;
    int d = threadIdx.x; // 0..127
    if (r < 256) {
        // r = k index, d = output channel
        float s = 0.f;
        for (int k = 0; k < 128; ++k) s += pv_w[r * 128 + k] * vp_w[k * 128 + d];
        unsigned short h = f2bf(s);
        int dt = d >> 4, mm = d & 15;
        int kc = r >> 5, qd = (r >> 3) & 3, jj = r & 7;
        size_t off = (((size_t)(dt * 8 + kc) * 64) + qd * 16 + mm) * 8 + jj;
        wvh[off] = h;
        wvl[off] = f2bf(s - bf2f(h));
    } else if (r == 256) {
        float s = vp_b[d];
        for (int k = 0; k < 128; ++k) s += pv_b[k] * vp_w[k * 128 + d];
        pvvp_b[d] = s;
    } else if (r < 385) {
        int rr = r - 257;
        float s = 0.f;
        for (int k = 0; k < 128; ++k) s += op_w[rr * 128 + k] * po_w[k * 128 + d];
        oppo_w[rr * 128 + d] = s;
    } else if (r == 385) {
        float s = po_b[d];
        for (int k = 0; k < 128; ++k) s += op_b[k] * po_w[k * 128 + d];
        oppo_b[d] = s;
    } else if (r < 450) {
        int rr = r - 386;
        float s = 0.f;
        for (int k = 0; k < 128; ++k) s += pq_w[rr * 128 + k] * qs_w1[k * 128 + d];
        pqqs_w[rr * 128 + d] = s;
    } else if (r == 450) {
        float s = qs_b1[d];
        for (int k = 0; k < 128; ++k) s += pq_b[k] * qs_w1[k * 128 + d];
        pqqs_b[d] = s;
    } else if (r < 459) {
        int w = (r - 451) * 128 + d;
        float az = -PI_F + (float)w * (6.283185307179586f / 1024.0f);
        azsc[w] = make_float2(sinf(az), cosf(az));
    } else if (r < 587) {
        int rr = r - 459;
        if (d < 96) {
            float s = 0.f;
            for (int k = 0; k < 128; ++k) s += qs_w2[rr * 128 + k] * so_w[k * 96 + d];
            qsso_w[rr * 96 + d] = s;
        }
    } else if (r == 587) {
        if (d < 96) {
            float s = so_b[d];
            for (int k = 0; k < 128; ++k) s += qs_b2[k] * so_w[k * 96 + d];
            qsso_b[d] = s;
        }
    } else if (r < 716) {
        int rr = r - 588;
        if (d < 48) {
            float s = 0.f;
            for (int k = 0; k < 128; ++k) s += qs_w2[rr * 128 + k] * aw_w[k * 48 + d];
            qsaw_w[rr * 48 + d] = s;
        }
    } else if (r == 716) {
        if (d < 48) {
            float s = aw_b[d];
            for (int k = 0; k < 128; ++k) s += qs_b2[k] * aw_w[k * 48 + d];
            qsaw_b[d] = s;
        }
    } else {
        // conv weights -> bf16, transposed: wtb[tap][cc4][o][ci]
        int idx = (r - 717) * 128 + d;   // 0 .. 73727
        int ci = idx & 31;
        int o = (idx >> 5) & 63;
        int cc4i = (idx >> 11) & 3;
        int tap = idx >> 13;
        float w = rh_w2[((size_t)tap * 128 + cc4i * 32 + ci) * 64 + o];
        wtb[idx] = f2bf(w);
    }
}

// ---------------- bev transpose + bf16 hi/lo split (round 11) ---------------
// bev[b][k][n] fp32 -> bvh/bvl in FRAGMENT-MAJOR order:
// bv[b][nt(2500)][kc(8)][lane(64)][j(8)], n = nt*16 + (lane&15),
// k = kc*32 + (lane>>4)*8 + j. Tile 32k x 256n, 256 threads.
// Reads 1KB contiguous per wave-instr; LDS pitch 257 conflict-light;
// writes per wave land in one contiguous 1KB fragment region.
__global__ __launch_bounds__(256) void bev_transpose(
    const float* __restrict__ bev,
    unsigned short* __restrict__ bvh, unsigned short* __restrict__ bvl) {
    __shared__ float T[32 * 257];
    const int t = threadIdx.x;
    const int wave = t >> 6, lane = t & 63;
    const int n0 = blockIdx.x * 256;
    const int kcY = blockIdx.y;          // k-chunk of 32
    const int k0 = kcY * 32;
    const int b = blockIdx.z;
    const float* src = bev + (size_t)b * 256 * 40000;
#pragma unroll
    for (int i = 0; i < 8; ++i) {
        int kk = i * 4 + wave;
        int nl = n0 + lane * 4;
        if (nl > 39996) nl = 39996;   // edge tile clamp (stores guarded)
        float4 v = *(const float4*)(src + (size_t)(k0 + kk) * 40000 + nl);
        *(float4*)&T[kk * 257 + lane * 4] = v;
    }
    __syncthreads();
    const int kp = t & 3;        // k-octet piece (quad), 8 k each
    const int nr0 = t >> 2;      // n-row within pass (0..63)
#pragma unroll
    for (int p = 0; p < 4; ++p) {
        int nrow = p * 64 + nr0;
        int n = n0 + nrow;
        float f[8];
#pragma unroll
        for (int j = 0; j < 8; ++j) f[j] = T[(kp * 8 + j) * 257 + nrow];
        unsigned hh[4], ll[4];
#pragma unroll
        for (int q = 0; q < 4; ++q) {
            unsigned u0 = __float_as_uint(f[2 * q]), u1 = __float_as_uint(f[2 * q + 1]);
            hh[q] = __builtin_amdgcn_perm(u1, u0, 0x07060302);  // trunc-bf16 pair
            float l0 = f[2 * q] - __uint_as_float(u0 & 0xffff0000u);
            float l1 = f[2 * q + 1] - __uint_as_float(u1 & 0xffff0000u);
            asm("v_cvt_pk_bf16_f32 %0, %1, %2" : "=v"(ll[q]) : "v"(l0), "v"(l1));
        }
        if (n < 40000) {
            size_t o = ((((size_t)b * 2500 + (n >> 4)) * 8 + kcY) * 64 + kp * 16 + (n & 15)) * 8;
            *(uint4*)(bvh + o) = make_uint4(hh[0], hh[1], hh[2], hh[3]);
            *(uint4*)(bvl + o) = make_uint4(ll[0], ll[1], ll[2], ll[3]);
        }
    }
}

// ---------------- MT=128 GEMM, 8x8 micro, 2*NT threads ----------------
template <int NT, bool STATS>
__global__ __launch_bounds__(2 * NT) void gemm_v3(
    const float* __restrict__ A, int lda,
    const float* __restrict__ W,
    const float* __restrict__ bias,
    float* __restrict__ C, int K,
    const float2* __restrict__ azsc,
    const float* __restrict__ extra2,
    const float* __restrict__ extra_w,
    int emode, int do_gelu, float* __restrict__ stats1) {
    constexpr int NTH = 2 * NT;
    constexpr int NTO = NT / 8;
    __shared__ float As[32][140];   // 140 % 32 = 12 -> conflict-free scatter
    __shared__ float Ws[32][NT];
    __shared__ float sred[8][2];
    const int tid = threadIdx.x;
    const int tn = tid % NTO;
    const int tm = tid / NTO;   // 0..15
    const int m0 = blockIdx.x * 128;
    if (STATS && tid < 16) sred[tid >> 1][tid & 1] = 0.f;
    float acc[8][8];
#pragma unroll
    for (int i = 0; i < 8; ++i)
#pragma unroll
        for (int j = 0; j < 8; ++j) acc[i][j] = 0.f;

    for (int k0 = 0; k0 < K; k0 += 32) {
        __syncthreads();
        for (int f = tid; f < 1024; f += NTH) {
            int r = f >> 3, c4 = f & 7;
            float4 v = *(const float4*)(A + (size_t)(m0 + r) * lda + k0 + c4 * 4);
            As[c4 * 4 + 0][r] = v.x;
            As[c4 * 4 + 1][r] = v.y;
            As[c4 * 4 + 2][r] = v.z;
            As[c4 * 4 + 3][r] = v.w;
        }
        for (int f = tid; f < 8 * NT; f += NTH) {
            int kk = f / (NT / 4), n4 = f % (NT / 4);
            *(float4*)&Ws[kk][n4 * 4] = *(const float4*)(W + (size_t)(k0 + kk) * NT + n4 * 4);
        }
        __syncthreads();
#pragma unroll 2
        for (int k = 0; k < 32; ++k) {
            const float4 a0 = *(const float4*)&As[k][tm * 8];
            const float4 a1 = *(const float4*)&As[k][tm * 8 + 4];
            const float4 w0 = *(const float4*)&Ws[k][tn * 8];
            const float4 w1 = *(const float4*)&Ws[k][tn * 8 + 4];
            const float av[8] = {a0.x, a0.y, a0.z, a0.w, a1.x, a1.y, a1.z, a1.w};
            const float wv[8] = {w0.x, w0.y, w0.z, w0.w, w1.x, w1.y, w1.z, w1.w};
#pragma unroll
            for (int i = 0; i < 8; ++i)
#pragma unroll
                for (int j = 0; j < 8; ++j) acc[i][j] += av[i] * wv[j];
        }
    }
    float bv[8], e0w[8], e1w[8];
#pragma unroll
    for (int j = 0; j < 8; ++j) bv[j] = bias[tn * 8 + j];
    if (emode) {
#pragma unroll
        for (int j = 0; j < 8; ++j) {
            e0w[j] = extra_w[tn * 8 + j];
            e1w[j] = extra_w[NT + tn * 8 + j];
        }
    }
    float ts = 0.f, ts2 = 0.f;
#pragma unroll
    for (int i = 0; i < 8; ++i) {
        int m = m0 + tm * 8 + i;
        float e0 = 0.f, e1 = 0.f;
        if (emode == 1) {
            float2 sc = azsc[m & 1023];
            e0 = sc.x; e1 = sc.y;
        } else if (emode == 2) {
            e0 = extra2[2 * (size_t)m];
            e1 = extra2[2 * (size_t)m + 1];
        }
        float o[8];
#pragma unroll
        for (int j = 0; j < 8; ++j) {
            float v = acc[i][j] + bv[j];
            if (emode) v += e0 * e0w[j] + e1 * e1w[j];
            if (do_gelu) v = gelu_f(v);
            if (STATS) { ts += v; ts2 += v * v; }
            o[j] = v;
        }
        *(float4*)(C + (size_t)m * NT + tn * 8) = make_float4(o[0], o[1], o[2], o[3]);
        *(float4*)(C + (size_t)m * NT + tn * 8 + 4) = make_float4(o[4], o[5], o[6], o[7]);
    }
    if (STATS) {  // C=128, CPG=16: thread's 8 cols lie in group tn>>1
        atomicAdd(&sred[tn >> 1][0], ts);
        atomicAdd(&sred[tn >> 1][1], ts2);
        __syncthreads();
        if (tid < 8) {
            int b = m0 >> 15;
            atomicAdd(&stats1[(b * 8 + tid) * 2 + 0], sred[tid][0]);
            atomicAdd(&stats1[(b * 8 + tid) * 2 + 1], sred[tid][1]);
        }
    }
}

// ---------------- small-NT GEMM (8x4 micro) for attw ----------------
template <int MT, int NT, int NTH>
__global__ __launch_bounds__(NTH) void gemm_rn(
    const float* __restrict__ A, int lda,
    const float* __restrict__ W, int ldw,
    const float* __restrict__ bias,
    float* __restrict__ C, int ldc, int K) {
    static_assert(NTH == (MT / 8) * (NT / 4), "thread count mismatch");
    __shared__ float As[32][MT + 12];
    __shared__ float Ws[32][NT];
    constexpr int NTN = NT / 4;
    const int tid = threadIdx.x;
    const int tn = tid % NTN;
    const int tm = tid / NTN;
    const int m0 = blockIdx.x * MT;
    float acc[8][4];
#pragma unroll
    for (int i = 0; i < 8; ++i)
#pragma unroll
        for (int j = 0; j < 4; ++j) acc[i][j] = 0.f;

    for (int k0 = 0; k0 < K; k0 += 32) {
        __syncthreads();
        for (int f = tid; f < MT * 8; f += NTH) {
            int r = f >> 3, c4 = f & 7;
            float4 v = *(const float4*)(A + (size_t)(m0 + r) * lda + k0 + c4 * 4);
            As[c4 * 4 + 0][r] = v.x;
            As[c4 * 4 + 1][r] = v.y;
            As[c4 * 4 + 2][r] = v.z;
            As[c4 * 4 + 3][r] = v.w;
        }
        for (int f = tid; f < 8 * NT; f += NTH) {
            int kk = f / NTN, n4 = f % NTN;
            *(float4*)&Ws[kk][n4 * 4] = *(const float4*)(W + (size_t)(k0 + kk) * ldw + n4 * 4);
        }
        __syncthreads();
#pragma unroll 4
        for (int k = 0; k < 32; ++k) {
            const float4 a0 = *(const float4*)&As[k][tm * 8];
            const float4 a1 = *(const float4*)&As[k][tm * 8 + 4];
            const float4 wv = *(const float4*)&Ws[k][tn * 4];
            acc[0][0] += a0.x * wv.x; acc[0][1] += a0.x * wv.y; acc[0][2] += a0.x * wv.z; acc[0][3] += a0.x * wv.w;
            acc[1][0] += a0.y * wv.x; acc[1][1] += a0.y * wv.y; acc[1][2] += a0.y * wv.z; acc[1][3] += a0.y * wv.w;
            acc[2][0] += a0.z * wv.x; acc[2][1] += a0.z * wv.y; acc[2][2] += a0.z * wv.z; acc[2][3] += a0.z * wv.w;
            acc[3][0] += a0.w * wv.x; acc[3][1] += a0.w * wv.y; acc[3][2] += a0.w * wv.z; acc[3][3] += a0.w * wv.w;
            acc[4][0] += a1.x * wv.x; acc[4][1] += a1.x * wv.y; acc[4][2] += a1.x * wv.z; acc[4][3] += a1.x * wv.w;
            acc[5][0] += a1.y * wv.x; acc[5][1] += a1.y * wv.y; acc[5][2] += a1.y * wv.z; acc[5][3] += a1.y * wv.w;
            acc[6][0] += a1.z * wv.x; acc[6][1] += a1.z * wv.y; acc[6][2] += a1.z * wv.z; acc[6][3] += a1.z * wv.w;
            acc[7][0] += a1.w * wv.x; acc[7][1] += a1.w * wv.y; acc[7][2] += a1.w * wv.z; acc[7][3] += a1.w * wv.w;
        }
    }
#pragma unroll
    for (int i = 0; i < 8; ++i) {
        int m = m0 + tm * 8 + i;
        float4 o;
        o.x = acc[i][0] + bias[tn * 4 + 0];
        o.y = acc[i][1] + bias[tn * 4 + 1];
        o.z = acc[i][2] + bias[tn * 4 + 2];
        o.w = acc[i][3] + bias[tn * 4 + 3];
        *(float4*)(C + (size_t)m * ldc + tn * 4) = o;
    }
}

// ---------------- value GEMM: LDS-free, coalesced frags (round 11) ----------
// V[b][n][d] = sum_k bevT[b][n][k] * W[k][d] + bias[d], K=256.
// A = bvh/bvl, B = wvh/wvl -- both FRAGMENT-MAJOR [tile16][kc][lane][8].
// Every fragment load = base + lane*16B: one contiguous 1KB wave-instr,
// 16 fully-used sectors (was 64 quarter-used -> L2-transaction-bound).
// 2-deep register pipeline; tile 64n x 128d, 4 waves 2x2, grid 625x2.
__global__ __launch_bounds__(256) void value_gemm_mfma(
    const unsigned short* __restrict__ Ah, const unsigned short* __restrict__ Al,
    const unsigned short* __restrict__ Wh, const unsigned short* __restrict__ Wl,
    const float* __restrict__ bf, float* __restrict__ V) {
    const int tid = threadIdx.x;
    const int wid = tid >> 6;
    const int lane = tid & 63;
    const int m = lane & 15;
    const int quad = lane >> 4;
    const int n0 = blockIdx.x * 64;
    const int b = blockIdx.y;
    const int wr = (wid >> 1) * 32;   // wave row block (n): 0 or 32
    const int wc = (wid & 1) * 64;    // wave col block (d): 0 or 64
    f32x4 acc[2][4];
#pragma unroll
    for (int i = 0; i < 2; ++i)
#pragma unroll
        for (int j = 0; j < 4; ++j) acc[i][j] = (f32x4){0.f, 0.f, 0.f, 0.f};

    const int ntb = b * 2500 + ((n0 + wr) >> 4);   // A tile base (16-row tiles)
    const int dt0 = wc >> 4;                       // B tile base
    size_t abase[2], bbase[4];
#pragma unroll
    for (int i = 0; i < 2; ++i) abase[i] = (size_t)(ntb + i) * 4096 + lane * 8;
#pragma unroll
    for (int j = 0; j < 4; ++j) bbase[j] = (size_t)(dt0 + j) * 4096 + lane * 8;

    bf16x8 a0h[2], a0l[2], b0h[4], b0l[4];
    bf16x8 a1h[2], a1l[2], b1h[4], b1l[4];

#define LOADSET(AH, AL, BH, BL, T)                                   \
    {                                                                \
        _Pragma("unroll")                                            \
        for (int i_ = 0; i_ < 2; ++i_) {                             \
            AH[i_] = *(const bf16x8*)(Ah + abase[i_] + (T) * 512);   \
            AL[i_] = *(const bf16x8*)(Al + abase[i_] + (T) * 512);   \
        }                                                            \
        _Pragma("unroll")                                            \
        for (int j_ = 0; j_ < 4; ++j_) {                             \
            BH[j_] = *(const bf16x8*)(Wh + bbase[j_] + (T) * 512);   \
            BL[j_] = *(const bf16x8*)(Wl + bbase[j_] + (T) * 512);   \
        }                                                            \
    }
#define MFMASET(AH, AL, BH, BL)                                                              \
    {                                                                                        \
        _Pragma("unroll")                                                                    \
        for (int i_ = 0; i_ < 2; ++i_)                                                       \
        _Pragma("unroll")                                                                    \
        for (int j_ = 0; j_ < 4; ++j_) {                                                     \
            acc[i_][j_] = __builtin_amdgcn_mfma_f32_16x16x32_bf16(AH[i_], BH[j_], acc[i_][j_], 0, 0, 0); \
            acc[i_][j_] = __builtin_amdgcn_mfma_f32_16x16x32_bf16(AH[i_], BL[j_], acc[i_][j_], 0, 0, 0); \
            acc[i_][j_] = __builtin_amdgcn_mfma_f32_16x16x32_bf16(AL[i_], BH[j_], acc[i_][j_], 0, 0, 0); \
        }                                                                                    \
    }

    LOADSET(a0h, a0l, b0h, b0l, 0);
    LOADSET(a1h, a1l, b1h, b1l, 1);
#pragma unroll
    for (int tt = 0; tt < 4; ++tt) {
        MFMASET(a0h, a0l, b0h, b0l);
        if (tt < 3) LOADSET(a0h, a0l, b0h, b0l, 2 * tt + 2);
        MFMASET(a1h, a1l, b1h, b1l);
        if (tt < 3) LOADSET(a1h, a1l, b1h, b1l, 2 * tt + 3);
    }
#undef LOADSET
#undef MFMASET
    // epilogue: D row = quad*4 + r (n), col = m (d); add fused bias
    float bv[4];
#pragma unroll
    for (int j = 0; j < 4; ++j) bv[j] = bf[wc + j * 16 + m];
#pragma unroll
    for (int i = 0; i < 2; ++i) {
        int nbase = n0 + wr + i * 16 + quad * 4;
#pragma unroll
        for (int r = 0; r < 4; ++r) {
            int n = nbase + r;
            float* vp = V + ((size_t)b * 40000 + n) * 128 + wc + m;
#pragma unroll
            for (int j = 0; j < 4; ++j) vp[j * 16] = acc[i][j][r] + bv[j];
        }
    }
}

// ---------------- GN1 apply + GELU -> bf16 ----------------
__global__ __launch_bounds__(256) void gn1_bf16(
    const float* __restrict__ X, const float* __restrict__ stats,
    const float* __restrict__ g1, const float* __restrict__ be1,
    unsigned short* __restrict__ Ob) {
    size_t i4 = (size_t)blockIdx.x * 256 + threadIdx.x;
    size_t base = i4 * 4;
    int c = (int)(base & 127);
    int mrow = (int)(base >> 7);
    int b = mrow >> 15;
    int g = c >> 4;
    float mean = stats[(b * 8 + g) * 2 + 0] * (1.0f / 524288.0f);
    float var = stats[(b * 8 + g) * 2 + 1] * (1.0f / 524288.0f) - mean * mean;
    float rs = 1.0f / sqrtf(var + 1e-5f);
    float4 x = *(const float4*)(X + base);
    float4 gm = *(const float4*)(g1 + c);
    float4 bt = *(const float4*)(be1 + c);
    ushort4 o;
    o.x = f2bf(gelu_f((x.x - mean) * rs * gm.x + bt.x));
    o.y = f2bf(gelu_f((x.y - mean) * rs * gm.y + bt.y));
    o.z = f2bf(gelu_f((x.z - mean) * rs * gm.z + bt.z));
    o.w = f2bf(gelu_f((x.w - mean) * rs * gm.w + bt.w));
    *(ushort4*)(Ob + base) = o;
}

// ---------------- 3x3 circular conv via bf16 MFMA ----------------
__global__ __launch_bounds__(256, 4) void conv3x3_mfma(
    const unsigned short* __restrict__ H1b,  // [2][32][1024][128] bf16
    const unsigned short* __restrict__ Wtb,  // [9][4][64][32] bf16
    float* __restrict__ Y,                   // [2][32][1024][64]
    float* __restrict__ stats2) {
    __shared__ short As_s[66 * 40];      // [xx][ci_chunk] 5.2 KB
    __shared__ short Ws_s[3 * 64 * 40];  // [dx][o][ci_chunk] 15.4 KB
    __shared__ float sred[8][2];
    const int tid = threadIdx.x;
    const int wid = tid >> 6;
    const int lane = tid & 63;
    const int m = lane & 15;
    const int quad = lane >> 4;
    const int x0 = blockIdx.x * 64;
    const int y = blockIdx.y;
    const int b = blockIdx.z;
    if (tid < 16) sred[tid >> 1][tid & 1] = 0.f;
    f32x4 acc[4];
#pragma unroll
    for (int oq = 0; oq < 4; ++oq) acc[oq] = (f32x4){0.f, 0.f, 0.f, 0.f};

    const unsigned short* Hb = H1b + (size_t)b * 32 * 1024 * 128;
    for (int ry = 0; ry < 3; ++ry) {
        const int gy = (y + ry + 31) & 31;
        const unsigned short* Hrow = Hb + (size_t)gy * 1024 * 128;
        for (int cc4 = 0; cc4 < 4; ++cc4) {
            __syncthreads();
            // A: 66 xx-rows x 4 octets of 8 bf16 = 264 16B chunks
            for (int f = tid; f < 264; f += 256) {
                int xx = f >> 2, cq = f & 3;
                int gx = (x0 + xx + 1023) & 1023;
                uint4 v = *(const uint4*)(Hrow + (size_t)gx * 128 + cc4 * 32 + cq * 8);
                *(uint4*)&As_s[xx * 40 + cq * 8] = v;
            }
            // W: 3 dx x 64 o x 4 octets = 768 16B chunks
            for (int f = tid; f < 768; f += 256) {
                int cq = f & 3, o = (f >> 2) & 63, dx = f >> 8;
                int tap = ry * 3 + dx;
                uint4 v = *(const uint4*)(Wtb + ((size_t)(tap * 4 + cc4) * 64 + o) * 32 + cq * 8);
                *(uint4*)&Ws_s[(dx * 64 + o) * 40 + cq * 8] = v;
            }
            __syncthreads();
            const int arow = wid * 16 + m;
#pragma unroll
            for (int dx = 0; dx < 3; ++dx) {
                bf16x8 a = *(const bf16x8*)&As_s[(arow + dx) * 40 + quad * 8];
#pragma unroll
                for (int oq = 0; oq < 4; ++oq) {
                    bf16x8 bfr = *(const bf16x8*)&Ws_s[(dx * 64 + oq * 16 + m) * 40 + quad * 8];
                    acc[oq] = __builtin_amdgcn_mfma_f32_16x16x32_bf16(a, bfr, acc[oq], 0, 0, 0);
                }
            }
        }
    }
    // GN2 stats: lane's frag oq covers o = oq*16 + m -> group oq*2 + (m>>3)
    float sv[4], qv[4];
#pragma unroll
    for (int oq = 0; oq < 4; ++oq) {
        sv[oq] = acc[oq].x + acc[oq].y + acc[oq].z + acc[oq].w;
        qv[oq] = acc[oq].x * acc[oq].x + acc[oq].y * acc[oq].y +
                 acc[oq].z * acc[oq].z + acc[oq].w * acc[oq].w;
    }
    const int masks[5] = {1, 2, 4, 16, 32};  // reduce over all but bit3
#pragma unroll
    for (int mi = 0; mi < 5; ++mi) {
#pragma unroll
        for (int oq = 0; oq < 4; ++oq) {
            sv[oq] += __shfl_xor(sv[oq], masks[mi]);
            qv[oq] += __shfl_xor(qv[oq], masks[mi]);
        }
    }
    if ((lane & 55) == 0) {  // lanes 0, 8
        int gb = (lane >> 3) & 1;
#pragma unroll
        for (int oq = 0; oq < 4; ++oq) {
            atomicAdd(&sred[oq * 2 + gb][0], sv[oq]);
            atomicAdd(&sred[oq * 2 + gb][1], qv[oq]);
        }
    }
    // store: D row = quad*4 + r (px), col = o
    const int pxb = x0 + wid * 16 + quad * 4;
    float* Yb = Y + ((size_t)(b * 32 + y) * 1024 + pxb) * 64;
#pragma unroll
    for (int oq = 0; oq < 4; ++oq) {
        const float av[4] = {acc[oq].x, acc[oq].y, acc[oq].z, acc[oq].w};
#pragma unroll
        for (int r = 0; r < 4; ++r) Yb[(size_t)r * 64 + oq * 16 + m] = av[r];
    }
    __syncthreads();
    if (tid < 16)
        atomicAdd(&stats2[(b * 8 + (tid >> 1)) * 2 + (tid & 1)], sred[tid >> 1][tid & 1]);
}

// ---------------- fused GN2-apply + GELU + rh3 head ----------------
__global__ __launch_bounds__(256) void rh3_kernel(
    const float* __restrict__ H2, const float* __restrict__ stats,
    const float* __restrict__ gamma, const float* __restrict__ beta, float inv_cnt,
    const float* __restrict__ w3, const float* __restrict__ b3,
    const float2* __restrict__ azsc,
    float2* __restrict__ refxy, float2* __restrict__ sigf) {
    const int tid = threadIdx.x;
    const int lane = tid & 15;
    const int m = blockIdx.x * 16 + (tid >> 4);
    const int b = m >> 15;
    const int c = lane * 4;
    const int g = c >> 3;
    float mean = stats[(b * 8 + g) * 2 + 0] * inv_cnt;
    float var = stats[(b * 8 + g) * 2 + 1] * inv_cnt - mean * mean;
    float rs = 1.0f / sqrtf(var + 1e-5f);
    float4 v = *(const float4*)(H2 + (size_t)m * 64 + c);
    float hv[4];
    hv[0] = gelu_f((v.x - mean) * rs * gamma[c + 0] + beta[c + 0]);
    hv[1] = gelu_f((v.y - mean) * rs * gamma[c + 1] + beta[c + 1]);
    hv[2] = gelu_f((v.z - mean) * rs * gamma[c + 2] + beta[c + 2]);
    hv[3] = gelu_f((v.w - mean) * rs * gamma[c + 3] + beta[c + 3]);
    float d0 = 0.f, d1 = 0.f;
#pragma unroll
    for (int k = 0; k < 4; ++k) {
        d0 += hv[k] * w3[(c + k) * 2 + 0];
        d1 += hv[k] * w3[(c + k) * 2 + 1];
    }
#pragma unroll
    for (int s = 1; s < 16; s <<= 1) {
        d0 += __shfl_xor(d0, s, 16);
        d1 += __shfl_xor(d1, s, 16);
    }
    if (lane == 0) {
        float mu = fminf(fmaxf(d0 + b3[0], 0.f), 55.f);
        float ls = fminf(fmaxf(d1 + b3[1], -5.f), 3.f);
        float sg = expf(ls);
        float2 sc = azsc[m & 1023];
        float rx = fminf(fmaxf(mu * sc.y * 0.01f + 0.5f, 0.f), 1.f);
        float ry = fminf(fmaxf(mu * sc.x * 0.01f + 0.5f, 0.f), 1.f);
        refxy[m] = make_float2(rx, ry);
        sigf[m] = make_float2(ls, 1.f / (sg + 1e-6f));
    }
}

// ---------------- MSDA bilinear sampling ----------------
__global__ __launch_bounds__(256) void msda_kernel(
    const float* __restrict__ V, const float2* __restrict__ refxy,
    const float* __restrict__ offs, const float* __restrict__ aw,
    float* __restrict__ out) {
    const int tid = threadIdx.x;
    const int l4 = tid & 3;         // dh quarter
    const int grp = tid >> 2;       // 0..63: 8 m x 8 heads
    const int m = blockIdx.x * 8 + (grp >> 3);
    const int head = grp & 7;
    const int b = m >> 15;
    float2 r = refxy[m];
    const float* lg = aw + (size_t)m * 48 + head * 6;
    float l[6];
#pragma unroll
    for (int p = 0; p < 6; ++p) l[p] = lg[p];
    float mx = l[0];
#pragma unroll
    for (int p = 1; p < 6; ++p) mx = fmaxf(mx, l[p]);
    float s = 0.f;
#pragma unroll
    for (int p = 0; p < 6; ++p) { l[p] = expf(l[p] - mx); s += l[p]; }
    float inv = 1.f / s;
#pragma unroll
    for (int p = 0; p < 6; ++p) l[p] *= inv;   // fold softmax into weights
    const float* of = offs + (size_t)m * 96 + head * 12;
    const float* Vb = V + (size_t)b * 40000 * 128 + head * 16 + l4 * 4;
    const float bx = r.x * 200.f - 0.5f;
    const float by = r.y * 200.f - 0.5f;
    f32x4 acc = (f32x4){0.f, 0.f, 0.f, 0.f};
#pragma unroll
    for (int p = 0; p < 6; ++p) {
        float px = bx + of[p * 2 + 0];
        float py = by + of[p * 2 + 1];
        float fx = floorf(px), fy = floorf(py);
        int x0 = (int)fx, y0 = (int)fy;
        float wx = px - fx, wy = py - fy;
        // clamped addresses (always in range); invalid corners get weight 0
        int xc0 = min(max(x0, 0), 199), xc1 = min(max(x0 + 1, 0), 199);
        int yc0 = min(max(y0, 0), 199), yc1 = min(max(y0 + 1, 0), 199);
        bool vx0 = ((unsigned)x0 < 200u), vx1 = ((unsigned)(x0 + 1) < 200u);
        bool vy0 = ((unsigned)y0 < 200u), vy1 = ((unsigned)(y0 + 1) < 200u);
        const f32x4 v00 = *(const f32x4*)(Vb + ((size_t)(yc0 * 200 + xc0)) * 128);
        const f32x4 v10 = *(const f32x4*)(Vb + ((size_t)(yc0 * 200 + xc1)) * 128);
        const f32x4 v01 = *(const f32x4*)(Vb + ((size_t)(yc1 * 200 + xc0)) * 128);
        const f32x4 v11 = *(const f32x4*)(Vb + ((size_t)(yc1 * 200 + xc1)) * 128);
        float w = l[p];
        float w00 = (vx0 && vy0) ? w * (1.f - wx) * (1.f - wy) : 0.f;
        float w10 = (vx1 && vy0) ? w * wx * (1.f - wy) : 0.f;
        float w01 = (vx0 && vy1) ? w * (1.f - wx) * wy : 0.f;
        float w11 = (vx1 && vy1) ? w * wx * wy : 0.f;
        acc += v00 * w00;
        acc += v10 * w10;
        acc += v01 * w01;
        acc += v11 * w11;
    }
    *(f32x4*)(out + (size_t)m * 128 + head * 16 + l4 * 4) = acc;
}

// ---------------- launch ----------------
extern "C" void kernel_launch(void* const* d_in, const int* in_sizes, int n_in,
                              void* d_out, int out_size, void* d_ws, size_t ws_size,
                              hipStream_t stream) {
    const float* x_rv = (const float*)d_in[0];
    const float* bev = (const float*)d_in[1];
    const float* pq_w = (const float*)d_in[2];
    const float* pq_b = (const float*)d_in[3];
    const float* pv_w = (const float*)d_in[4];
    const float* pv_b = (const float*)d_in[5];
    const float* po_w = (const float*)d_in[6];
    const float* po_b = (const float*)d_in[7];
    const float* qs_w1 = (const float*)d_in[8];
    const float* qs_b1 = (const float*)d_in[9];
    const float* qs_w2 = (const float*)d_in[10];
    const float* qs_b2 = (const float*)d_in[11];
    const float* rh_w1 = (const float*)d_in[12];
    const float* rh_b1 = (const float*)d_in[13];
    const float* rh_g1 = (const float*)d_in[14];
    const float* rh_be1 = (const float*)d_in[15];
    const float* rh_w2 = (const float*)d_in[16];
    const float* rh_g2 = (const float*)d_in[17];
    const float* rh_be2 = (const float*)d_in[18];
    const float* rh_w3 = (const float*)d_in[19];
    const float* rh_b3 = (const float*)d_in[20];
    const float* so_w = (const float*)d_in[21];
    const float* so_b = (const float*)d_in[22];
    const float* aw_w = (const float*)d_in[23];
    const float* aw_b = (const float*)d_in[24];
    const float* vp_w = (const float*)d_in[25];
    const float* vp_b = (const float*)d_in[26];
    const float* op_w = (const float*)d_in[27];
    const float* op_b = (const float*)d_in[28];

    const int M = 65536;

    float* ws = (float*)d_ws;
    float* azsc = ws;    ws += 2048;
    unsigned short* wvh = (unsigned short*)ws; ws += 16384;  // 8x8x64x8 bf16-hi frag-major
    unsigned short* wvl = (unsigned short*)ws; ws += 16384;  // 8x8x64x8 bf16-lo frag-major
    float* pvvp_b = ws;  ws += 128;
    float* oppo_w = ws;  ws += 128 * 128;
    float* oppo_b = ws;  ws += 128;
    float* pqqs_w = ws;  ws += 64 * 128;
    float* pqqs_b = ws;  ws += 128;
    float* qsso_w = ws;  ws += 128 * 96;
    float* qsso_b = ws;  ws += 128;
    float* qsaw_w = ws;  ws += 128 * 48;
    float* qsaw_b = ws;  ws += 64;
    float* stats = ws;   ws += 64;   // [0:32) GN1, [32:64) GN2
    unsigned short* wtb = (unsigned short*)ws;  ws += 36864;   // 73728 bf16
    unsigned short* h1b = (unsigned short*)ws;  ws += (size_t)M * 64;  // M*128 bf16
    float* Vv = ws;      ws += (size_t)80000 * 128;
    float* h1 = ws;      ws += (size_t)M * 128;
    float* h2 = ws;      ws += (size_t)M * 64;
    float* q1 = ws;      ws += (size_t)M * 128;
    float* refxy = ws;   ws += (size_t)M * 2;
    float* sigf = ws;    ws += (size_t)M * 2;
    size_t need_bytes = (size_t)(ws - (float*)d_ws) * sizeof(float);
    if (ws_size < need_bytes) return;
    float* offs = h1;   // h1 (raw rh1) dead after gn1_bf16
    float* attw = h2;   // h2 dead after rh3
    float* mo = q1;     // q1 dead after offs/attw GEMMs
    // bvh/bvl (2x2500x8x64x8 bf16 = 10.24M floats each) alias [h1, h1+20.48M)
    // (h1+h2+part of q1, 20.97M contiguous). Dead before rh1 writes h1:
    // the value path (transpose + value_gemm) launches FIRST.
    unsigned short* bvh = (unsigned short*)h1;
    unsigned short* bvl = (unsigned short*)(h1 + 10240000);

    float2* azsc2 = (float2*)azsc;
    float2* refxy2 = (float2*)refxy;
    float2* sigf2 = (float2*)sigf;

    prep_weights<<<1293, 128, 0, stream>>>(
        pv_w, pv_b, vp_w, vp_b, op_w, op_b, po_w, po_b, pq_w, pq_b,
        qs_w1, qs_b1, qs_w2, qs_b2, so_w, so_b, aw_w, aw_b, rh_w2,
        wvh, wvl, pvvp_b, oppo_w, oppo_b, pqqs_w, pqqs_b,
        qsso_w, qsso_b, qsaw_w, qsaw_b, wtb, azsc2);
    hipMemsetAsync(stats, 0, 64 * sizeof(float), stream);

    // bev [k][n] -> bvh/bvl fragment-major bf16 hi/lo (coalesced both sides)
    bev_transpose<<<dim3(157, 8, 2), 256, 0, stream>>>(bev, bvh, bvl);

    // value = bevT @ (pv_w@vp_w) + fused bias, bf16x2-split MFMA (no LDS)
    value_gemm_mfma<<<dim3(625, 2), 256, 0, stream>>>(bvh, bvl, wvh, wvl, pvvp_b, Vv);

    // h1 = raw rh1 (x_rv(+az) @ rh_w1 + b); fused GN1 stats  (clobbers bvh)
    gemm_v3<128, true><<<M / 128, 256, 0, stream>>>(
        x_rv, 64, rh_w1, rh_b1, h1, 64, azsc2, nullptr, rh_w1 + 64 * 128, 1, 0, stats);

    // GN1 apply + gelu -> bf16
    gn1_bf16<<<8192, 256, 0, stream>>>(h1, stats, rh_g1, rh_be1, h1b);

    // conv via bf16 MFMA; GN2 stats in epilogue
    conv3x3_mfma<<<dim3(16, 32, 2), 256, 0, stream>>>(h1b, wtb, h2, stats + 32);

    // fused GN2-apply + gelu + rh3 head
    rh3_kernel<<<4096, 256, 0, stream>>>(h2, stats + 32, rh_g2, rh_be2, 1.0f / 262144.0f,
                                         rh_w3, rh_b3, azsc2, refxy2, sigf2);

    // q1 = gelu(x_rv @ (pq_w@qs_w1a) + sigf extras + fused bias) (clobbers bvl)
    gemm_v3<128, false><<<M / 128, 256, 0, stream>>>(
        x_rv, 64, pqqs_w, pqqs_b, q1, 64, nullptr, sigf, qs_w1 + 128 * 128, 2, 1, nullptr);

    // offs = q1 @ (qs_w2@so_w) + folded bias
    gemm_v3<96, false><<<M / 128, 192, 0, stream>>>(
        q1, 128, qsso_w, qsso_b, offs, 128, nullptr, nullptr, nullptr, 0, 0, nullptr);

    // attw logits = q1 @ (qs_w2@aw_w) + folded bias
    gemm_rn<128, 48, 192><<<M / 128, 192, 0, stream>>>(
        q1, 128, qsaw_w, 48, qsaw_b, attw, 48, 128);

    // MSDA sampling (into q1)
    msda_kernel<<<M / 8, 256, 0, stream>>>(Vv, refxy2, offs, attw, mo);

    // y = mo @ (op_w@po_w) + fused bias -> d_out
    gemm_v3<128, false><<<M / 128, 256, 0, stream>>>(
        mo, 128, oppo_w, oppo_b, (float*)d_out, 128, nullptr, nullptr, nullptr, 0, 0, nullptr);
}

// Round 7
// 469.553 us; speedup vs baseline: 1.1166x; 1.0408x over previous
//
#include <hip/hip_runtime.h>
#include <math.h>

#define PI_F 3.14159265358979323846f

// ---- static config ----
// B=2, HRV=32, WRV=1024, CRV=64; CB=256, HB=200, WB=200
// D=128, COUT=128, HEADS=8, POINTS=6, DH=16; M=65536, NV=40000
//
// Hard-won rules (rounds 1-12):
//  - value path needs ~fp32 ACCURACY, not fp32 ARITHMETIC: bf16x2 split
//    (hi = trunc, lo = RNE residual; hh+hl+lh MFMA) ~2^-17 rel error.
//  - (round 7) msda: replicate softmax/addr math 4x not 16x; float4 loads.
//  - (rounds 8-11) value-gemm walls, each HW-verified:
//    #1 strided global reads -> 64 quarter-used sectors/wave-instr,
//       ~31TB/s L2 sector traffic at the ~34.5TB/s ceiling.
//    #2 __syncthreads drains vmcnt(0) -> kills cross-chunk prefetch; use
//       raw s_barrier + lgkmcnt(0) only.
//    #3 per-lane 16B frags at 512B lane stride = wall #1 again; fixed by
//       fragment-major weight layout (round 11, confirmed: gemm 63 -> <47us).
//  - (round 12) transpose+gemm split pays 82MB extra read+write; fuse:
//    coalesced row staging -> LDS [k][n] pitch-134 fp32 (column b32 reads
//    2-way free: (8*134)%32=16 splits quads), in-register hi/lo split,
//    double-buffered, 1 raw barrier/chunk, prefetch 2 ahead.
//  - top-5 counters now masked by harness workspace-poison fills (327MB,
//    85% HBM) -- judge by dur_us.

typedef __attribute__((ext_vector_type(8))) short bf16x8;
typedef __attribute__((ext_vector_type(4))) float f32x4;

__device__ __forceinline__ float gelu_f(float x) {
    return 0.5f * x * (1.0f + erff(x * 0.70710678118654752440f));
}

__device__ __forceinline__ unsigned short f2bf(float x) {
    unsigned int u = __float_as_uint(x);
    u += 0x7fffu + ((u >> 16) & 1u);  // RNE
    return (unsigned short)(u >> 16);
}

__device__ __forceinline__ float bf2f(unsigned short h) {
    return __uint_as_float((unsigned int)h << 16);
}

// ---------------- fused weight prep (+ az table + bf16 conv weights) -------
// r<256 emits the value-path weight (pv_w@vp_w) split bf16 hi/lo in
// FRAGMENT-MAJOR order: wv[dt(8)][kc(8)][lane(64)][j(8)], where
// d = dt*16 + (lane&15), k = kc*32 + (lane>>4)*8 + j. A B-fragment load in
// the value GEMM is then base + lane*16B (coalesced 1KB).
__global__ void prep_weights(const float* __restrict__ pv_w, const float* __restrict__ pv_b,
                             const float* __restrict__ vp_w, const float* __restrict__ vp_b,
                             const float* __restrict__ op_w, const float* __restrict__ op_b,
                             const float* __restrict__ po_w, const float* __restrict__ po_b,
                             const float* __restrict__ pq_w, const float* __restrict__ pq_b,
                             const float* __restrict__ qs_w1, const float* __restrict__ qs_b1,
                             const float* __restrict__ qs_w2, const float* __restrict__ qs_b2,
                             const float* __restrict__ so_w, const float* __restrict__ so_b,
                             const float* __restrict__ aw_w, const float* __restrict__ aw_b,
                             const float* __restrict__ rh_w2,
                             unsigned short* __restrict__ wvh, unsigned short* __restrict__ wvl,
                             float* __restrict__ pvvp_b,
                             float* __restrict__ oppo_w, float* __restrict__ oppo_b,
                             float* __restrict__ pqqs_w, float* __restrict__ pqqs_b,
                             float* __restrict__ qsso_w, float* __restrict__ qsso_b,
                             float* __restrict__ qsaw_w, float* __restrict__ qsaw_b,
                             unsigned short* __restrict__ wtb,
                             float2* __restrict__ azsc) {
    int r = blockIdx.x;
    int d = threadIdx.x; // 0..127
    if (r < 256) {
        // r = k index, d = output channel
        float s = 0.f;
        for (int k = 0; k < 128; ++k) s += pv_w[r * 128 + k] * vp_w[k * 128 + d];
        unsigned short h = f2bf(s);
        int dt = d >> 4, mm = d & 15;
        int kc = r >> 5, qd = (r >> 3) & 3, jj = r & 7;
        size_t off = (((size_t)(dt * 8 + kc) * 64) + qd * 16 + mm) * 8 + jj;
        wvh[off] = h;
        wvl[off] = f2bf(s - bf2f(h));
    } else if (r == 256) {
        float s = vp_b[d];
        for (int k = 0; k < 128; ++k) s += pv_b[k] * vp_w[k * 128 + d];
        pvvp_b[d] = s;
    } else if (r < 385) {
        int rr = r - 257;
        float s = 0.f;
        for (int k = 0; k < 128; ++k) s += op_w[rr * 128 + k] * po_w[k * 128 + d];
        oppo_w[rr * 128 + d] = s;
    } else if (r == 385) {
        float s = po_b[d];
        for (int k = 0; k < 128; ++k) s += op_b[k] * po_w[k * 128 + d];
        oppo_b[d] = s;
    } else if (r < 450) {
        int rr = r - 386;
        float s = 0.f;
        for (int k = 0; k < 128; ++k) s += pq_w[rr * 128 + k] * qs_w1[k * 128 + d];
        pqqs_w[rr * 128 + d] = s;
    } else if (r == 450) {
        float s = qs_b1[d];
        for (int k = 0; k < 128; ++k) s += pq_b[k] * qs_w1[k * 128 + d];
        pqqs_b[d] = s;
    } else if (r < 459) {
        int w = (r - 451) * 128 + d;
        float az = -PI_F + (float)w * (6.283185307179586f / 1024.0f);
        azsc[w] = make_float2(sinf(az), cosf(az));
    } else if (r < 587) {
        int rr = r - 459;
        if (d < 96) {
            float s = 0.f;
            for (int k = 0; k < 128; ++k) s += qs_w2[rr * 128 + k] * so_w[k * 96 + d];
            qsso_w[rr * 96 + d] = s;
        }
    } else if (r == 587) {
        if (d < 96) {
            float s = so_b[d];
            for (int k = 0; k < 128; ++k) s += qs_b2[k] * so_w[k * 96 + d];
            qsso_b[d] = s;
        }
    } else if (r < 716) {
        int rr = r - 588;
        if (d < 48) {
            float s = 0.f;
            for (int k = 0; k < 128; ++k) s += qs_w2[rr * 128 + k] * aw_w[k * 48 + d];
            qsaw_w[rr * 48 + d] = s;
        }
    } else if (r == 716) {
        if (d < 48) {
            float s = aw_b[d];
            for (int k = 0; k < 128; ++k) s += qs_b2[k] * aw_w[k * 48 + d];
            qsaw_b[d] = s;
        }
    } else {
        // conv weights -> bf16, transposed: wtb[tap][cc4][o][ci]
        int idx = (r - 717) * 128 + d;   // 0 .. 73727
        int ci = idx & 31;
        int o = (idx >> 5) & 63;
        int cc4i = (idx >> 11) & 3;
        int tap = idx >> 13;
        float w = rh_w2[((size_t)tap * 128 + cc4i * 32 + ci) * 64 + o];
        wtb[idx] = f2bf(w);
    }
}

// ---------------- MT=128 GEMM, 8x8 micro, 2*NT threads ----------------
template <int NT, bool STATS>
__global__ __launch_bounds__(2 * NT) void gemm_v3(
    const float* __restrict__ A, int lda,
    const float* __restrict__ W,
    const float* __restrict__ bias,
    float* __restrict__ C, int K,
    const float2* __restrict__ azsc,
    const float* __restrict__ extra2,
    const float* __restrict__ extra_w,
    int emode, int do_gelu, float* __restrict__ stats1) {
    constexpr int NTH = 2 * NT;
    constexpr int NTO = NT / 8;
    __shared__ float As[32][140];   // 140 % 32 = 12 -> conflict-free scatter
    __shared__ float Ws[32][NT];
    __shared__ float sred[8][2];
    const int tid = threadIdx.x;
    const int tn = tid % NTO;
    const int tm = tid / NTO;   // 0..15
    const int m0 = blockIdx.x * 128;
    if (STATS && tid < 16) sred[tid >> 1][tid & 1] = 0.f;
    float acc[8][8];
#pragma unroll
    for (int i = 0; i < 8; ++i)
#pragma unroll
        for (int j = 0; j < 8; ++j) acc[i][j] = 0.f;

    for (int k0 = 0; k0 < K; k0 += 32) {
        __syncthreads();
        for (int f = tid; f < 1024; f += NTH) {
            int r = f >> 3, c4 = f & 7;
            float4 v = *(const float4*)(A + (size_t)(m0 + r) * lda + k0 + c4 * 4);
            As[c4 * 4 + 0][r] = v.x;
            As[c4 * 4 + 1][r] = v.y;
            As[c4 * 4 + 2][r] = v.z;
            As[c4 * 4 + 3][r] = v.w;
        }
        for (int f = tid; f < 8 * NT; f += NTH) {
            int kk = f / (NT / 4), n4 = f % (NT / 4);
            *(float4*)&Ws[kk][n4 * 4] = *(const float4*)(W + (size_t)(k0 + kk) * NT + n4 * 4);
        }
        __syncthreads();
#pragma unroll 2
        for (int k = 0; k < 32; ++k) {
            const float4 a0 = *(const float4*)&As[k][tm * 8];
            const float4 a1 = *(const float4*)&As[k][tm * 8 + 4];
            const float4 w0 = *(const float4*)&Ws[k][tn * 8];
            const float4 w1 = *(const float4*)&Ws[k][tn * 8 + 4];
            const float av[8] = {a0.x, a0.y, a0.z, a0.w, a1.x, a1.y, a1.z, a1.w};
            const float wv[8] = {w0.x, w0.y, w0.z, w0.w, w1.x, w1.y, w1.z, w1.w};
#pragma unroll
            for (int i = 0; i < 8; ++i)
#pragma unroll
                for (int j = 0; j < 8; ++j) acc[i][j] += av[i] * wv[j];
        }
    }
    float bv[8], e0w[8], e1w[8];
#pragma unroll
    for (int j = 0; j < 8; ++j) bv[j] = bias[tn * 8 + j];
    if (emode) {
#pragma unroll
        for (int j = 0; j < 8; ++j) {
            e0w[j] = extra_w[tn * 8 + j];
            e1w[j] = extra_w[NT + tn * 8 + j];
        }
    }
    float ts = 0.f, ts2 = 0.f;
#pragma unroll
    for (int i = 0; i < 8; ++i) {
        int m = m0 + tm * 8 + i;
        float e0 = 0.f, e1 = 0.f;
        if (emode == 1) {
            float2 sc = azsc[m & 1023];
            e0 = sc.x; e1 = sc.y;
        } else if (emode == 2) {
            e0 = extra2[2 * (size_t)m];
            e1 = extra2[2 * (size_t)m + 1];
        }
        float o[8];
#pragma unroll
        for (int j = 0; j < 8; ++j) {
            float v = acc[i][j] + bv[j];
            if (emode) v += e0 * e0w[j] + e1 * e1w[j];
            if (do_gelu) v = gelu_f(v);
            if (STATS) { ts += v; ts2 += v * v; }
            o[j] = v;
        }
        *(float4*)(C + (size_t)m * NT + tn * 8) = make_float4(o[0], o[1], o[2], o[3]);
        *(float4*)(C + (size_t)m * NT + tn * 8 + 4) = make_float4(o[4], o[5], o[6], o[7]);
    }
    if (STATS) {  // C=128, CPG=16: thread's 8 cols lie in group tn>>1
        atomicAdd(&sred[tn >> 1][0], ts);
        atomicAdd(&sred[tn >> 1][1], ts2);
        __syncthreads();
        if (tid < 8) {
            int b = m0 >> 15;
            atomicAdd(&stats1[(b * 8 + tid) * 2 + 0], sred[tid][0]);
            atomicAdd(&stats1[(b * 8 + tid) * 2 + 1], sred[tid][1]);
        }
    }
}

// ---------------- small-NT GEMM (8x4 micro) for attw ----------------
template <int MT, int NT, int NTH>
__global__ __launch_bounds__(NTH) void gemm_rn(
    const float* __restrict__ A, int lda,
    const float* __restrict__ W, int ldw,
    const float* __restrict__ bias,
    float* __restrict__ C, int ldc, int K) {
    static_assert(NTH == (MT / 8) * (NT / 4), "thread count mismatch");
    __shared__ float As[32][MT + 12];
    __shared__ float Ws[32][NT];
    constexpr int NTN = NT / 4;
    const int tid = threadIdx.x;
    const int tn = tid % NTN;
    const int tm = tid / NTN;
    const int m0 = blockIdx.x * MT;
    float acc[8][4];
#pragma unroll
    for (int i = 0; i < 8; ++i)
#pragma unroll
        for (int j = 0; j < 4; ++j) acc[i][j] = 0.f;

    for (int k0 = 0; k0 < K; k0 += 32) {
        __syncthreads();
        for (int f = tid; f < MT * 8; f += NTH) {
            int r = f >> 3, c4 = f & 7;
            float4 v = *(const float4*)(A + (size_t)(m0 + r) * lda + k0 + c4 * 4);
            As[c4 * 4 + 0][r] = v.x;
            As[c4 * 4 + 1][r] = v.y;
            As[c4 * 4 + 2][r] = v.z;
            As[c4 * 4 + 3][r] = v.w;
        }
        for (int f = tid; f < 8 * NT; f += NTH) {
            int kk = f / NTN, n4 = f % NTN;
            *(float4*)&Ws[kk][n4 * 4] = *(const float4*)(W + (size_t)(k0 + kk) * ldw + n4 * 4);
        }
        __syncthreads();
#pragma unroll 4
        for (int k = 0; k < 32; ++k) {
            const float4 a0 = *(const float4*)&As[k][tm * 8];
            const float4 a1 = *(const float4*)&As[k][tm * 8 + 4];
            const float4 wv = *(const float4*)&Ws[k][tn * 4];
            acc[0][0] += a0.x * wv.x; acc[0][1] += a0.x * wv.y; acc[0][2] += a0.x * wv.z; acc[0][3] += a0.x * wv.w;
            acc[1][0] += a0.y * wv.x; acc[1][1] += a0.y * wv.y; acc[1][2] += a0.y * wv.z; acc[1][3] += a0.y * wv.w;
            acc[2][0] += a0.z * wv.x; acc[2][1] += a0.z * wv.y; acc[2][2] += a0.z * wv.z; acc[2][3] += a0.z * wv.w;
            acc[3][0] += a0.w * wv.x; acc[3][1] += a0.w * wv.y; acc[3][2] += a0.w * wv.z; acc[3][3] += a0.w * wv.w;
            acc[4][0] += a1.x * wv.x; acc[4][1] += a1.x * wv.y; acc[4][2] += a1.x * wv.z; acc[4][3] += a1.x * wv.w;
            acc[5][0] += a1.y * wv.x; acc[5][1] += a1.y * wv.y; acc[5][2] += a1.y * wv.z; acc[5][3] += a1.y * wv.w;
            acc[6][0] += a1.z * wv.x; acc[6][1] += a1.z * wv.y; acc[6][2] += a1.z * wv.z; acc[6][3] += a1.z * wv.w;
            acc[7][0] += a1.w * wv.x; acc[7][1] += a1.w * wv.y; acc[7][2] += a1.w * wv.z; acc[7][3] += a1.w * wv.w;
        }
    }
#pragma unroll
    for (int i = 0; i < 8; ++i) {
        int m = m0 + tm * 8 + i;
        float4 o;
        o.x = acc[i][0] + bias[tn * 4 + 0];
        o.y = acc[i][1] + bias[tn * 4 + 1];
        o.z = acc[i][2] + bias[tn * 4 + 2];
        o.w = acc[i][3] + bias[tn * 4 + 3];
        *(float4*)(C + (size_t)m * ldc + tn * 4) = o;
    }
}

// ------------- fused value GEMM: transpose + split + MFMA (round 12) -------
// V[b][n][d] = sum_k bev[b][k][n] * W[k][d] + bias[d], K=256.
// Block: 512 thr / 8 waves, tile 128n x 128d, k-chunks of 32.
// Stage: bev ROWS (coalesced 512B segments) -> LDS [k][n] fp32 pitch 134.
// Frag read: column b32 x8 (2-way bank = free: (8*134)%32=16 splits quads),
// then in-register hi/lo split (trunc-perm + cvt_pk, same numerics as the
// round-9 transpose). B: fragment-major wvh/wvl direct from L2.
// Double-buffered LDS, ONE raw s_barrier + lgkmcnt(0) per chunk, global
// prefetch 2 chunks ahead stays in flight across barriers (no vmcnt drain).
__global__ __launch_bounds__(512) void value_gemm_fused(
    const float* __restrict__ bev,
    const unsigned short* __restrict__ Wh, const unsigned short* __restrict__ Wl,
    const float* __restrict__ bf, float* __restrict__ V) {
    __shared__ __align__(16) float T0[32 * 134];
    __shared__ __align__(16) float T1[32 * 134];
    const int tid = threadIdx.x;
    const int wid = tid >> 6;
    const int lane = tid & 63;
    const int m = lane & 15;
    const int quad = lane >> 4;
    const int n0 = blockIdx.x * 128;
    const int b = blockIdx.y;
    const int wn = wid >> 1;          // 0..3: n-group of 32
    const int wd = wid & 1;           // 0..1: d-group of 64
    const float* src = bev + (size_t)b * 256 * 40000;

    // staging: 2 float4 per thread per chunk; rows k, cols n (clamped reads)
    int srow[2];
    const float* sp[2];
    int lcol[2];
#pragma unroll
    for (int i = 0; i < 2; ++i) {
        int f = tid + i * 512;
        srow[i] = f >> 5;
        lcol[i] = (f & 31) * 4;
        int nl = n0 + lcol[i];
        if (nl > 39996) nl = 39996;    // clamp read; stores are guarded
        sp[i] = src + nl;
    }

    f32x4 acc[2][4];
#pragma unroll
    for (int i = 0; i < 2; ++i)
#pragma unroll
        for (int j = 0; j < 4; ++j) acc[i][j] = (f32x4){0.f, 0.f, 0.f, 0.f};

    const int dt0 = wd * 4;
    size_t bb[4];
#pragma unroll
    for (int j = 0; j < 4; ++j) bb[j] = (size_t)(dt0 + j) * 4096 + lane * 8;

    union UV { uint4 u; bf16x8 v; };
    float4 st[2];

#define LOADG(K0)                                                           \
    {                                                                       \
        _Pragma("unroll")                                                   \
        for (int i_ = 0; i_ < 2; ++i_)                                      \
            st[i_] = *(const float4*)(sp[i_] + (size_t)((K0) + srow[i_]) * 40000); \
    }
#define WRITELDS(TB)                                                        \
    {                                                                       \
        _Pragma("unroll")                                                   \
        for (int i_ = 0; i_ < 2; ++i_) {                                    \
            float* d_ = (TB) + srow[i_] * 134 + lcol[i_];                   \
            *(float2*)(d_ + 0) = make_float2(st[i_].x, st[i_].y);           \
            *(float2*)(d_ + 2) = make_float2(st[i_].z, st[i_].w);           \
        }                                                                   \
    }

    float* Tc = T0;
    float* Tn = T1;
    LOADG(0);
    WRITELDS(Tc);
    LOADG(32);
    asm volatile("s_waitcnt lgkmcnt(0)" ::: "memory");
    __builtin_amdgcn_sched_barrier(0);
    __builtin_amdgcn_s_barrier();
    __builtin_amdgcn_sched_barrier(0);

    for (int t = 0; t < 8; ++t) {
        // A fragments: column reads from Tc + in-register hi/lo split
        bf16x8 ah[2], al[2];
#pragma unroll
        for (int i = 0; i < 2; ++i) {
            const int nc = wn * 32 + i * 16 + m;
            float f8[8];
#pragma unroll
            for (int jj = 0; jj < 8; ++jj)
                f8[jj] = Tc[(quad * 8 + jj) * 134 + nc];
            unsigned hh[4], ll[4];
#pragma unroll
            for (int q = 0; q < 4; ++q) {
                unsigned u0 = __float_as_uint(f8[2 * q]);
                unsigned u1 = __float_as_uint(f8[2 * q + 1]);
                hh[q] = __builtin_amdgcn_perm(u1, u0, 0x07060302);  // trunc pair
                float l0 = f8[2 * q] - __uint_as_float(u0 & 0xffff0000u);
                float l1 = f8[2 * q + 1] - __uint_as_float(u1 & 0xffff0000u);
                asm("v_cvt_pk_bf16_f32 %0, %1, %2" : "=v"(ll[q]) : "v"(l0), "v"(l1));
            }
            UV th, tl;
            th.u = make_uint4(hh[0], hh[1], hh[2], hh[3]);
            tl.u = make_uint4(ll[0], ll[1], ll[2], ll[3]);
            ah[i] = th.v;
            al[i] = tl.v;
        }
        // stage next chunk into the other buffer; prefetch chunk t+2
        if (t < 7) WRITELDS(Tn);
        if (t < 6) LOADG(t * 32 + 64);
        // B fragments (fragment-major, L2-resident)
        bf16x8 bh[4], bl[4];
#pragma unroll
        for (int j = 0; j < 4; ++j) {
            bh[j] = *(const bf16x8*)(Wh + bb[j] + t * 512);
            bl[j] = *(const bf16x8*)(Wl + bb[j] + t * 512);
        }
#pragma unroll
        for (int i = 0; i < 2; ++i)
#pragma unroll
            for (int j = 0; j < 4; ++j) {
                acc[i][j] = __builtin_amdgcn_mfma_f32_16x16x32_bf16(ah[i], bh[j], acc[i][j], 0, 0, 0);
                acc[i][j] = __builtin_amdgcn_mfma_f32_16x16x32_bf16(ah[i], bl[j], acc[i][j], 0, 0, 0);
                acc[i][j] = __builtin_amdgcn_mfma_f32_16x16x32_bf16(al[i], bh[j], acc[i][j], 0, 0, 0);
            }
        if (t < 7) {
            asm volatile("s_waitcnt lgkmcnt(0)" ::: "memory");
            __builtin_amdgcn_sched_barrier(0);
            __builtin_amdgcn_s_barrier();
            __builtin_amdgcn_sched_barrier(0);
            float* tmp = Tc; Tc = Tn; Tn = tmp;
        }
    }
#undef LOADG
#undef WRITELDS
    // epilogue: D row = quad*4 + r (n), col = m (d); add fused bias
    float bv[4];
#pragma unroll
    for (int j = 0; j < 4; ++j) bv[j] = bf[wd * 64 + j * 16 + m];
#pragma unroll
    for (int i = 0; i < 2; ++i) {
        int nbase = n0 + wn * 32 + i * 16 + quad * 4;
#pragma unroll
        for (int r = 0; r < 4; ++r) {
            int n = nbase + r;
            if (n < 40000) {
                float* vp = V + ((size_t)b * 40000 + n) * 128 + wd * 64 + m;
#pragma unroll
                for (int j = 0; j < 4; ++j) vp[j * 16] = acc[i][j][r] + bv[j];
            }
        }
    }
}

// ---------------- GN1 apply + GELU -> bf16 ----------------
__global__ __launch_bounds__(256) void gn1_bf16(
    const float* __restrict__ X, const float* __restrict__ stats,
    const float* __restrict__ g1, const float* __restrict__ be1,
    unsigned short* __restrict__ Ob) {
    size_t i4 = (size_t)blockIdx.x * 256 + threadIdx.x;
    size_t base = i4 * 4;
    int c = (int)(base & 127);
    int mrow = (int)(base >> 7);
    int b = mrow >> 15;
    int g = c >> 4;
    float mean = stats[(b * 8 + g) * 2 + 0] * (1.0f / 524288.0f);
    float var = stats[(b * 8 + g) * 2 + 1] * (1.0f / 524288.0f) - mean * mean;
    float rs = 1.0f / sqrtf(var + 1e-5f);
    float4 x = *(const float4*)(X + base);
    float4 gm = *(const float4*)(g1 + c);
    float4 bt = *(const float4*)(be1 + c);
    ushort4 o;
    o.x = f2bf(gelu_f((x.x - mean) * rs * gm.x + bt.x));
    o.y = f2bf(gelu_f((x.y - mean) * rs * gm.y + bt.y));
    o.z = f2bf(gelu_f((x.z - mean) * rs * gm.z + bt.z));
    o.w = f2bf(gelu_f((x.w - mean) * rs * gm.w + bt.w));
    *(ushort4*)(Ob + base) = o;
}

// ---------------- 3x3 circular conv via bf16 MFMA ----------------
__global__ __launch_bounds__(256, 4) void conv3x3_mfma(
    const unsigned short* __restrict__ H1b,  // [2][32][1024][128] bf16
    const unsigned short* __restrict__ Wtb,  // [9][4][64][32] bf16
    float* __restrict__ Y,                   // [2][32][1024][64]
    float* __restrict__ stats2) {
    __shared__ short As_s[66 * 40];      // [xx][ci_chunk] 5.2 KB
    __shared__ short Ws_s[3 * 64 * 40];  // [dx][o][ci_chunk] 15.4 KB
    __shared__ float sred[8][2];
    const int tid = threadIdx.x;
    const int wid = tid >> 6;
    const int lane = tid & 63;
    const int m = lane & 15;
    const int quad = lane >> 4;
    const int x0 = blockIdx.x * 64;
    const int y = blockIdx.y;
    const int b = blockIdx.z;
    if (tid < 16) sred[tid >> 1][tid & 1] = 0.f;
    f32x4 acc[4];
#pragma unroll
    for (int oq = 0; oq < 4; ++oq) acc[oq] = (f32x4){0.f, 0.f, 0.f, 0.f};

    const unsigned short* Hb = H1b + (size_t)b * 32 * 1024 * 128;
    for (int ry = 0; ry < 3; ++ry) {
        const int gy = (y + ry + 31) & 31;
        const unsigned short* Hrow = Hb + (size_t)gy * 1024 * 128;
        for (int cc4 = 0; cc4 < 4; ++cc4) {
            __syncthreads();
            // A: 66 xx-rows x 4 octets of 8 bf16 = 264 16B chunks
            for (int f = tid; f < 264; f += 256) {
                int xx = f >> 2, cq = f & 3;
                int gx = (x0 + xx + 1023) & 1023;
                uint4 v = *(const uint4*)(Hrow + (size_t)gx * 128 + cc4 * 32 + cq * 8);
                *(uint4*)&As_s[xx * 40 + cq * 8] = v;
            }
            // W: 3 dx x 64 o x 4 octets = 768 16B chunks
            for (int f = tid; f < 768; f += 256) {
                int cq = f & 3, o = (f >> 2) & 63, dx = f >> 8;
                int tap = ry * 3 + dx;
                uint4 v = *(const uint4*)(Wtb + ((size_t)(tap * 4 + cc4) * 64 + o) * 32 + cq * 8);
                *(uint4*)&Ws_s[(dx * 64 + o) * 40 + cq * 8] = v;
            }
            __syncthreads();
            const int arow = wid * 16 + m;
#pragma unroll
            for (int dx = 0; dx < 3; ++dx) {
                bf16x8 a = *(const bf16x8*)&As_s[(arow + dx) * 40 + quad * 8];
#pragma unroll
                for (int oq = 0; oq < 4; ++oq) {
                    bf16x8 bfr = *(const bf16x8*)&Ws_s[(dx * 64 + oq * 16 + m) * 40 + quad * 8];
                    acc[oq] = __builtin_amdgcn_mfma_f32_16x16x32_bf16(a, bfr, acc[oq], 0, 0, 0);
                }
            }
        }
    }
    // GN2 stats: lane's frag oq covers o = oq*16 + m -> group oq*2 + (m>>3)
    float sv[4], qv[4];
#pragma unroll
    for (int oq = 0; oq < 4; ++oq) {
        sv[oq] = acc[oq].x + acc[oq].y + acc[oq].z + acc[oq].w;
        qv[oq] = acc[oq].x * acc[oq].x + acc[oq].y * acc[oq].y +
                 acc[oq].z * acc[oq].z + acc[oq].w * acc[oq].w;
    }
    const int masks[5] = {1, 2, 4, 16, 32};  // reduce over all but bit3
#pragma unroll
    for (int mi = 0; mi < 5; ++mi) {
#pragma unroll
        for (int oq = 0; oq < 4; ++oq) {
            sv[oq] += __shfl_xor(sv[oq], masks[mi]);
            qv[oq] += __shfl_xor(qv[oq], masks[mi]);
        }
    }
    if ((lane & 55) == 0) {  // lanes 0, 8
        int gb = (lane >> 3) & 1;
#pragma unroll
        for (int oq = 0; oq < 4; ++oq) {
            atomicAdd(&sred[oq * 2 + gb][0], sv[oq]);
            atomicAdd(&sred[oq * 2 + gb][1], qv[oq]);
        }
    }
    // store: D row = quad*4 + r (px), col = o
    const int pxb = x0 + wid * 16 + quad * 4;
    float* Yb = Y + ((size_t)(b * 32 + y) * 1024 + pxb) * 64;
#pragma unroll
    for (int oq = 0; oq < 4; ++oq) {
        const float av[4] = {acc[oq].x, acc[oq].y, acc[oq].z, acc[oq].w};
#pragma unroll
        for (int r = 0; r < 4; ++r) Yb[(size_t)r * 64 + oq * 16 + m] = av[r];
    }
    __syncthreads();
    if (tid < 16)
        atomicAdd(&stats2[(b * 8 + (tid >> 1)) * 2 + (tid & 1)], sred[tid >> 1][tid & 1]);
}

// ---------------- fused GN2-apply + GELU + rh3 head ----------------
__global__ __launch_bounds__(256) void rh3_kernel(
    const float* __restrict__ H2, const float* __restrict__ stats,
    const float* __restrict__ gamma, const float* __restrict__ beta, float inv_cnt,
    const float* __restrict__ w3, const float* __restrict__ b3,
    const float2* __restrict__ azsc,
    float2* __restrict__ refxy, float2* __restrict__ sigf) {
    const int tid = threadIdx.x;
    const int lane = tid & 15;
    const int m = blockIdx.x * 16 + (tid >> 4);
    const int b = m >> 15;
    const int c = lane * 4;
    const int g = c >> 3;
    float mean = stats[(b * 8 + g) * 2 + 0] * inv_cnt;
    float var = stats[(b * 8 + g) * 2 + 1] * inv_cnt - mean * mean;
    float rs = 1.0f / sqrtf(var + 1e-5f);
    float4 v = *(const float4*)(H2 + (size_t)m * 64 + c);
    float hv[4];
    hv[0] = gelu_f((v.x - mean) * rs * gamma[c + 0] + beta[c + 0]);
    hv[1] = gelu_f((v.y - mean) * rs * gamma[c + 1] + beta[c + 1]);
    hv[2] = gelu_f((v.z - mean) * rs * gamma[c + 2] + beta[c + 2]);
    hv[3] = gelu_f((v.w - mean) * rs * gamma[c + 3] + beta[c + 3]);
    float d0 = 0.f, d1 = 0.f;
#pragma unroll
    for (int k = 0; k < 4; ++k) {
        d0 += hv[k] * w3[(c + k) * 2 + 0];
        d1 += hv[k] * w3[(c + k) * 2 + 1];
    }
#pragma unroll
    for (int s = 1; s < 16; s <<= 1) {
        d0 += __shfl_xor(d0, s, 16);
        d1 += __shfl_xor(d1, s, 16);
    }
    if (lane == 0) {
        float mu = fminf(fmaxf(d0 + b3[0], 0.f), 55.f);
        float ls = fminf(fmaxf(d1 + b3[1], -5.f), 3.f);
        float sg = expf(ls);
        float2 sc = azsc[m & 1023];
        float rx = fminf(fmaxf(mu * sc.y * 0.01f + 0.5f, 0.f), 1.f);
        float ry = fminf(fmaxf(mu * sc.x * 0.01f + 0.5f, 0.f), 1.f);
        refxy[m] = make_float2(rx, ry);
        sigf[m] = make_float2(ls, 1.f / (sg + 1e-6f));
    }
}

// ---------------- MSDA bilinear sampling ----------------
__global__ __launch_bounds__(256) void msda_kernel(
    const float* __restrict__ V, const float2* __restrict__ refxy,
    const float* __restrict__ offs, const float* __restrict__ aw,
    float* __restrict__ out) {
    const int tid = threadIdx.x;
    const int l4 = tid & 3;         // dh quarter
    const int grp = tid >> 2;       // 0..63: 8 m x 8 heads
    const int m = blockIdx.x * 8 + (grp >> 3);
    const int head = grp & 7;
    const int b = m >> 15;
    float2 r = refxy[m];
    const float* lg = aw + (size_t)m * 48 + head * 6;
    float l[6];
#pragma unroll
    for (int p = 0; p < 6; ++p) l[p] = lg[p];
    float mx = l[0];
#pragma unroll
    for (int p = 1; p < 6; ++p) mx = fmaxf(mx, l[p]);
    float s = 0.f;
#pragma unroll
    for (int p = 0; p < 6; ++p) { l[p] = expf(l[p] - mx); s += l[p]; }
    float inv = 1.f / s;
#pragma unroll
    for (int p = 0; p < 6; ++p) l[p] *= inv;   // fold softmax into weights
    const float* of = offs + (size_t)m * 96 + head * 12;
    const float* Vb = V + (size_t)b * 40000 * 128 + head * 16 + l4 * 4;
    const float bx = r.x * 200.f - 0.5f;
    const float by = r.y * 200.f - 0.5f;
    f32x4 acc = (f32x4){0.f, 0.f, 0.f, 0.f};
#pragma unroll
    for (int p = 0; p < 6; ++p) {
        float px = bx + of[p * 2 + 0];
        float py = by + of[p * 2 + 1];
        float fx = floorf(px), fy = floorf(py);
        int x0 = (int)fx, y0 = (int)fy;
        float wx = px - fx, wy = py - fy;
        // clamped addresses (always in range); invalid corners get weight 0
        int xc0 = min(max(x0, 0), 199), xc1 = min(max(x0 + 1, 0), 199);
        int yc0 = min(max(y0, 0), 199), yc1 = min(max(y0 + 1, 0), 199);
        bool vx0 = ((unsigned)x0 < 200u), vx1 = ((unsigned)(x0 + 1) < 200u);
        bool vy0 = ((unsigned)y0 < 200u), vy1 = ((unsigned)(y0 + 1) < 200u);
        const f32x4 v00 = *(const f32x4*)(Vb + ((size_t)(yc0 * 200 + xc0)) * 128);
        const f32x4 v10 = *(const f32x4*)(Vb + ((size_t)(yc0 * 200 + xc1)) * 128);
        const f32x4 v01 = *(const f32x4*)(Vb + ((size_t)(yc1 * 200 + xc0)) * 128);
        const f32x4 v11 = *(const f32x4*)(Vb + ((size_t)(yc1 * 200 + xc1)) * 128);
        float w = l[p];
        float w00 = (vx0 && vy0) ? w * (1.f - wx) * (1.f - wy) : 0.f;
        float w10 = (vx1 && vy0) ? w * wx * (1.f - wy) : 0.f;
        float w01 = (vx0 && vy1) ? w * (1.f - wx) * wy : 0.f;
        float w11 = (vx1 && vy1) ? w * wx * wy : 0.f;
        acc += v00 * w00;
        acc += v10 * w10;
        acc += v01 * w01;
        acc += v11 * w11;
    }
    *(f32x4*)(out + (size_t)m * 128 + head * 16 + l4 * 4) = acc;
}

// ---------------- launch ----------------
extern "C" void kernel_launch(void* const* d_in, const int* in_sizes, int n_in,
                              void* d_out, int out_size, void* d_ws, size_t ws_size,
                              hipStream_t stream) {
    const float* x_rv = (const float*)d_in[0];
    const float* bev = (const float*)d_in[1];
    const float* pq_w = (const float*)d_in[2];
    const float* pq_b = (const float*)d_in[3];
    const float* pv_w = (const float*)d_in[4];
    const float* pv_b = (const float*)d_in[5];
    const float* po_w = (const float*)d_in[6];
    const float* po_b = (const float*)d_in[7];
    const float* qs_w1 = (const float*)d_in[8];
    const float* qs_b1 = (const float*)d_in[9];
    const float* qs_w2 = (const float*)d_in[10];
    const float* qs_b2 = (const float*)d_in[11];
    const float* rh_w1 = (const float*)d_in[12];
    const float* rh_b1 = (const float*)d_in[13];
    const float* rh_g1 = (const float*)d_in[14];
    const float* rh_be1 = (const float*)d_in[15];
    const float* rh_w2 = (const float*)d_in[16];
    const float* rh_g2 = (const float*)d_in[17];
    const float* rh_be2 = (const float*)d_in[18];
    const float* rh_w3 = (const float*)d_in[19];
    const float* rh_b3 = (const float*)d_in[20];
    const float* so_w = (const float*)d_in[21];
    const float* so_b = (const float*)d_in[22];
    const float* aw_w = (const float*)d_in[23];
    const float* aw_b = (const float*)d_in[24];
    const float* vp_w = (const float*)d_in[25];
    const float* vp_b = (const float*)d_in[26];
    const float* op_w = (const float*)d_in[27];
    const float* op_b = (const float*)d_in[28];

    const int M = 65536;

    float* ws = (float*)d_ws;
    float* azsc = ws;    ws += 2048;
    unsigned short* wvh = (unsigned short*)ws; ws += 16384;  // 8x8x64x8 bf16-hi frag-major
    unsigned short* wvl = (unsigned short*)ws; ws += 16384;  // 8x8x64x8 bf16-lo frag-major
    float* pvvp_b = ws;  ws += 128;
    float* oppo_w = ws;  ws += 128 * 128;
    float* oppo_b = ws;  ws += 128;
    float* pqqs_w = ws;  ws += 64 * 128;
    float* pqqs_b = ws;  ws += 128;
    float* qsso_w = ws;  ws += 128 * 96;
    float* qsso_b = ws;  ws += 128;
    float* qsaw_w = ws;  ws += 128 * 48;
    float* qsaw_b = ws;  ws += 64;
    float* stats = ws;   ws += 64;   // [0:32) GN1, [32:64) GN2
    unsigned short* wtb = (unsigned short*)ws;  ws += 36864;   // 73728 bf16
    unsigned short* h1b = (unsigned short*)ws;  ws += (size_t)M * 64;  // M*128 bf16
    float* Vv = ws;      ws += (size_t)80000 * 128;
    float* h1 = ws;      ws += (size_t)M * 128;
    float* h2 = ws;      ws += (size_t)M * 64;
    float* q1 = ws;      ws += (size_t)M * 128;
    float* refxy = ws;   ws += (size_t)M * 2;
    float* sigf = ws;    ws += (size_t)M * 2;
    size_t need_bytes = (size_t)(ws - (float*)d_ws) * sizeof(float);
    if (ws_size < need_bytes) return;
    float* offs = h1;   // h1 (raw rh1) dead after gn1_bf16
    float* attw = h2;   // h2 dead after rh3
    float* mo = q1;     // q1 dead after offs/attw GEMMs

    float2* azsc2 = (float2*)azsc;
    float2* refxy2 = (float2*)refxy;
    float2* sigf2 = (float2*)sigf;

    prep_weights<<<1293, 128, 0, stream>>>(
        pv_w, pv_b, vp_w, vp_b, op_w, op_b, po_w, po_b, pq_w, pq_b,
        qs_w1, qs_b1, qs_w2, qs_b2, so_w, so_b, aw_w, aw_b, rh_w2,
        wvh, wvl, pvvp_b, oppo_w, oppo_b, pqqs_w, pqqs_b,
        qsso_w, qsso_b, qsaw_w, qsaw_b, wtb, azsc2);
    hipMemsetAsync(stats, 0, 64 * sizeof(float), stream);

    // value = bev^T @ (pv_w@vp_w) + fused bias -- fused transpose+split+MFMA
    value_gemm_fused<<<dim3(313, 2), 512, 0, stream>>>(bev, wvh, wvl, pvvp_b, Vv);

    // h1 = raw rh1 (x_rv(+az) @ rh_w1 + b); fused GN1 stats
    gemm_v3<128, true><<<M / 128, 256, 0, stream>>>(
        x_rv, 64, rh_w1, rh_b1, h1, 64, azsc2, nullptr, rh_w1 + 64 * 128, 1, 0, stats);

    // GN1 apply + gelu -> bf16
    gn1_bf16<<<8192, 256, 0, stream>>>(h1, stats, rh_g1, rh_be1, h1b);

    // conv via bf16 MFMA; GN2 stats in epilogue
    conv3x3_mfma<<<dim3(16, 32, 2), 256, 0, stream>>>(h1b, wtb, h2, stats + 32);

    // fused GN2-apply + gelu + rh3 head
    rh3_kernel<<<4096, 256, 0, stream>>>(h2, stats + 32, rh_g2, rh_be2, 1.0f / 262144.0f,
                                         rh_w3, rh_b3, azsc2, refxy2, sigf2);

    // q1 = gelu(x_rv @ (pq_w@qs_w1a) + sigf extras + fused bias)
    gemm_v3<128, false><<<M / 128, 256, 0, stream>>>(
        x_rv, 64, pqqs_w, pqqs_b, q1, 64, nullptr, sigf, qs_w1 + 128 * 128, 2, 1, nullptr);

    // offs = q1 @ (qs_w2@so_w) + folded bias
    gemm_v3<96, false><<<M / 128, 192, 0, stream>>>(
        q1, 128, qsso_w, qsso_b, offs, 128, nullptr, nullptr, nullptr, 0, 0, nullptr);

    // attw logits = q1 @ (qs_w2@aw_w) + folded bias
    gemm_rn<128, 48, 192><<<M / 128, 192, 0, stream>>>(
        q1, 128, qsaw_w, 48, qsaw_b, attw, 48, 128);

    // MSDA sampling (into q1)
    msda_kernel<<<M / 8, 256, 0, stream>>>(Vv, refxy2, offs, attw, mo);

    // y = mo @ (op_w@po_w) + fused bias -> d_out
    gemm_v3<128, false><<<M / 128, 256, 0, stream>>>(
        mo, 128, oppo_w, oppo_b, (float*)d_out, 128, nullptr, nullptr, nullptr, 0, 0, nullptr);
}

// Round 8
// 464.450 us; speedup vs baseline: 1.1288x; 1.0110x over previous
//
#include <hip/hip_runtime.h>
#include <math.h>

#define PI_F 3.14159265358979323846f

// ---- static config ----
// B=2, HRV=32, WRV=1024, CRV=64; CB=256, HB=200, WB=200
// D=128, COUT=128, HEADS=8, POINTS=6, DH=16; M=65536, NV=40000
//
// Hard-won rules (rounds 1-13):
//  - value path needs ~fp32 ACCURACY, not fp32 ARITHMETIC: bf16x2 split
//    (hi = trunc, lo = RNE residual; hh+hl+lh MFMA) ~2^-17 rel error.
//  - (round 7) msda: replicate softmax/addr math 4x not 16x; float4 loads.
//  - (rounds 8-11) value-gemm walls, each HW-verified:
//    #1 strided global reads -> 64 quarter-used sectors/wave-instr at the
//       ~34.5TB/s L2 sector ceiling.
//    #2 __syncthreads drains vmcnt(0) -> kills cross-chunk prefetch; use
//       raw s_barrier + lgkmcnt(0) only.
//    #3 per-lane 16B frags at 512B lane stride = wall #1; fixed by
//       fragment-major layout (round 11, confirmed 63 -> <47us).
//  - (round 12) fused transpose+split+GEMM: coalesced row staging -> LDS
//    [k][n] (column b32 reads 2-way free when (8*pitch)%32==16),
//    in-register hi/lo split, 1 raw barrier/chunk. 60us split -> 54 fused.
//  - (round 13) 54us with clean sector counts + all pipes idle + occupancy
//    25% (= ONE 512-thr block/CU, breadth-first dispatch) = lockstep
//    barrier latency, no independent work. -> 4-wave blocks, 2x grid,
//    17.9KB LDS so multiple blocks/CU interleave across barriers.
//  - top-5 counters partially masked by harness workspace-poison fills
//    (327MB, 85% HBM) -- judge by dur_us.

typedef __attribute__((ext_vector_type(8))) short bf16x8;
typedef __attribute__((ext_vector_type(4))) float f32x4;

__device__ __forceinline__ float gelu_f(float x) {
    return 0.5f * x * (1.0f + erff(x * 0.70710678118654752440f));
}

__device__ __forceinline__ unsigned short f2bf(float x) {
    unsigned int u = __float_as_uint(x);
    u += 0x7fffu + ((u >> 16) & 1u);  // RNE
    return (unsigned short)(u >> 16);
}

__device__ __forceinline__ float bf2f(unsigned short h) {
    return __uint_as_float((unsigned int)h << 16);
}

// ---------------- fused weight prep (+ az table + bf16 conv weights) -------
// r<256 emits the value-path weight (pv_w@vp_w) split bf16 hi/lo in
// FRAGMENT-MAJOR order: wv[dt(8)][kc(8)][lane(64)][j(8)], where
// d = dt*16 + (lane&15), k = kc*32 + (lane>>4)*8 + j. A B-fragment load in
// the value GEMM is then base + lane*16B (coalesced 1KB).
__global__ void prep_weights(const float* __restrict__ pv_w, const float* __restrict__ pv_b,
                             const float* __restrict__ vp_w, const float* __restrict__ vp_b,
                             const float* __restrict__ op_w, const float* __restrict__ op_b,
                             const float* __restrict__ po_w, const float* __restrict__ po_b,
                             const float* __restrict__ pq_w, const float* __restrict__ pq_b,
                             const float* __restrict__ qs_w1, const float* __restrict__ qs_b1,
                             const float* __restrict__ qs_w2, const float* __restrict__ qs_b2,
                             const float* __restrict__ so_w, const float* __restrict__ so_b,
                             const float* __restrict__ aw_w, const float* __restrict__ aw_b,
                             const float* __restrict__ rh_w2,
                             unsigned short* __restrict__ wvh, unsigned short* __restrict__ wvl,
                             float* __restrict__ pvvp_b,
                             float* __restrict__ oppo_w, float* __restrict__ oppo_b,
                             float* __restrict__ pqqs_w, float* __restrict__ pqqs_b,
                             float* __restrict__ qsso_w, float* __restrict__ qsso_b,
                             float* __restrict__ qsaw_w, float* __restrict__ qsaw_b,
                             unsigned short* __restrict__ wtb,
                             float2* __restrict__ azsc) {
    int r = blockIdx.x;
    int d = threadIdx.x; // 0..127
    if (r < 256) {
        // r = k index, d = output channel
        float s = 0.f;
        for (int k = 0; k < 128; ++k) s += pv_w[r * 128 + k] * vp_w[k * 128 + d];
        unsigned short h = f2bf(s);
        int dt = d >> 4, mm = d & 15;
        int kc = r >> 5, qd = (r >> 3) & 3, jj = r & 7;
        size_t off = (((size_t)(dt * 8 + kc) * 64) + qd * 16 + mm) * 8 + jj;
        wvh[off] = h;
        wvl[off] = f2bf(s - bf2f(h));
    } else if (r == 256) {
        float s = vp_b[d];
        for (int k = 0; k < 128; ++k) s += pv_b[k] * vp_w[k * 128 + d];
        pvvp_b[d] = s;
    } else if (r < 385) {
        int rr = r - 257;
        float s = 0.f;
        for (int k = 0; k < 128; ++k) s += op_w[rr * 128 + k] * po_w[k * 128 + d];
        oppo_w[rr * 128 + d] = s;
    } else if (r == 385) {
        float s = po_b[d];
        for (int k = 0; k < 128; ++k) s += op_b[k] * po_w[k * 128 + d];
        oppo_b[d] = s;
    } else if (r < 450) {
        int rr = r - 386;
        float s = 0.f;
        for (int k = 0; k < 128; ++k) s += pq_w[rr * 128 + k] * qs_w1[k * 128 + d];
        pqqs_w[rr * 128 + d] = s;
    } else if (r == 450) {
        float s = qs_b1[d];
        for (int k = 0; k < 128; ++k) s += pq_b[k] * qs_w1[k * 128 + d];
        pqqs_b[d] = s;
    } else if (r < 459) {
        int w = (r - 451) * 128 + d;
        float az = -PI_F + (float)w * (6.283185307179586f / 1024.0f);
        azsc[w] = make_float2(sinf(az), cosf(az));
    } else if (r < 587) {
        int rr = r - 459;
        if (d < 96) {
            float s = 0.f;
            for (int k = 0; k < 128; ++k) s += qs_w2[rr * 128 + k] * so_w[k * 96 + d];
            qsso_w[rr * 96 + d] = s;
        }
    } else if (r == 587) {
        if (d < 96) {
            float s = so_b[d];
            for (int k = 0; k < 128; ++k) s += qs_b2[k] * so_w[k * 96 + d];
            qsso_b[d] = s;
        }
    } else if (r < 716) {
        int rr = r - 588;
        if (d < 48) {
            float s = 0.f;
            for (int k = 0; k < 128; ++k) s += qs_w2[rr * 128 + k] * aw_w[k * 48 + d];
            qsaw_w[rr * 48 + d] = s;
        }
    } else if (r == 716) {
        if (d < 48) {
            float s = aw_b[d];
            for (int k = 0; k < 128; ++k) s += qs_b2[k] * aw_w[k * 48 + d];
            qsaw_b[d] = s;
        }
    } else {
        // conv weights -> bf16, transposed: wtb[tap][cc4][o][ci]
        int idx = (r - 717) * 128 + d;   // 0 .. 73727
        int ci = idx & 31;
        int o = (idx >> 5) & 63;
        int cc4i = (idx >> 11) & 3;
        int tap = idx >> 13;
        float w = rh_w2[((size_t)tap * 128 + cc4i * 32 + ci) * 64 + o];
        wtb[idx] = f2bf(w);
    }
}

// ---------------- MT=128 GEMM, 8x8 micro, 2*NT threads ----------------
template <int NT, bool STATS>
__global__ __launch_bounds__(2 * NT) void gemm_v3(
    const float* __restrict__ A, int lda,
    const float* __restrict__ W,
    const float* __restrict__ bias,
    float* __restrict__ C, int K,
    const float2* __restrict__ azsc,
    const float* __restrict__ extra2,
    const float* __restrict__ extra_w,
    int emode, int do_gelu, float* __restrict__ stats1) {
    constexpr int NTH = 2 * NT;
    constexpr int NTO = NT / 8;
    __shared__ float As[32][140];   // 140 % 32 = 12 -> conflict-free scatter
    __shared__ float Ws[32][NT];
    __shared__ float sred[8][2];
    const int tid = threadIdx.x;
    const int tn = tid % NTO;
    const int tm = tid / NTO;   // 0..15
    const int m0 = blockIdx.x * 128;
    if (STATS && tid < 16) sred[tid >> 1][tid & 1] = 0.f;
    float acc[8][8];
#pragma unroll
    for (int i = 0; i < 8; ++i)
#pragma unroll
        for (int j = 0; j < 8; ++j) acc[i][j] = 0.f;

    for (int k0 = 0; k0 < K; k0 += 32) {
        __syncthreads();
        for (int f = tid; f < 1024; f += NTH) {
            int r = f >> 3, c4 = f & 7;
            float4 v = *(const float4*)(A + (size_t)(m0 + r) * lda + k0 + c4 * 4);
            As[c4 * 4 + 0][r] = v.x;
            As[c4 * 4 + 1][r] = v.y;
            As[c4 * 4 + 2][r] = v.z;
            As[c4 * 4 + 3][r] = v.w;
        }
        for (int f = tid; f < 8 * NT; f += NTH) {
            int kk = f / (NT / 4), n4 = f % (NT / 4);
            *(float4*)&Ws[kk][n4 * 4] = *(const float4*)(W + (size_t)(k0 + kk) * NT + n4 * 4);
        }
        __syncthreads();
#pragma unroll 2
        for (int k = 0; k < 32; ++k) {
            const float4 a0 = *(const float4*)&As[k][tm * 8];
            const float4 a1 = *(const float4*)&As[k][tm * 8 + 4];
            const float4 w0 = *(const float4*)&Ws[k][tn * 8];
            const float4 w1 = *(const float4*)&Ws[k][tn * 8 + 4];
            const float av[8] = {a0.x, a0.y, a0.z, a0.w, a1.x, a1.y, a1.z, a1.w};
            const float wv[8] = {w0.x, w0.y, w0.z, w0.w, w1.x, w1.y, w1.z, w1.w};
#pragma unroll
            for (int i = 0; i < 8; ++i)
#pragma unroll
                for (int j = 0; j < 8; ++j) acc[i][j] += av[i] * wv[j];
        }
    }
    float bv[8], e0w[8], e1w[8];
#pragma unroll
    for (int j = 0; j < 8; ++j) bv[j] = bias[tn * 8 + j];
    if (emode) {
#pragma unroll
        for (int j = 0; j < 8; ++j) {
            e0w[j] = extra_w[tn * 8 + j];
            e1w[j] = extra_w[NT + tn * 8 + j];
        }
    }
    float ts = 0.f, ts2 = 0.f;
#pragma unroll
    for (int i = 0; i < 8; ++i) {
        int m = m0 + tm * 8 + i;
        float e0 = 0.f, e1 = 0.f;
        if (emode == 1) {
            float2 sc = azsc[m & 1023];
            e0 = sc.x; e1 = sc.y;
        } else if (emode == 2) {
            e0 = extra2[2 * (size_t)m];
            e1 = extra2[2 * (size_t)m + 1];
        }
        float o[8];
#pragma unroll
        for (int j = 0; j < 8; ++j) {
            float v = acc[i][j] + bv[j];
            if (emode) v += e0 * e0w[j] + e1 * e1w[j];
            if (do_gelu) v = gelu_f(v);
            if (STATS) { ts += v; ts2 += v * v; }
            o[j] = v;
        }
        *(float4*)(C + (size_t)m * NT + tn * 8) = make_float4(o[0], o[1], o[2], o[3]);
        *(float4*)(C + (size_t)m * NT + tn * 8 + 4) = make_float4(o[4], o[5], o[6], o[7]);
    }
    if (STATS) {  // C=128, CPG=16: thread's 8 cols lie in group tn>>1
        atomicAdd(&sred[tn >> 1][0], ts);
        atomicAdd(&sred[tn >> 1][1], ts2);
        __syncthreads();
        if (tid < 8) {
            int b = m0 >> 15;
            atomicAdd(&stats1[(b * 8 + tid) * 2 + 0], sred[tid][0]);
            atomicAdd(&stats1[(b * 8 + tid) * 2 + 1], sred[tid][1]);
        }
    }
}

// ---------------- small-NT GEMM (8x4 micro) for attw ----------------
template <int MT, int NT, int NTH>
__global__ __launch_bounds__(NTH) void gemm_rn(
    const float* __restrict__ A, int lda,
    const float* __restrict__ W, int ldw,
    const float* __restrict__ bias,
    float* __restrict__ C, int ldc, int K) {
    static_assert(NTH == (MT / 8) * (NT / 4), "thread count mismatch");
    __shared__ float As[32][MT + 12];
    __shared__ float Ws[32][NT];
    constexpr int NTN = NT / 4;
    const int tid = threadIdx.x;
    const int tn = tid % NTN;
    const int tm = tid / NTN;
    const int m0 = blockIdx.x * MT;
    float acc[8][4];
#pragma unroll
    for (int i = 0; i < 8; ++i)
#pragma unroll
        for (int j = 0; j < 4; ++j) acc[i][j] = 0.f;

    for (int k0 = 0; k0 < K; k0 += 32) {
        __syncthreads();
        for (int f = tid; f < MT * 8; f += NTH) {
            int r = f >> 3, c4 = f & 7;
            float4 v = *(const float4*)(A + (size_t)(m0 + r) * lda + k0 + c4 * 4);
            As[c4 * 4 + 0][r] = v.x;
            As[c4 * 4 + 1][r] = v.y;
            As[c4 * 4 + 2][r] = v.z;
            As[c4 * 4 + 3][r] = v.w;
        }
        for (int f = tid; f < 8 * NT; f += NTH) {
            int kk = f / NTN, n4 = f % NTN;
            *(float4*)&Ws[kk][n4 * 4] = *(const float4*)(W + (size_t)(k0 + kk) * ldw + n4 * 4);
        }
        __syncthreads();
#pragma unroll 4
        for (int k = 0; k < 32; ++k) {
            const float4 a0 = *(const float4*)&As[k][tm * 8];
            const float4 a1 = *(const float4*)&As[k][tm * 8 + 4];
            const float4 wv = *(const float4*)&Ws[k][tn * 4];
            acc[0][0] += a0.x * wv.x; acc[0][1] += a0.x * wv.y; acc[0][2] += a0.x * wv.z; acc[0][3] += a0.x * wv.w;
            acc[1][0] += a0.y * wv.x; acc[1][1] += a0.y * wv.y; acc[1][2] += a0.y * wv.z; acc[1][3] += a0.y * wv.w;
            acc[2][0] += a0.z * wv.x; acc[2][1] += a0.z * wv.y; acc[2][2] += a0.z * wv.z; acc[2][3] += a0.z * wv.w;
            acc[3][0] += a0.w * wv.x; acc[3][1] += a0.w * wv.y; acc[3][2] += a0.w * wv.z; acc[3][3] += a0.w * wv.w;
            acc[4][0] += a1.x * wv.x; acc[4][1] += a1.x * wv.y; acc[4][2] += a1.x * wv.z; acc[4][3] += a1.x * wv.w;
            acc[5][0] += a1.y * wv.x; acc[5][1] += a1.y * wv.y; acc[5][2] += a1.y * wv.z; acc[5][3] += a1.y * wv.w;
            acc[6][0] += a1.z * wv.x; acc[6][1] += a1.z * wv.y; acc[6][2] += a1.z * wv.z; acc[6][3] += a1.z * wv.w;
            acc[7][0] += a1.w * wv.x; acc[7][1] += a1.w * wv.y; acc[7][2] += a1.w * wv.z; acc[7][3] += a1.w * wv.w;
        }
    }
#pragma unroll
    for (int i = 0; i < 8; ++i) {
        int m = m0 + tm * 8 + i;
        float4 o;
        o.x = acc[i][0] + bias[tn * 4 + 0];
        o.y = acc[i][1] + bias[tn * 4 + 1];
        o.z = acc[i][2] + bias[tn * 4 + 2];
        o.w = acc[i][3] + bias[tn * 4 + 3];
        *(float4*)(C + (size_t)m * ldc + tn * 4) = o;
    }
}

// ------------- fused value GEMM: transpose + split + MFMA (round 13) -------
// V[b][n][d] = sum_k bev[b][k][n] * W[k][d] + bias[d], K=256.
// Block: 256 thr / 4 waves, tile 64n x 128d, k-chunks of 32; grid 625x2
// EXACT (no clamps/guards anywhere). Stage: bev ROWS (coalesced 256B
// segments) -> LDS [k][n] fp32 pitch 70 ((8*70)%32=16 -> column b32 reads
// 2-way free). In-register hi/lo split (trunc-perm + cvt_pk). B:
// fragment-major wvh/wvl direct from L2. Double-buffered LDS, ONE raw
// s_barrier + lgkmcnt(0) per chunk, prefetch in flight across barriers.
// 17.9KB LDS + 4-wave blocks -> several blocks/CU interleave (round-13 fix
// for the 1-block/CU lockstep latency wall).
__global__ __launch_bounds__(256) void value_gemm_fused(
    const float* __restrict__ bev,
    const unsigned short* __restrict__ Wh, const unsigned short* __restrict__ Wl,
    const float* __restrict__ bf, float* __restrict__ V) {
    __shared__ __align__(16) float T0[32 * 70];
    __shared__ __align__(16) float T1[32 * 70];
    const int tid = threadIdx.x;
    const int wid = tid >> 6;
    const int lane = tid & 63;
    const int m = lane & 15;
    const int quad = lane >> 4;
    const int n0 = blockIdx.x * 64;
    const int b = blockIdx.y;
    const int wn = wid >> 1;          // 0..1: n-group of 32
    const int wd = wid & 1;           // 0..1: d-group of 64
    const float* src = bev + (size_t)b * 256 * 40000;

    // staging: 2 float4 per thread per chunk; rows k (32), cols n (64)
    int srow[2], scol[2];
    const float* sp[2];
#pragma unroll
    for (int i = 0; i < 2; ++i) {
        int f = tid + i * 256;
        srow[i] = f >> 4;
        scol[i] = (f & 15) * 4;
        sp[i] = src + n0 + scol[i];    // n0+scol+4 <= 40000 always (exact grid)
    }

    f32x4 acc[2][4];
#pragma unroll
    for (int i = 0; i < 2; ++i)
#pragma unroll
        for (int j = 0; j < 4; ++j) acc[i][j] = (f32x4){0.f, 0.f, 0.f, 0.f};

    const int dt0 = wd * 4;
    size_t bb[4];
#pragma unroll
    for (int j = 0; j < 4; ++j) bb[j] = (size_t)(dt0 + j) * 4096 + lane * 8;

    union UV { uint4 u; bf16x8 v; };
    float4 st[2];

#define LOADG(K0)                                                           \
    {                                                                       \
        _Pragma("unroll")                                                   \
        for (int i_ = 0; i_ < 2; ++i_)                                      \
            st[i_] = *(const float4*)(sp[i_] + (size_t)((K0) + srow[i_]) * 40000); \
    }
#define WRITELDS(TB)                                                        \
    {                                                                       \
        _Pragma("unroll")                                                   \
        for (int i_ = 0; i_ < 2; ++i_) {                                    \
            float* d_ = (TB) + srow[i_] * 70 + scol[i_];                    \
            *(float2*)(d_ + 0) = make_float2(st[i_].x, st[i_].y);           \
            *(float2*)(d_ + 2) = make_float2(st[i_].z, st[i_].w);           \
        }                                                                   \
    }

    float* Tc = T0;
    float* Tn = T1;
    LOADG(0);
    WRITELDS(Tc);
    LOADG(32);
    asm volatile("s_waitcnt lgkmcnt(0)" ::: "memory");
    __builtin_amdgcn_sched_barrier(0);
    __builtin_amdgcn_s_barrier();
    __builtin_amdgcn_sched_barrier(0);

    for (int t = 0; t < 8; ++t) {
        // A fragments: column reads from Tc + in-register hi/lo split
        bf16x8 ah[2], al[2];
#pragma unroll
        for (int i = 0; i < 2; ++i) {
            const int nc = wn * 32 + i * 16 + m;
            float f8[8];
#pragma unroll
            for (int jj = 0; jj < 8; ++jj)
                f8[jj] = Tc[(quad * 8 + jj) * 70 + nc];
            unsigned hh[4], ll[4];
#pragma unroll
            for (int q = 0; q < 4; ++q) {
                unsigned u0 = __float_as_uint(f8[2 * q]);
                unsigned u1 = __float_as_uint(f8[2 * q + 1]);
                hh[q] = __builtin_amdgcn_perm(u1, u0, 0x07060302);  // trunc pair
                float l0 = f8[2 * q] - __uint_as_float(u0 & 0xffff0000u);
                float l1 = f8[2 * q + 1] - __uint_as_float(u1 & 0xffff0000u);
                asm("v_cvt_pk_bf16_f32 %0, %1, %2" : "=v"(ll[q]) : "v"(l0), "v"(l1));
            }
            UV th, tl;
            th.u = make_uint4(hh[0], hh[1], hh[2], hh[3]);
            tl.u = make_uint4(ll[0], ll[1], ll[2], ll[3]);
            ah[i] = th.v;
            al[i] = tl.v;
        }
        // stage next chunk into the other buffer; prefetch chunk t+2
        if (t < 7) WRITELDS(Tn);
        if (t < 6) LOADG(t * 32 + 64);
        // B fragments (fragment-major, L2-resident)
        bf16x8 bh[4], bl[4];
#pragma unroll
        for (int j = 0; j < 4; ++j) {
            bh[j] = *(const bf16x8*)(Wh + bb[j] + t * 512);
            bl[j] = *(const bf16x8*)(Wl + bb[j] + t * 512);
        }
#pragma unroll
        for (int i = 0; i < 2; ++i)
#pragma unroll
            for (int j = 0; j < 4; ++j) {
                acc[i][j] = __builtin_amdgcn_mfma_f32_16x16x32_bf16(ah[i], bh[j], acc[i][j], 0, 0, 0);
                acc[i][j] = __builtin_amdgcn_mfma_f32_16x16x32_bf16(ah[i], bl[j], acc[i][j], 0, 0, 0);
                acc[i][j] = __builtin_amdgcn_mfma_f32_16x16x32_bf16(al[i], bh[j], acc[i][j], 0, 0, 0);
            }
        if (t < 7) {
            asm volatile("s_waitcnt lgkmcnt(0)" ::: "memory");
            __builtin_amdgcn_sched_barrier(0);
            __builtin_amdgcn_s_barrier();
            __builtin_amdgcn_sched_barrier(0);
            float* tmp = Tc; Tc = Tn; Tn = tmp;
        }
    }
#undef LOADG
#undef WRITELDS
    // epilogue: D row = quad*4 + r (n), col = m (d); add fused bias
    float bv[4];
#pragma unroll
    for (int j = 0; j < 4; ++j) bv[j] = bf[wd * 64 + j * 16 + m];
#pragma unroll
    for (int i = 0; i < 2; ++i) {
        int nbase = n0 + wn * 32 + i * 16 + quad * 4;
#pragma unroll
        for (int r = 0; r < 4; ++r) {
            int n = nbase + r;   // always < 40000 (exact grid)
            float* vp = V + ((size_t)b * 40000 + n) * 128 + wd * 64 + m;
#pragma unroll
            for (int j = 0; j < 4; ++j) vp[j * 16] = acc[i][j][r] + bv[j];
        }
    }
}

// ---------------- GN1 apply + GELU -> bf16 ----------------
__global__ __launch_bounds__(256) void gn1_bf16(
    const float* __restrict__ X, const float* __restrict__ stats,
    const float* __restrict__ g1, const float* __restrict__ be1,
    unsigned short* __restrict__ Ob) {
    size_t i4 = (size_t)blockIdx.x * 256 + threadIdx.x;
    size_t base = i4 * 4;
    int c = (int)(base & 127);
    int mrow = (int)(base >> 7);
    int b = mrow >> 15;
    int g = c >> 4;
    float mean = stats[(b * 8 + g) * 2 + 0] * (1.0f / 524288.0f);
    float var = stats[(b * 8 + g) * 2 + 1] * (1.0f / 524288.0f) - mean * mean;
    float rs = 1.0f / sqrtf(var + 1e-5f);
    float4 x = *(const float4*)(X + base);
    float4 gm = *(const float4*)(g1 + c);
    float4 bt = *(const float4*)(be1 + c);
    ushort4 o;
    o.x = f2bf(gelu_f((x.x - mean) * rs * gm.x + bt.x));
    o.y = f2bf(gelu_f((x.y - mean) * rs * gm.y + bt.y));
    o.z = f2bf(gelu_f((x.z - mean) * rs * gm.z + bt.z));
    o.w = f2bf(gelu_f((x.w - mean) * rs * gm.w + bt.w));
    *(ushort4*)(Ob + base) = o;
}

// ---------------- 3x3 circular conv via bf16 MFMA ----------------
__global__ __launch_bounds__(256, 4) void conv3x3_mfma(
    const unsigned short* __restrict__ H1b,  // [2][32][1024][128] bf16
    const unsigned short* __restrict__ Wtb,  // [9][4][64][32] bf16
    float* __restrict__ Y,                   // [2][32][1024][64]
    float* __restrict__ stats2) {
    __shared__ short As_s[66 * 40];      // [xx][ci_chunk] 5.2 KB
    __shared__ short Ws_s[3 * 64 * 40];  // [dx][o][ci_chunk] 15.4 KB
    __shared__ float sred[8][2];
    const int tid = threadIdx.x;
    const int wid = tid >> 6;
    const int lane = tid & 63;
    const int m = lane & 15;
    const int quad = lane >> 4;
    const int x0 = blockIdx.x * 64;
    const int y = blockIdx.y;
    const int b = blockIdx.z;
    if (tid < 16) sred[tid >> 1][tid & 1] = 0.f;
    f32x4 acc[4];
#pragma unroll
    for (int oq = 0; oq < 4; ++oq) acc[oq] = (f32x4){0.f, 0.f, 0.f, 0.f};

    const unsigned short* Hb = H1b + (size_t)b * 32 * 1024 * 128;
    for (int ry = 0; ry < 3; ++ry) {
        const int gy = (y + ry + 31) & 31;
        const unsigned short* Hrow = Hb + (size_t)gy * 1024 * 128;
        for (int cc4 = 0; cc4 < 4; ++cc4) {
            __syncthreads();
            // A: 66 xx-rows x 4 octets of 8 bf16 = 264 16B chunks
            for (int f = tid; f < 264; f += 256) {
                int xx = f >> 2, cq = f & 3;
                int gx = (x0 + xx + 1023) & 1023;
                uint4 v = *(const uint4*)(Hrow + (size_t)gx * 128 + cc4 * 32 + cq * 8);
                *(uint4*)&As_s[xx * 40 + cq * 8] = v;
            }
            // W: 3 dx x 64 o x 4 octets = 768 16B chunks
            for (int f = tid; f < 768; f += 256) {
                int cq = f & 3, o = (f >> 2) & 63, dx = f >> 8;
                int tap = ry * 3 + dx;
                uint4 v = *(const uint4*)(Wtb + ((size_t)(tap * 4 + cc4) * 64 + o) * 32 + cq * 8);
                *(uint4*)&Ws_s[(dx * 64 + o) * 40 + cq * 8] = v;
            }
            __syncthreads();
            const int arow = wid * 16 + m;
#pragma unroll
            for (int dx = 0; dx < 3; ++dx) {
                bf16x8 a = *(const bf16x8*)&As_s[(arow + dx) * 40 + quad * 8];
#pragma unroll
                for (int oq = 0; oq < 4; ++oq) {
                    bf16x8 bfr = *(const bf16x8*)&Ws_s[(dx * 64 + oq * 16 + m) * 40 + quad * 8];
                    acc[oq] = __builtin_amdgcn_mfma_f32_16x16x32_bf16(a, bfr, acc[oq], 0, 0, 0);
                }
            }
        }
    }
    // GN2 stats: lane's frag oq covers o = oq*16 + m -> group oq*2 + (m>>3)
    float sv[4], qv[4];
#pragma unroll
    for (int oq = 0; oq < 4; ++oq) {
        sv[oq] = acc[oq].x + acc[oq].y + acc[oq].z + acc[oq].w;
        qv[oq] = acc[oq].x * acc[oq].x + acc[oq].y * acc[oq].y +
                 acc[oq].z * acc[oq].z + acc[oq].w * acc[oq].w;
    }
    const int masks[5] = {1, 2, 4, 16, 32};  // reduce over all but bit3
#pragma unroll
    for (int mi = 0; mi < 5; ++mi) {
#pragma unroll
        for (int oq = 0; oq < 4; ++oq) {
            sv[oq] += __shfl_xor(sv[oq], masks[mi]);
            qv[oq] += __shfl_xor(qv[oq], masks[mi]);
        }
    }
    if ((lane & 55) == 0) {  // lanes 0, 8
        int gb = (lane >> 3) & 1;
#pragma unroll
        for (int oq = 0; oq < 4; ++oq) {
            atomicAdd(&sred[oq * 2 + gb][0], sv[oq]);
            atomicAdd(&sred[oq * 2 + gb][1], qv[oq]);
        }
    }
    // store: D row = quad*4 + r (px), col = o
    const int pxb = x0 + wid * 16 + quad * 4;
    float* Yb = Y + ((size_t)(b * 32 + y) * 1024 + pxb) * 64;
#pragma unroll
    for (int oq = 0; oq < 4; ++oq) {
        const float av[4] = {acc[oq].x, acc[oq].y, acc[oq].z, acc[oq].w};
#pragma unroll
        for (int r = 0; r < 4; ++r) Yb[(size_t)r * 64 + oq * 16 + m] = av[r];
    }
    __syncthreads();
    if (tid < 16)
        atomicAdd(&stats2[(b * 8 + (tid >> 1)) * 2 + (tid & 1)], sred[tid >> 1][tid & 1]);
}

// ---------------- fused GN2-apply + GELU + rh3 head ----------------
__global__ __launch_bounds__(256) void rh3_kernel(
    const float* __restrict__ H2, const float* __restrict__ stats,
    const float* __restrict__ gamma, const float* __restrict__ beta, float inv_cnt,
    const float* __restrict__ w3, const float* __restrict__ b3,
    const float2* __restrict__ azsc,
    float2* __restrict__ refxy, float2* __restrict__ sigf) {
    const int tid = threadIdx.x;
    const int lane = tid & 15;
    const int m = blockIdx.x * 16 + (tid >> 4);
    const int b = m >> 15;
    const int c = lane * 4;
    const int g = c >> 3;
    float mean = stats[(b * 8 + g) * 2 + 0] * inv_cnt;
    float var = stats[(b * 8 + g) * 2 + 1] * inv_cnt - mean * mean;
    float rs = 1.0f / sqrtf(var + 1e-5f);
    float4 v = *(const float4*)(H2 + (size_t)m * 64 + c);
    float hv[4];
    hv[0] = gelu_f((v.x - mean) * rs * gamma[c + 0] + beta[c + 0]);
    hv[1] = gelu_f((v.y - mean) * rs * gamma[c + 1] + beta[c + 1]);
    hv[2] = gelu_f((v.z - mean) * rs * gamma[c + 2] + beta[c + 2]);
    hv[3] = gelu_f((v.w - mean) * rs * gamma[c + 3] + beta[c + 3]);
    float d0 = 0.f, d1 = 0.f;
#pragma unroll
    for (int k = 0; k < 4; ++k) {
        d0 += hv[k] * w3[(c + k) * 2 + 0];
        d1 += hv[k] * w3[(c + k) * 2 + 1];
    }
#pragma unroll
    for (int s = 1; s < 16; s <<= 1) {
        d0 += __shfl_xor(d0, s, 16);
        d1 += __shfl_xor(d1, s, 16);
    }
    if (lane == 0) {
        float mu = fminf(fmaxf(d0 + b3[0], 0.f), 55.f);
        float ls = fminf(fmaxf(d1 + b3[1], -5.f), 3.f);
        float sg = expf(ls);
        float2 sc = azsc[m & 1023];
        float rx = fminf(fmaxf(mu * sc.y * 0.01f + 0.5f, 0.f), 1.f);
        float ry = fminf(fmaxf(mu * sc.x * 0.01f + 0.5f, 0.f), 1.f);
        refxy[m] = make_float2(rx, ry);
        sigf[m] = make_float2(ls, 1.f / (sg + 1e-6f));
    }
}

// ---------------- MSDA bilinear sampling ----------------
__global__ __launch_bounds__(256) void msda_kernel(
    const float* __restrict__ V, const float2* __restrict__ refxy,
    const float* __restrict__ offs, const float* __restrict__ aw,
    float* __restrict__ out) {
    const int tid = threadIdx.x;
    const int l4 = tid & 3;         // dh quarter
    const int grp = tid >> 2;       // 0..63: 8 m x 8 heads
    const int m = blockIdx.x * 8 + (grp >> 3);
    const int head = grp & 7;
    const int b = m >> 15;
    float2 r = refxy[m];
    const float* lg = aw + (size_t)m * 48 + head * 6;
    float l[6];
#pragma unroll
    for (int p = 0; p < 6; ++p) l[p] = lg[p];
    float mx = l[0];
#pragma unroll
    for (int p = 1; p < 6; ++p) mx = fmaxf(mx, l[p]);
    float s = 0.f;
#pragma unroll
    for (int p = 0; p < 6; ++p) { l[p] = expf(l[p] - mx); s += l[p]; }
    float inv = 1.f / s;
#pragma unroll
    for (int p = 0; p < 6; ++p) l[p] *= inv;   // fold softmax into weights
    const float* of = offs + (size_t)m * 96 + head * 12;
    const float* Vb = V + (size_t)b * 40000 * 128 + head * 16 + l4 * 4;
    const float bx = r.x * 200.f - 0.5f;
    const float by = r.y * 200.f - 0.5f;
    f32x4 acc = (f32x4){0.f, 0.f, 0.f, 0.f};
#pragma unroll
    for (int p = 0; p < 6; ++p) {
        float px = bx + of[p * 2 + 0];
        float py = by + of[p * 2 + 1];
        float fx = floorf(px), fy = floorf(py);
        int x0 = (int)fx, y0 = (int)fy;
        float wx = px - fx, wy = py - fy;
        // clamped addresses (always in range); invalid corners get weight 0
        int xc0 = min(max(x0, 0), 199), xc1 = min(max(x0 + 1, 0), 199);
        int yc0 = min(max(y0, 0), 199), yc1 = min(max(y0 + 1, 0), 199);
        bool vx0 = ((unsigned)x0 < 200u), vx1 = ((unsigned)(x0 + 1) < 200u);
        bool vy0 = ((unsigned)y0 < 200u), vy1 = ((unsigned)(y0 + 1) < 200u);
        const f32x4 v00 = *(const f32x4*)(Vb + ((size_t)(yc0 * 200 + xc0)) * 128);
        const f32x4 v10 = *(const f32x4*)(Vb + ((size_t)(yc0 * 200 + xc1)) * 128);
        const f32x4 v01 = *(const f32x4*)(Vb + ((size_t)(yc1 * 200 + xc0)) * 128);
        const f32x4 v11 = *(const f32x4*)(Vb + ((size_t)(yc1 * 200 + xc1)) * 128);
        float w = l[p];
        float w00 = (vx0 && vy0) ? w * (1.f - wx) * (1.f - wy) : 0.f;
        float w10 = (vx1 && vy0) ? w * wx * (1.f - wy) : 0.f;
        float w01 = (vx0 && vy1) ? w * (1.f - wx) * wy : 0.f;
        float w11 = (vx1 && vy1) ? w * wx * wy : 0.f;
        acc += v00 * w00;
        acc += v10 * w10;
        acc += v01 * w01;
        acc += v11 * w11;
    }
    *(f32x4*)(out + (size_t)m * 128 + head * 16 + l4 * 4) = acc;
}

// ---------------- launch ----------------
extern "C" void kernel_launch(void* const* d_in, const int* in_sizes, int n_in,
                              void* d_out, int out_size, void* d_ws, size_t ws_size,
                              hipStream_t stream) {
    const float* x_rv = (const float*)d_in[0];
    const float* bev = (const float*)d_in[1];
    const float* pq_w = (const float*)d_in[2];
    const float* pq_b = (const float*)d_in[3];
    const float* pv_w = (const float*)d_in[4];
    const float* pv_b = (const float*)d_in[5];
    const float* po_w = (const float*)d_in[6];
    const float* po_b = (const float*)d_in[7];
    const float* qs_w1 = (const float*)d_in[8];
    const float* qs_b1 = (const float*)d_in[9];
    const float* qs_w2 = (const float*)d_in[10];
    const float* qs_b2 = (const float*)d_in[11];
    const float* rh_w1 = (const float*)d_in[12];
    const float* rh_b1 = (const float*)d_in[13];
    const float* rh_g1 = (const float*)d_in[14];
    const float* rh_be1 = (const float*)d_in[15];
    const float* rh_w2 = (const float*)d_in[16];
    const float* rh_g2 = (const float*)d_in[17];
    const float* rh_be2 = (const float*)d_in[18];
    const float* rh_w3 = (const float*)d_in[19];
    const float* rh_b3 = (const float*)d_in[20];
    const float* so_w = (const float*)d_in[21];
    const float* so_b = (const float*)d_in[22];
    const float* aw_w = (const float*)d_in[23];
    const float* aw_b = (const float*)d_in[24];
    const float* vp_w = (const float*)d_in[25];
    const float* vp_b = (const float*)d_in[26];
    const float* op_w = (const float*)d_in[27];
    const float* op_b = (const float*)d_in[28];

    const int M = 65536;

    float* ws = (float*)d_ws;
    float* azsc = ws;    ws += 2048;
    unsigned short* wvh = (unsigned short*)ws; ws += 16384;  // 8x8x64x8 bf16-hi frag-major
    unsigned short* wvl = (unsigned short*)ws; ws += 16384;  // 8x8x64x8 bf16-lo frag-major
    float* pvvp_b = ws;  ws += 128;
    float* oppo_w = ws;  ws += 128 * 128;
    float* oppo_b = ws;  ws += 128;
    float* pqqs_w = ws;  ws += 64 * 128;
    float* pqqs_b = ws;  ws += 128;
    float* qsso_w = ws;  ws += 128 * 96;
    float* qsso_b = ws;  ws += 128;
    float* qsaw_w = ws;  ws += 128 * 48;
    float* qsaw_b = ws;  ws += 64;
    float* stats = ws;   ws += 64;   // [0:32) GN1, [32:64) GN2
    unsigned short* wtb = (unsigned short*)ws;  ws += 36864;   // 73728 bf16
    unsigned short* h1b = (unsigned short*)ws;  ws += (size_t)M * 64;  // M*128 bf16
    float* Vv = ws;      ws += (size_t)80000 * 128;
    float* h1 = ws;      ws += (size_t)M * 128;
    float* h2 = ws;      ws += (size_t)M * 64;
    float* q1 = ws;      ws += (size_t)M * 128;
    float* refxy = ws;   ws += (size_t)M * 2;
    float* sigf = ws;    ws += (size_t)M * 2;
    size_t need_bytes = (size_t)(ws - (float*)d_ws) * sizeof(float);
    if (ws_size < need_bytes) return;
    float* offs = h1;   // h1 (raw rh1) dead after gn1_bf16
    float* attw = h2;   // h2 dead after rh3
    float* mo = q1;     // q1 dead after offs/attw GEMMs

    float2* azsc2 = (float2*)azsc;
    float2* refxy2 = (float2*)refxy;
    float2* sigf2 = (float2*)sigf;

    prep_weights<<<1293, 128, 0, stream>>>(
        pv_w, pv_b, vp_w, vp_b, op_w, op_b, po_w, po_b, pq_w, pq_b,
        qs_w1, qs_b1, qs_w2, qs_b2, so_w, so_b, aw_w, aw_b, rh_w2,
        wvh, wvl, pvvp_b, oppo_w, oppo_b, pqqs_w, pqqs_b,
        qsso_w, qsso_b, qsaw_w, qsaw_b, wtb, azsc2);
    hipMemsetAsync(stats, 0, 64 * sizeof(float), stream);

    // value = bev^T @ (pv_w@vp_w) + fused bias -- fused transpose+split+MFMA
    value_gemm_fused<<<dim3(625, 2), 256, 0, stream>>>(bev, wvh, wvl, pvvp_b, Vv);

    // h1 = raw rh1 (x_rv(+az) @ rh_w1 + b); fused GN1 stats
    gemm_v3<128, true><<<M / 128, 256, 0, stream>>>(
        x_rv, 64, rh_w1, rh_b1, h1, 64, azsc2, nullptr, rh_w1 + 64 * 128, 1, 0, stats);

    // GN1 apply + gelu -> bf16
    gn1_bf16<<<8192, 256, 0, stream>>>(h1, stats, rh_g1, rh_be1, h1b);

    // conv via bf16 MFMA; GN2 stats in epilogue
    conv3x3_mfma<<<dim3(16, 32, 2), 256, 0, stream>>>(h1b, wtb, h2, stats + 32);

    // fused GN2-apply + gelu + rh3 head
    rh3_kernel<<<4096, 256, 0, stream>>>(h2, stats + 32, rh_g2, rh_be2, 1.0f / 262144.0f,
                                         rh_w3, rh_b3, azsc2, refxy2, sigf2);

    // q1 = gelu(x_rv @ (pq_w@qs_w1a) + sigf extras + fused bias)
    gemm_v3<128, false><<<M / 128, 256, 0, stream>>>(
        x_rv, 64, pqqs_w, pqqs_b, q1, 64, nullptr, sigf, qs_w1 + 128 * 128, 2, 1, nullptr);

    // offs = q1 @ (qs_w2@so_w) + folded bias
    gemm_v3<96, false><<<M / 128, 192, 0, stream>>>(
        q1, 128, qsso_w, qsso_b, offs, 128, nullptr, nullptr, nullptr, 0, 0, nullptr);

    // attw logits = q1 @ (qs_w2@aw_w) + folded bias
    gemm_rn<128, 48, 192><<<M / 128, 192, 0, stream>>>(
        q1, 128, qsaw_w, 48, qsaw_b, attw, 48, 128);

    // MSDA sampling (into q1)
    msda_kernel<<<M / 8, 256, 0, stream>>>(Vv, refxy2, offs, attw, mo);

    // y = mo @ (op_w@po_w) + fused bias -> d_out
    gemm_v3<128, false><<<M / 128, 256, 0, stream>>>(
        mo, 128, oppo_w, oppo_b, (float*)d_out, 128, nullptr, nullptr, nullptr, 0, 0, nullptr);
}

// Round 9
// 397.096 us; speedup vs baseline: 1.3203x; 1.1696x over previous
//
#include <hip/hip_runtime.h>
#include <math.h>

#define PI_F 3.14159265358979323846f

// ---- static config ----
// B=2, HRV=32, WRV=1024, CRV=64; CB=256, HB=200, WB=200
// D=128, COUT=128, HEADS=8, POINTS=6, DH=16; M=65536, NV=40000
//
// Hard-won rules (rounds 1-14):
//  - value/output paths need ~fp32 ACCURACY, not fp32 ARITHMETIC: bf16x2
//    split (hi trunc, lo RNE residual; hh+hl+lh MFMA) ~2^-17 rel error.
//  - (round 7) msda: replicate softmax/addr math 4x not 16x; float4 loads.
//  - value-gemm walls, each HW-verified:
//    #1/#3 strided or 512B-lane-stride reads -> quarter-used 64B sectors ->
//       L2 sector ceiling (~34.5TB/s). Fix: fragment-major [tile][kc][lane][8]
//       layouts (frag load = base + lane*16B, round 11: 63 -> <47us).
//    #2 __syncthreads drains vmcnt(0) -> kills cross-chunk prefetch; use
//       raw s_barrier + lgkmcnt(0) (+sched_barrier fences) only.
//    #4 (round 13) 1 block/CU lockstep barriers = latency wall; 4-wave
//       blocks + small LDS so blocks interleave.
//  - (round 12) fuse transpose+split+GEMM: coalesced row staging -> LDS
//    pitch-70 fp32 (column b32 reads 2-way free: (8*70)%32=16), in-register
//    hi/lo split, double-buffer, 1 raw barrier/chunk, prefetch 2 ahead.
//  - (round 14) remaining fp32 VALU GEMMs (~120us est at ~54TF measured
//    eff) -> gemm_mf template: same verified pieces; q1 / offs+attw(dual,
//    shares q1 read) / y-final converted. rh1 stays fp32 (STATS epilogue,
//    known-good).
//  - top-5 counters masked by harness workspace-poison fills (327MB, 85%
//    HBM) -- judge by dur_us.

typedef __attribute__((ext_vector_type(8))) short bf16x8;
typedef __attribute__((ext_vector_type(4))) float f32x4;

__device__ __forceinline__ float gelu_f(float x) {
    return 0.5f * x * (1.0f + erff(x * 0.70710678118654752440f));
}

__device__ __forceinline__ unsigned short f2bf(float x) {
    unsigned int u = __float_as_uint(x);
    u += 0x7fffu + ((u >> 16) & 1u);  // RNE
    return (unsigned short)(u >> 16);
}

__device__ __forceinline__ float bf2f(unsigned short h) {
    return __uint_as_float((unsigned int)h << 16);
}

// frag-major offset for element (k, c) of a K x N weight: KC = K/32
__device__ __forceinline__ size_t fragoff(int k, int c, int KC, int tilebase) {
    return (((size_t)((tilebase + (c >> 4)) * KC + (k >> 5)) * 64) +
            ((k >> 3) & 3) * 16 + (c & 15)) * 8 + (k & 7);
}

// ---------------- fused weight prep (+ az table + bf16 conv weights) -------
// Emits ALL gemm weights in fragment-major bf16 hi/lo:
//   wv   : pv_w@vp_w   [k=256][d=128]  (value GEMM B)
//   wo   : op_w@po_w   [k=128][c=128]  (y-final B)
//   wq   : pq_w@qs_w1  [k=64][c=128]   (q1 B)
//   wa   : qs_w2@so_w | qs_w2@aw_w concat [k=128][c=144] (offs+attw dual B)
// plus fp32 biases, az table, conv wtb.
__global__ void prep_weights(const float* __restrict__ pv_w, const float* __restrict__ pv_b,
                             const float* __restrict__ vp_w, const float* __restrict__ vp_b,
                             const float* __restrict__ op_w, const float* __restrict__ op_b,
                             const float* __restrict__ po_w, const float* __restrict__ po_b,
                             const float* __restrict__ pq_w, const float* __restrict__ pq_b,
                             const float* __restrict__ qs_w1, const float* __restrict__ qs_b1,
                             const float* __restrict__ qs_w2, const float* __restrict__ qs_b2,
                             const float* __restrict__ so_w, const float* __restrict__ so_b,
                             const float* __restrict__ aw_w, const float* __restrict__ aw_b,
                             const float* __restrict__ rh_w2,
                             unsigned short* __restrict__ wvh, unsigned short* __restrict__ wvl,
                             float* __restrict__ pvvp_b,
                             unsigned short* __restrict__ woh, unsigned short* __restrict__ wol,
                             float* __restrict__ oppo_b,
                             unsigned short* __restrict__ wqh, unsigned short* __restrict__ wql,
                             float* __restrict__ pqqs_b,
                             unsigned short* __restrict__ wah, unsigned short* __restrict__ wal,
                             float* __restrict__ qab,
                             unsigned short* __restrict__ wtb,
                             float2* __restrict__ azsc) {
    int r = blockIdx.x;
    int d = threadIdx.x; // 0..127
    if (r < 256) {
        // value B: k = r, col = d, KC = 8
        float s = 0.f;
        for (int k = 0; k < 128; ++k) s += pv_w[r * 128 + k] * vp_w[k * 128 + d];
        unsigned short h = f2bf(s);
        size_t off = fragoff(r, d, 8, 0);
        wvh[off] = h;
        wvl[off] = f2bf(s - bf2f(h));
    } else if (r == 256) {
        float s = vp_b[d];
        for (int k = 0; k < 128; ++k) s += pv_b[k] * vp_w[k * 128 + d];
        pvvp_b[d] = s;
    } else if (r < 385) {
        // y-final B (op_w@po_w): k = rr, col = d, KC = 4
        int rr = r - 257;
        float s = 0.f;
        for (int k = 0; k < 128; ++k) s += op_w[rr * 128 + k] * po_w[k * 128 + d];
        unsigned short h = f2bf(s);
        size_t off = fragoff(rr, d, 4, 0);
        woh[off] = h;
        wol[off] = f2bf(s - bf2f(h));
    } else if (r == 385) {
        float s = po_b[d];
        for (int k = 0; k < 128; ++k) s += op_b[k] * po_w[k * 128 + d];
        oppo_b[d] = s;
    } else if (r < 450) {
        // q1 B (pq_w@qs_w1): k = rr (0..63), col = d, KC = 2
        int rr = r - 386;
        float s = 0.f;
        for (int k = 0; k < 128; ++k) s += pq_w[rr * 128 + k] * qs_w1[k * 128 + d];
        unsigned short h = f2bf(s);
        size_t off = fragoff(rr, d, 2, 0);
        wqh[off] = h;
        wql[off] = f2bf(s - bf2f(h));
    } else if (r == 450) {
        float s = qs_b1[d];
        for (int k = 0; k < 128; ++k) s += pq_b[k] * qs_w1[k * 128 + d];
        pqqs_b[d] = s;
    } else if (r < 459) {
        int w = (r - 451) * 128 + d;
        float az = -PI_F + (float)w * (6.283185307179586f / 1024.0f);
        azsc[w] = make_float2(sinf(az), cosf(az));
    } else if (r < 587) {
        // dual B, offs half (qs_w2@so_w): k = rr, col = d<96, tiles 0..5
        int rr = r - 459;
        if (d < 96) {
            float s = 0.f;
            for (int k = 0; k < 128; ++k) s += qs_w2[rr * 128 + k] * so_w[k * 96 + d];
            unsigned short h = f2bf(s);
            size_t off = fragoff(rr, d, 4, 0);
            wah[off] = h;
            wal[off] = f2bf(s - bf2f(h));
        }
    } else if (r == 587) {
        if (d < 96) {
            float s = so_b[d];
            for (int k = 0; k < 128; ++k) s += qs_b2[k] * so_w[k * 96 + d];
            qab[d] = s;
        }
    } else if (r < 716) {
        // dual B, attw half (qs_w2@aw_w): k = rr, col = d<48, tiles 6..8
        int rr = r - 588;
        if (d < 48) {
            float s = 0.f;
            for (int k = 0; k < 128; ++k) s += qs_w2[rr * 128 + k] * aw_w[k * 48 + d];
            unsigned short h = f2bf(s);
            size_t off = fragoff(rr, d, 4, 6);
            wah[off] = h;
            wal[off] = f2bf(s - bf2f(h));
        }
    } else if (r == 716) {
        if (d < 48) {
            float s = aw_b[d];
            for (int k = 0; k < 128; ++k) s += qs_b2[k] * aw_w[k * 48 + d];
            qab[96 + d] = s;
        }
    } else {
        // conv weights -> bf16, transposed: wtb[tap][cc4][o][ci]
        int idx = (r - 717) * 128 + d;   // 0 .. 73727
        int ci = idx & 31;
        int o = (idx >> 5) & 63;
        int cc4i = (idx >> 11) & 3;
        int tap = idx >> 13;
        float w = rh_w2[((size_t)tap * 128 + cc4i * 32 + ci) * 64 + o];
        wtb[idx] = f2bf(w);
    }
}

// ---------------- MT=128 GEMM, 8x8 micro, 2*NT threads (rh1 only) ----------
template <int NT, bool STATS>
__global__ __launch_bounds__(2 * NT) void gemm_v3(
    const float* __restrict__ A, int lda,
    const float* __restrict__ W,
    const float* __restrict__ bias,
    float* __restrict__ C, int K,
    const float2* __restrict__ azsc,
    const float* __restrict__ extra2,
    const float* __restrict__ extra_w,
    int emode, int do_gelu, float* __restrict__ stats1) {
    constexpr int NTH = 2 * NT;
    constexpr int NTO = NT / 8;
    __shared__ float As[32][140];   // 140 % 32 = 12 -> conflict-free scatter
    __shared__ float Ws[32][NT];
    __shared__ float sred[8][2];
    const int tid = threadIdx.x;
    const int tn = tid % NTO;
    const int tm = tid / NTO;   // 0..15
    const int m0 = blockIdx.x * 128;
    if (STATS && tid < 16) sred[tid >> 1][tid & 1] = 0.f;
    float acc[8][8];
#pragma unroll
    for (int i = 0; i < 8; ++i)
#pragma unroll
        for (int j = 0; j < 8; ++j) acc[i][j] = 0.f;

    for (int k0 = 0; k0 < K; k0 += 32) {
        __syncthreads();
        for (int f = tid; f < 1024; f += NTH) {
            int r = f >> 3, c4 = f & 7;
            float4 v = *(const float4*)(A + (size_t)(m0 + r) * lda + k0 + c4 * 4);
            As[c4 * 4 + 0][r] = v.x;
            As[c4 * 4 + 1][r] = v.y;
            As[c4 * 4 + 2][r] = v.z;
            As[c4 * 4 + 3][r] = v.w;
        }
        for (int f = tid; f < 8 * NT; f += NTH) {
            int kk = f / (NT / 4), n4 = f % (NT / 4);
            *(float4*)&Ws[kk][n4 * 4] = *(const float4*)(W + (size_t)(k0 + kk) * NT + n4 * 4);
        }
        __syncthreads();
#pragma unroll 2
        for (int k = 0; k < 32; ++k) {
            const float4 a0 = *(const float4*)&As[k][tm * 8];
            const float4 a1 = *(const float4*)&As[k][tm * 8 + 4];
            const float4 w0 = *(const float4*)&Ws[k][tn * 8];
            const float4 w1 = *(const float4*)&Ws[k][tn * 8 + 4];
            const float av[8] = {a0.x, a0.y, a0.z, a0.w, a1.x, a1.y, a1.z, a1.w};
            const float wv[8] = {w0.x, w0.y, w0.z, w0.w, w1.x, w1.y, w1.z, w1.w};
#pragma unroll
            for (int i = 0; i < 8; ++i)
#pragma unroll
                for (int j = 0; j < 8; ++j) acc[i][j] += av[i] * wv[j];
        }
    }
    float bv[8], e0w[8], e1w[8];
#pragma unroll
    for (int j = 0; j < 8; ++j) bv[j] = bias[tn * 8 + j];
    if (emode) {
#pragma unroll
        for (int j = 0; j < 8; ++j) {
            e0w[j] = extra_w[tn * 8 + j];
            e1w[j] = extra_w[NT + tn * 8 + j];
        }
    }
    float ts = 0.f, ts2 = 0.f;
#pragma unroll
    for (int i = 0; i < 8; ++i) {
        int m = m0 + tm * 8 + i;
        float e0 = 0.f, e1 = 0.f;
        if (emode == 1) {
            float2 sc = azsc[m & 1023];
            e0 = sc.x; e1 = sc.y;
        } else if (emode == 2) {
            e0 = extra2[2 * (size_t)m];
            e1 = extra2[2 * (size_t)m + 1];
        }
        float o[8];
#pragma unroll
        for (int j = 0; j < 8; ++j) {
            float v = acc[i][j] + bv[j];
            if (emode) v += e0 * e0w[j] + e1 * e1w[j];
            if (do_gelu) v = gelu_f(v);
            if (STATS) { ts += v; ts2 += v * v; }
            o[j] = v;
        }
        *(float4*)(C + (size_t)m * NT + tn * 8) = make_float4(o[0], o[1], o[2], o[3]);
        *(float4*)(C + (size_t)m * NT + tn * 8 + 4) = make_float4(o[4], o[5], o[6], o[7]);
    }
    if (STATS) {  // C=128, CPG=16: thread's 8 cols lie in group tn>>1
        atomicAdd(&sred[tn >> 1][0], ts);
        atomicAdd(&sred[tn >> 1][1], ts2);
        __syncthreads();
        if (tid < 8) {
            int b = m0 >> 15;
            atomicAdd(&stats1[(b * 8 + tid) * 2 + 0], sred[tid][0]);
            atomicAdd(&stats1[(b * 8 + tid) * 2 + 1], sred[tid][1]);
        }
    }
}

// ------------- generic fused-split MFMA GEMM (round 14) --------------------
// C = A @ B + bias (+sigf extras) (+gelu), A fp32 [M][K] row-major,
// B fragment-major bf16 hi/lo. Block: 256 thr / 4 waves, tile 64m x N,
// K-chunks of 32. A rows staged coalesced -> LDS [k][m] pitch 70 (scatter
// writes & column reads both 2-way free), in-register hi/lo split,
// double-buffered, ONE raw s_barrier + lgkmcnt(0) per chunk, prefetch 2
// ahead (verified value_gemm_fused structure). DUAL: cols 0..95 -> C1
// (offs), 96..143 -> C2 (attw).
template <int KC, int NJ, int EMODE, int GELU, int DUAL>
__global__ __launch_bounds__(256) void gemm_mf(
    const float* __restrict__ A,
    const unsigned short* __restrict__ Bh, const unsigned short* __restrict__ Bl,
    const float* __restrict__ bias,
    float* __restrict__ C1, float* __restrict__ C2,
    const float2* __restrict__ ex2, const float* __restrict__ exw) {
    constexpr int K = KC * 32;
    __shared__ __align__(16) float T0[32 * 70];
    __shared__ __align__(16) float T1[32 * 70];
    const int tid = threadIdx.x;
    const int wid = tid >> 6;
    const int lane = tid & 63;
    const int mm = lane & 15;
    const int quad = lane >> 4;
    const int m0 = blockIdx.x * 64;

    // staging: 2 float4/thread/chunk; rows m (64), k-octets (8)
    int srow[2], scol[2];
    const float* sp[2];
#pragma unroll
    for (int i = 0; i < 2; ++i) {
        int f = tid + i * 256;
        srow[i] = f >> 3;
        scol[i] = (f & 7) * 4;
        sp[i] = A + (size_t)(m0 + srow[i]) * K + scol[i];
    }

    f32x4 acc[NJ];
#pragma unroll
    for (int j = 0; j < NJ; ++j) acc[j] = (f32x4){0.f, 0.f, 0.f, 0.f};

    union UV { uint4 u; bf16x8 v; };
    float4 st[2];

#define LOADG(K0)                                                 \
    {                                                             \
        _Pragma("unroll")                                         \
        for (int i_ = 0; i_ < 2; ++i_)                            \
            st[i_] = *(const float4*)(sp[i_] + (K0));             \
    }
#define WRITELDS(TB)                                              \
    {                                                             \
        _Pragma("unroll")                                         \
        for (int i_ = 0; i_ < 2; ++i_) {                          \
            _Pragma("unroll")                                     \
            for (int c_ = 0; c_ < 4; ++c_)                        \
                (TB)[(scol[i_] + c_) * 70 + srow[i_]] = st[i_][c_]; \
        }                                                         \
    }
#define BARRIER()                                                 \
    asm volatile("s_waitcnt lgkmcnt(0)" ::: "memory");            \
    __builtin_amdgcn_sched_barrier(0);                            \
    __builtin_amdgcn_s_barrier();                                 \
    __builtin_amdgcn_sched_barrier(0);

    float* Tc = T0;
    float* Tn = T1;
    LOADG(0);
    WRITELDS(Tc);
    if (KC > 1) LOADG(32);
    BARRIER();

#pragma unroll
    for (int t = 0; t < KC; ++t) {
        // A fragment: column read from Tc + in-register hi/lo split
        bf16x8 ah, al;
        {
            const int nc = wid * 16 + mm;
            float f8[8];
#pragma unroll
            for (int jj = 0; jj < 8; ++jj)
                f8[jj] = Tc[(quad * 8 + jj) * 70 + nc];
            unsigned hh[4], ll[4];
#pragma unroll
            for (int q = 0; q < 4; ++q) {
                unsigned u0 = __float_as_uint(f8[2 * q]);
                unsigned u1 = __float_as_uint(f8[2 * q + 1]);
                hh[q] = __builtin_amdgcn_perm(u1, u0, 0x07060302);  // trunc pair
                float l0 = f8[2 * q] - __uint_as_float(u0 & 0xffff0000u);
                float l1 = f8[2 * q + 1] - __uint_as_float(u1 & 0xffff0000u);
                asm("v_cvt_pk_bf16_f32 %0, %1, %2" : "=v"(ll[q]) : "v"(l0), "v"(l1));
            }
            UV th, tl;
            th.u = make_uint4(hh[0], hh[1], hh[2], hh[3]);
            tl.u = make_uint4(ll[0], ll[1], ll[2], ll[3]);
            ah = th.v;
            al = tl.v;
        }
        if (t < KC - 1) WRITELDS(Tn);
        if (t < KC - 2) LOADG((t + 2) * 32);
        // B fragments (fragment-major, L2-resident)
        bf16x8 bh[NJ], bl[NJ];
#pragma unroll
        for (int j = 0; j < NJ; ++j) {
            size_t o = ((size_t)(j * KC + t) * 64 + lane) * 8;
            bh[j] = *(const bf16x8*)(Bh + o);
            bl[j] = *(const bf16x8*)(Bl + o);
        }
#pragma unroll
        for (int j = 0; j < NJ; ++j) {
            acc[j] = __builtin_amdgcn_mfma_f32_16x16x32_bf16(ah, bh[j], acc[j], 0, 0, 0);
            acc[j] = __builtin_amdgcn_mfma_f32_16x16x32_bf16(ah, bl[j], acc[j], 0, 0, 0);
            acc[j] = __builtin_amdgcn_mfma_f32_16x16x32_bf16(al, bh[j], acc[j], 0, 0, 0);
        }
        if (t < KC - 1) {
            BARRIER();
            float* tmp = Tc; Tc = Tn; Tn = tmp;
        }
    }
#undef LOADG
#undef WRITELDS
#undef BARRIER
    // epilogue: D row (m) = quad*4 + r, col = j*16 + mm
    float bvj[NJ];
#pragma unroll
    for (int j = 0; j < NJ; ++j) bvj[j] = bias[j * 16 + mm];
    float2 ev[4];
    float e0w[NJ], e1w[NJ];
    if (EMODE) {
#pragma unroll
        for (int r = 0; r < 4; ++r) ev[r] = ex2[m0 + wid * 16 + quad * 4 + r];
#pragma unroll
        for (int j = 0; j < NJ; ++j) {
            e0w[j] = exw[j * 16 + mm];
            e1w[j] = exw[128 + j * 16 + mm];
        }
    }
#pragma unroll
    for (int j = 0; j < NJ; ++j) {
        float* Cp;
        int col, ldc;
        if (DUAL && j >= 6) {
            Cp = C2; col = (j - 6) * 16 + mm; ldc = 48;
        } else {
            Cp = C1; col = j * 16 + mm; ldc = DUAL ? 96 : NJ * 16;
        }
#pragma unroll
        for (int r = 0; r < 4; ++r) {
            int row = m0 + wid * 16 + quad * 4 + r;
            float v = acc[j][r] + bvj[j];
            if (EMODE) v += ev[r].x * e0w[j] + ev[r].y * e1w[j];
            if (GELU) v = gelu_f(v);
            Cp[(size_t)row * ldc + col] = v;
        }
    }
}

// ------------- fused value GEMM: transpose + split + MFMA ------------------
__global__ __launch_bounds__(256) void value_gemm_fused(
    const float* __restrict__ bev,
    const unsigned short* __restrict__ Wh, const unsigned short* __restrict__ Wl,
    const float* __restrict__ bf, float* __restrict__ V) {
    __shared__ __align__(16) float T0[32 * 70];
    __shared__ __align__(16) float T1[32 * 70];
    const int tid = threadIdx.x;
    const int wid = tid >> 6;
    const int lane = tid & 63;
    const int m = lane & 15;
    const int quad = lane >> 4;
    const int n0 = blockIdx.x * 64;
    const int b = blockIdx.y;
    const int wn = wid >> 1;          // 0..1: n-group of 32
    const int wd = wid & 1;           // 0..1: d-group of 64
    const float* src = bev + (size_t)b * 256 * 40000;

    int srow[2], scol[2];
    const float* sp[2];
#pragma unroll
    for (int i = 0; i < 2; ++i) {
        int f = tid + i * 256;
        srow[i] = f >> 4;
        scol[i] = (f & 15) * 4;
        sp[i] = src + n0 + scol[i];
    }

    f32x4 acc[2][4];
#pragma unroll
    for (int i = 0; i < 2; ++i)
#pragma unroll
        for (int j = 0; j < 4; ++j) acc[i][j] = (f32x4){0.f, 0.f, 0.f, 0.f};

    const int dt0 = wd * 4;
    size_t bb[4];
#pragma unroll
    for (int j = 0; j < 4; ++j) bb[j] = (size_t)(dt0 + j) * 4096 + lane * 8;

    union UV { uint4 u; bf16x8 v; };
    float4 st[2];

#define LOADG(K0)                                                           \
    {                                                                       \
        _Pragma("unroll")                                                   \
        for (int i_ = 0; i_ < 2; ++i_)                                      \
            st[i_] = *(const float4*)(sp[i_] + (size_t)((K0) + srow[i_]) * 40000); \
    }
#define WRITELDS(TB)                                                        \
    {                                                                       \
        _Pragma("unroll")                                                   \
        for (int i_ = 0; i_ < 2; ++i_) {                                    \
            float* d_ = (TB) + srow[i_] * 70 + scol[i_];                    \
            *(float2*)(d_ + 0) = make_float2(st[i_].x, st[i_].y);           \
            *(float2*)(d_ + 2) = make_float2(st[i_].z, st[i_].w);           \
        }                                                                   \
    }

    float* Tc = T0;
    float* Tn = T1;
    LOADG(0);
    WRITELDS(Tc);
    LOADG(32);
    asm volatile("s_waitcnt lgkmcnt(0)" ::: "memory");
    __builtin_amdgcn_sched_barrier(0);
    __builtin_amdgcn_s_barrier();
    __builtin_amdgcn_sched_barrier(0);

    for (int t = 0; t < 8; ++t) {
        bf16x8 ah[2], al[2];
#pragma unroll
        for (int i = 0; i < 2; ++i) {
            const int nc = wn * 32 + i * 16 + m;
            float f8[8];
#pragma unroll
            for (int jj = 0; jj < 8; ++jj)
                f8[jj] = Tc[(quad * 8 + jj) * 70 + nc];
            unsigned hh[4], ll[4];
#pragma unroll
            for (int q = 0; q < 4; ++q) {
                unsigned u0 = __float_as_uint(f8[2 * q]);
                unsigned u1 = __float_as_uint(f8[2 * q + 1]);
                hh[q] = __builtin_amdgcn_perm(u1, u0, 0x07060302);  // trunc pair
                float l0 = f8[2 * q] - __uint_as_float(u0 & 0xffff0000u);
                float l1 = f8[2 * q + 1] - __uint_as_float(u1 & 0xffff0000u);
                asm("v_cvt_pk_bf16_f32 %0, %1, %2" : "=v"(ll[q]) : "v"(l0), "v"(l1));
            }
            UV th, tl;
            th.u = make_uint4(hh[0], hh[1], hh[2], hh[3]);
            tl.u = make_uint4(ll[0], ll[1], ll[2], ll[3]);
            ah[i] = th.v;
            al[i] = tl.v;
        }
        if (t < 7) WRITELDS(Tn);
        if (t < 6) LOADG(t * 32 + 64);
        bf16x8 bh[4], bl[4];
#pragma unroll
        for (int j = 0; j < 4; ++j) {
            bh[j] = *(const bf16x8*)(Wh + bb[j] + t * 512);
            bl[j] = *(const bf16x8*)(Wl + bb[j] + t * 512);
        }
#pragma unroll
        for (int i = 0; i < 2; ++i)
#pragma unroll
            for (int j = 0; j < 4; ++j) {
                acc[i][j] = __builtin_amdgcn_mfma_f32_16x16x32_bf16(ah[i], bh[j], acc[i][j], 0, 0, 0);
                acc[i][j] = __builtin_amdgcn_mfma_f32_16x16x32_bf16(ah[i], bl[j], acc[i][j], 0, 0, 0);
                acc[i][j] = __builtin_amdgcn_mfma_f32_16x16x32_bf16(al[i], bh[j], acc[i][j], 0, 0, 0);
            }
        if (t < 7) {
            asm volatile("s_waitcnt lgkmcnt(0)" ::: "memory");
            __builtin_amdgcn_sched_barrier(0);
            __builtin_amdgcn_s_barrier();
            __builtin_amdgcn_sched_barrier(0);
            float* tmp = Tc; Tc = Tn; Tn = tmp;
        }
    }
#undef LOADG
#undef WRITELDS
    float bv[4];
#pragma unroll
    for (int j = 0; j < 4; ++j) bv[j] = bf[wd * 64 + j * 16 + m];
#pragma unroll
    for (int i = 0; i < 2; ++i) {
        int nbase = n0 + wn * 32 + i * 16 + quad * 4;
#pragma unroll
        for (int r = 0; r < 4; ++r) {
            int n = nbase + r;
            float* vp = V + ((size_t)b * 40000 + n) * 128 + wd * 64 + m;
#pragma unroll
            for (int j = 0; j < 4; ++j) vp[j * 16] = acc[i][j][r] + bv[j];
        }
    }
}

// ---------------- GN1 apply + GELU -> bf16 ----------------
__global__ __launch_bounds__(256) void gn1_bf16(
    const float* __restrict__ X, const float* __restrict__ stats,
    const float* __restrict__ g1, const float* __restrict__ be1,
    unsigned short* __restrict__ Ob) {
    size_t i4 = (size_t)blockIdx.x * 256 + threadIdx.x;
    size_t base = i4 * 4;
    int c = (int)(base & 127);
    int mrow = (int)(base >> 7);
    int b = mrow >> 15;
    int g = c >> 4;
    float mean = stats[(b * 8 + g) * 2 + 0] * (1.0f / 524288.0f);
    float var = stats[(b * 8 + g) * 2 + 1] * (1.0f / 524288.0f) - mean * mean;
    float rs = 1.0f / sqrtf(var + 1e-5f);
    float4 x = *(const float4*)(X + base);
    float4 gm = *(const float4*)(g1 + c);
    float4 bt = *(const float4*)(be1 + c);
    ushort4 o;
    o.x = f2bf(gelu_f((x.x - mean) * rs * gm.x + bt.x));
    o.y = f2bf(gelu_f((x.y - mean) * rs * gm.y + bt.y));
    o.z = f2bf(gelu_f((x.z - mean) * rs * gm.z + bt.z));
    o.w = f2bf(gelu_f((x.w - mean) * rs * gm.w + bt.w));
    *(ushort4*)(Ob + base) = o;
}

// ---------------- 3x3 circular conv via bf16 MFMA ----------------
__global__ __launch_bounds__(256, 4) void conv3x3_mfma(
    const unsigned short* __restrict__ H1b,  // [2][32][1024][128] bf16
    const unsigned short* __restrict__ Wtb,  // [9][4][64][32] bf16
    float* __restrict__ Y,                   // [2][32][1024][64]
    float* __restrict__ stats2) {
    __shared__ short As_s[66 * 40];      // [xx][ci_chunk] 5.2 KB
    __shared__ short Ws_s[3 * 64 * 40];  // [dx][o][ci_chunk] 15.4 KB
    __shared__ float sred[8][2];
    const int tid = threadIdx.x;
    const int wid = tid >> 6;
    const int lane = tid & 63;
    const int m = lane & 15;
    const int quad = lane >> 4;
    const int x0 = blockIdx.x * 64;
    const int y = blockIdx.y;
    const int b = blockIdx.z;
    if (tid < 16) sred[tid >> 1][tid & 1] = 0.f;
    f32x4 acc[4];
#pragma unroll
    for (int oq = 0; oq < 4; ++oq) acc[oq] = (f32x4){0.f, 0.f, 0.f, 0.f};

    const unsigned short* Hb = H1b + (size_t)b * 32 * 1024 * 128;
    for (int ry = 0; ry < 3; ++ry) {
        const int gy = (y + ry + 31) & 31;
        const unsigned short* Hrow = Hb + (size_t)gy * 1024 * 128;
        for (int cc4 = 0; cc4 < 4; ++cc4) {
            __syncthreads();
            // A: 66 xx-rows x 4 octets of 8 bf16 = 264 16B chunks
            for (int f = tid; f < 264; f += 256) {
                int xx = f >> 2, cq = f & 3;
                int gx = (x0 + xx + 1023) & 1023;
                uint4 v = *(const uint4*)(Hrow + (size_t)gx * 128 + cc4 * 32 + cq * 8);
                *(uint4*)&As_s[xx * 40 + cq * 8] = v;
            }
            // W: 3 dx x 64 o x 4 octets = 768 16B chunks
            for (int f = tid; f < 768; f += 256) {
                int cq = f & 3, o = (f >> 2) & 63, dx = f >> 8;
                int tap = ry * 3 + dx;
                uint4 v = *(const uint4*)(Wtb + ((size_t)(tap * 4 + cc4) * 64 + o) * 32 + cq * 8);
                *(uint4*)&Ws_s[(dx * 64 + o) * 40 + cq * 8] = v;
            }
            __syncthreads();
            const int arow = wid * 16 + m;
#pragma unroll
            for (int dx = 0; dx < 3; ++dx) {
                bf16x8 a = *(const bf16x8*)&As_s[(arow + dx) * 40 + quad * 8];
#pragma unroll
                for (int oq = 0; oq < 4; ++oq) {
                    bf16x8 bfr = *(const bf16x8*)&Ws_s[(dx * 64 + oq * 16 + m) * 40 + quad * 8];
                    acc[oq] = __builtin_amdgcn_mfma_f32_16x16x32_bf16(a, bfr, acc[oq], 0, 0, 0);
                }
            }
        }
    }
    // GN2 stats: lane's frag oq covers o = oq*16 + m -> group oq*2 + (m>>3)
    float sv[4], qv[4];
#pragma unroll
    for (int oq = 0; oq < 4; ++oq) {
        sv[oq] = acc[oq].x + acc[oq].y + acc[oq].z + acc[oq].w;
        qv[oq] = acc[oq].x * acc[oq].x + acc[oq].y * acc[oq].y +
                 acc[oq].z * acc[oq].z + acc[oq].w * acc[oq].w;
    }
    const int masks[5] = {1, 2, 4, 16, 32};  // reduce over all but bit3
#pragma unroll
    for (int mi = 0; mi < 5; ++mi) {
#pragma unroll
        for (int oq = 0; oq < 4; ++oq) {
            sv[oq] += __shfl_xor(sv[oq], masks[mi]);
            qv[oq] += __shfl_xor(qv[oq], masks[mi]);
        }
    }
    if ((lane & 55) == 0) {  // lanes 0, 8
        int gb = (lane >> 3) & 1;
#pragma unroll
        for (int oq = 0; oq < 4; ++oq) {
            atomicAdd(&sred[oq * 2 + gb][0], sv[oq]);
            atomicAdd(&sred[oq * 2 + gb][1], qv[oq]);
        }
    }
    // store: D row = quad*4 + r (px), col = o
    const int pxb = x0 + wid * 16 + quad * 4;
    float* Yb = Y + ((size_t)(b * 32 + y) * 1024 + pxb) * 64;
#pragma unroll
    for (int oq = 0; oq < 4; ++oq) {
        const float av[4] = {acc[oq].x, acc[oq].y, acc[oq].z, acc[oq].w};
#pragma unroll
        for (int r = 0; r < 4; ++r) Yb[(size_t)r * 64 + oq * 16 + m] = av[r];
    }
    __syncthreads();
    if (tid < 16)
        atomicAdd(&stats2[(b * 8 + (tid >> 1)) * 2 + (tid & 1)], sred[tid >> 1][tid & 1]);
}

// ---------------- fused GN2-apply + GELU + rh3 head ----------------
__global__ __launch_bounds__(256) void rh3_kernel(
    const float* __restrict__ H2, const float* __restrict__ stats,
    const float* __restrict__ gamma, const float* __restrict__ beta, float inv_cnt,
    const float* __restrict__ w3, const float* __restrict__ b3,
    const float2* __restrict__ azsc,
    float2* __restrict__ refxy, float2* __restrict__ sigf) {
    const int tid = threadIdx.x;
    const int lane = tid & 15;
    const int m = blockIdx.x * 16 + (tid >> 4);
    const int b = m >> 15;
    const int c = lane * 4;
    const int g = c >> 3;
    float mean = stats[(b * 8 + g) * 2 + 0] * inv_cnt;
    float var = stats[(b * 8 + g) * 2 + 1] * inv_cnt - mean * mean;
    float rs = 1.0f / sqrtf(var + 1e-5f);
    float4 v = *(const float4*)(H2 + (size_t)m * 64 + c);
    float hv[4];
    hv[0] = gelu_f((v.x - mean) * rs * gamma[c + 0] + beta[c + 0]);
    hv[1] = gelu_f((v.y - mean) * rs * gamma[c + 1] + beta[c + 1]);
    hv[2] = gelu_f((v.z - mean) * rs * gamma[c + 2] + beta[c + 2]);
    hv[3] = gelu_f((v.w - mean) * rs * gamma[c + 3] + beta[c + 3]);
    float d0 = 0.f, d1 = 0.f;
#pragma unroll
    for (int k = 0; k < 4; ++k) {
        d0 += hv[k] * w3[(c + k) * 2 + 0];
        d1 += hv[k] * w3[(c + k) * 2 + 1];
    }
#pragma unroll
    for (int s = 1; s < 16; s <<= 1) {
        d0 += __shfl_xor(d0, s, 16);
        d1 += __shfl_xor(d1, s, 16);
    }
    if (lane == 0) {
        float mu = fminf(fmaxf(d0 + b3[0], 0.f), 55.f);
        float ls = fminf(fmaxf(d1 + b3[1], -5.f), 3.f);
        float sg = expf(ls);
        float2 sc = azsc[m & 1023];
        float rx = fminf(fmaxf(mu * sc.y * 0.01f + 0.5f, 0.f), 1.f);
        float ry = fminf(fmaxf(mu * sc.x * 0.01f + 0.5f, 0.f), 1.f);
        refxy[m] = make_float2(rx, ry);
        sigf[m] = make_float2(ls, 1.f / (sg + 1e-6f));
    }
}

// ---------------- MSDA bilinear sampling ----------------
__global__ __launch_bounds__(256) void msda_kernel(
    const float* __restrict__ V, const float2* __restrict__ refxy,
    const float* __restrict__ offs, const float* __restrict__ aw,
    float* __restrict__ out) {
    const int tid = threadIdx.x;
    const int l4 = tid & 3;         // dh quarter
    const int grp = tid >> 2;       // 0..63: 8 m x 8 heads
    const int m = blockIdx.x * 8 + (grp >> 3);
    const int head = grp & 7;
    const int b = m >> 15;
    float2 r = refxy[m];
    const float* lg = aw + (size_t)m * 48 + head * 6;
    float l[6];
#pragma unroll
    for (int p = 0; p < 6; ++p) l[p] = lg[p];
    float mx = l[0];
#pragma unroll
    for (int p = 1; p < 6; ++p) mx = fmaxf(mx, l[p]);
    float s = 0.f;
#pragma unroll
    for (int p = 0; p < 6; ++p) { l[p] = expf(l[p] - mx); s += l[p]; }
    float inv = 1.f / s;
#pragma unroll
    for (int p = 0; p < 6; ++p) l[p] *= inv;   // fold softmax into weights
    const float* of = offs + (size_t)m * 96 + head * 12;
    const float* Vb = V + (size_t)b * 40000 * 128 + head * 16 + l4 * 4;
    const float bx = r.x * 200.f - 0.5f;
    const float by = r.y * 200.f - 0.5f;
    f32x4 acc = (f32x4){0.f, 0.f, 0.f, 0.f};
#pragma unroll
    for (int p = 0; p < 6; ++p) {
        float px = bx + of[p * 2 + 0];
        float py = by + of[p * 2 + 1];
        float fx = floorf(px), fy = floorf(py);
        int x0 = (int)fx, y0 = (int)fy;
        float wx = px - fx, wy = py - fy;
        // clamped addresses (always in range); invalid corners get weight 0
        int xc0 = min(max(x0, 0), 199), xc1 = min(max(x0 + 1, 0), 199);
        int yc0 = min(max(y0, 0), 199), yc1 = min(max(y0 + 1, 0), 199);
        bool vx0 = ((unsigned)x0 < 200u), vx1 = ((unsigned)(x0 + 1) < 200u);
        bool vy0 = ((unsigned)y0 < 200u), vy1 = ((unsigned)(y0 + 1) < 200u);
        const f32x4 v00 = *(const f32x4*)(Vb + ((size_t)(yc0 * 200 + xc0)) * 128);
        const f32x4 v10 = *(const f32x4*)(Vb + ((size_t)(yc0 * 200 + xc1)) * 128);
        const f32x4 v01 = *(const f32x4*)(Vb + ((size_t)(yc1 * 200 + xc0)) * 128);
        const f32x4 v11 = *(const f32x4*)(Vb + ((size_t)(yc1 * 200 + xc1)) * 128);
        float w = l[p];
        float w00 = (vx0 && vy0) ? w * (1.f - wx) * (1.f - wy) : 0.f;
        float w10 = (vx1 && vy0) ? w * wx * (1.f - wy) : 0.f;
        float w01 = (vx0 && vy1) ? w * (1.f - wx) * wy : 0.f;
        float w11 = (vx1 && vy1) ? w * wx * wy : 0.f;
        acc += v00 * w00;
        acc += v10 * w10;
        acc += v01 * w01;
        acc += v11 * w11;
    }
    *(f32x4*)(out + (size_t)m * 128 + head * 16 + l4 * 4) = acc;
}

// ---------------- launch ----------------
extern "C" void kernel_launch(void* const* d_in, const int* in_sizes, int n_in,
                              void* d_out, int out_size, void* d_ws, size_t ws_size,
                              hipStream_t stream) {
    const float* x_rv = (const float*)d_in[0];
    const float* bev = (const float*)d_in[1];
    const float* pq_w = (const float*)d_in[2];
    const float* pq_b = (const float*)d_in[3];
    const float* pv_w = (const float*)d_in[4];
    const float* pv_b = (const float*)d_in[5];
    const float* po_w = (const float*)d_in[6];
    const float* po_b = (const float*)d_in[7];
    const float* qs_w1 = (const float*)d_in[8];
    const float* qs_b1 = (const float*)d_in[9];
    const float* qs_w2 = (const float*)d_in[10];
    const float* qs_b2 = (const float*)d_in[11];
    const float* rh_w1 = (const float*)d_in[12];
    const float* rh_b1 = (const float*)d_in[13];
    const float* rh_g1 = (const float*)d_in[14];
    const float* rh_be1 = (const float*)d_in[15];
    const float* rh_w2 = (const float*)d_in[16];
    const float* rh_g2 = (const float*)d_in[17];
    const float* rh_be2 = (const float*)d_in[18];
    const float* rh_w3 = (const float*)d_in[19];
    const float* rh_b3 = (const float*)d_in[20];
    const float* so_w = (const float*)d_in[21];
    const float* so_b = (const float*)d_in[22];
    const float* aw_w = (const float*)d_in[23];
    const float* aw_b = (const float*)d_in[24];
    const float* vp_w = (const float*)d_in[25];
    const float* vp_b = (const float*)d_in[26];
    const float* op_w = (const float*)d_in[27];
    const float* op_b = (const float*)d_in[28];

    const int M = 65536;

    float* ws = (float*)d_ws;
    float* azsc = ws;    ws += 2048;
    unsigned short* wvh = (unsigned short*)ws; ws += 16384;  // 256x128 frag-major hi
    unsigned short* wvl = (unsigned short*)ws; ws += 16384;
    float* pvvp_b = ws;  ws += 128;
    unsigned short* woh = (unsigned short*)ws; ws += 8192;   // 128x128 frag-major hi
    unsigned short* wol = (unsigned short*)ws; ws += 8192;
    float* oppo_b = ws;  ws += 128;
    unsigned short* wqh = (unsigned short*)ws; ws += 4096;   // 64x128 frag-major hi
    unsigned short* wql = (unsigned short*)ws; ws += 4096;
    float* pqqs_b = ws;  ws += 128;
    unsigned short* wah = (unsigned short*)ws; ws += 9216;   // 128x144 frag-major hi
    unsigned short* wal = (unsigned short*)ws; ws += 9216;
    float* qab = ws;     ws += 144;
    float* stats = ws;   ws += 64;   // [0:32) GN1, [32:64) GN2
    unsigned short* wtb = (unsigned short*)ws;  ws += 36864;   // 73728 bf16
    unsigned short* h1b = (unsigned short*)ws;  ws += (size_t)M * 64;  // M*128 bf16
    float* Vv = ws;      ws += (size_t)80000 * 128;
    float* h1 = ws;      ws += (size_t)M * 128;
    float* h2 = ws;      ws += (size_t)M * 64;
    float* q1 = ws;      ws += (size_t)M * 128;
    float* refxy = ws;   ws += (size_t)M * 2;
    float* sigf = ws;    ws += (size_t)M * 2;
    size_t need_bytes = (size_t)(ws - (float*)d_ws) * sizeof(float);
    if (ws_size < need_bytes) return;
    float* offs = h1;   // h1 (raw rh1) dead after gn1_bf16
    float* attw = h2;   // h2 dead after rh3
    float* mo = q1;     // q1 dead after offs/attw GEMM

    float2* azsc2 = (float2*)azsc;
    float2* refxy2 = (float2*)refxy;
    float2* sigf2 = (float2*)sigf;

    prep_weights<<<1293, 128, 0, stream>>>(
        pv_w, pv_b, vp_w, vp_b, op_w, op_b, po_w, po_b, pq_w, pq_b,
        qs_w1, qs_b1, qs_w2, qs_b2, so_w, so_b, aw_w, aw_b, rh_w2,
        wvh, wvl, pvvp_b, woh, wol, oppo_b, wqh, wql, pqqs_b,
        wah, wal, qab, wtb, azsc2);
    hipMemsetAsync(stats, 0, 64 * sizeof(float), stream);

    // value = bev^T @ (pv_w@vp_w) + fused bias -- fused transpose+split+MFMA
    value_gemm_fused<<<dim3(625, 2), 256, 0, stream>>>(bev, wvh, wvl, pvvp_b, Vv);

    // h1 = raw rh1 (x_rv(+az) @ rh_w1 + b); fused GN1 stats (fp32, STATS)
    gemm_v3<128, true><<<M / 128, 256, 0, stream>>>(
        x_rv, 64, rh_w1, rh_b1, h1, 64, azsc2, nullptr, rh_w1 + 64 * 128, 1, 0, stats);

    // GN1 apply + gelu -> bf16
    gn1_bf16<<<8192, 256, 0, stream>>>(h1, stats, rh_g1, rh_be1, h1b);

    // conv via bf16 MFMA; GN2 stats in epilogue
    conv3x3_mfma<<<dim3(16, 32, 2), 256, 0, stream>>>(h1b, wtb, h2, stats + 32);

    // fused GN2-apply + gelu + rh3 head
    rh3_kernel<<<4096, 256, 0, stream>>>(h2, stats + 32, rh_g2, rh_be2, 1.0f / 262144.0f,
                                         rh_w3, rh_b3, azsc2, refxy2, sigf2);

    // q1 = gelu(x_rv @ (pq_w@qs_w1a) + sigf extras + bias) -- split MFMA
    gemm_mf<2, 8, 1, 1, 0><<<M / 64, 256, 0, stream>>>(
        x_rv, wqh, wql, pqqs_b, q1, nullptr, sigf2, qs_w1 + 128 * 128);

    // offs (96) + attw logits (48) = q1 @ concat-B, dual output -- split MFMA
    gemm_mf<4, 9, 0, 0, 1><<<M / 64, 256, 0, stream>>>(
        q1, wah, wal, qab, offs, attw, nullptr, nullptr);

    // MSDA sampling (into q1)
    msda_kernel<<<M / 8, 256, 0, stream>>>(Vv, refxy2, offs, attw, mo);

    // y = mo @ (op_w@po_w) + fused bias -> d_out -- split MFMA
    gemm_mf<4, 8, 0, 0, 0><<<M / 64, 256, 0, stream>>>(
        mo, woh, wol, oppo_b, (float*)d_out, nullptr, nullptr, nullptr);
}

// Round 10
// 388.994 us; speedup vs baseline: 1.3478x; 1.0208x over previous
//
#include <hip/hip_runtime.h>
#include <math.h>

#define PI_F 3.14159265358979323846f

// ---- static config ----
// B=2, HRV=32, WRV=1024, CRV=64; CB=256, HB=200, WB=200
// D=128, COUT=128, HEADS=8, POINTS=6, DH=16; M=65536, NV=40000
//
// Hard-won rules (rounds 1-15):
//  - value/output paths need ~fp32 ACCURACY, not fp32 ARITHMETIC: bf16x2
//    split (hi trunc, lo RNE residual; hh+hl+lh MFMA) ~2^-17 rel error.
//    Round 14 confirmed: q1/offs/attw/y converted, absmax unchanged.
//  - (round 7) msda: replicate softmax/addr math 4x not 16x; float4 loads.
//  - GEMM walls, each HW-verified:
//    #1/#3 strided or 512B-lane-stride reads -> quarter-used 64B sectors ->
//       L2 sector ceiling. Fix: fragment-major [tile][kc][lane][8] layouts.
//    #2 __syncthreads drains vmcnt(0) -> kills cross-chunk prefetch.
//    #4 (round 13) barrier lockstep = latency wall even with raw barriers;
//       round 15: make waves INDEPENDENT (private LDS transpose buffer,
//       producer==consumer wave -> zero barriers, compiler lgkmcnt orders).
//  - (round 12) fuse transpose+split+GEMM; LDS pitch chosen so column b32
//    reads are 2-way (free): pitch 70 for 64-wide, 34 for 32-wide.
//  - (round 14) gemm_mf template (verified): A fp32 staged->LDS->split,
//    B frag-major; round 15 adds STATS epilogue (rh1 GN1 stats) -> all five
//    fp32 VALU GEMMs now MFMA.
//  - top-5 counters masked by harness workspace-poison fills (327MB, 85%
//    HBM) -- judge by dur_us.

typedef __attribute__((ext_vector_type(8))) short bf16x8;
typedef __attribute__((ext_vector_type(4))) float f32x4;

__device__ __forceinline__ float gelu_f(float x) {
    return 0.5f * x * (1.0f + erff(x * 0.70710678118654752440f));
}

__device__ __forceinline__ unsigned short f2bf(float x) {
    unsigned int u = __float_as_uint(x);
    u += 0x7fffu + ((u >> 16) & 1u);  // RNE
    return (unsigned short)(u >> 16);
}

__device__ __forceinline__ float bf2f(unsigned short h) {
    return __uint_as_float((unsigned int)h << 16);
}

// frag-major offset for element (k, c) of a K x N weight: KC = K/32
__device__ __forceinline__ size_t fragoff(int k, int c, int KC, int tilebase) {
    return (((size_t)((tilebase + (c >> 4)) * KC + (k >> 5)) * 64) +
            ((k >> 3) & 3) * 16 + (c & 15)) * 8 + (k & 7);
}

// ---------------- fused weight prep (+ az table + bf16 conv weights) -------
// Emits ALL gemm weights in fragment-major bf16 hi/lo:
//   wv : pv_w@vp_w [256][128] | wo : op_w@po_w [128][128]
//   wq : pq_w@qs_w1 [64][128] | wa : qs_w2@{so_w|aw_w} [128][144]
//   wr : rh_w1[0:64] [64][128] (round 15; rh1 B, no fusion)
__global__ void prep_weights(const float* __restrict__ pv_w, const float* __restrict__ pv_b,
                             const float* __restrict__ vp_w, const float* __restrict__ vp_b,
                             const float* __restrict__ op_w, const float* __restrict__ op_b,
                             const float* __restrict__ po_w, const float* __restrict__ po_b,
                             const float* __restrict__ pq_w, const float* __restrict__ pq_b,
                             const float* __restrict__ qs_w1, const float* __restrict__ qs_b1,
                             const float* __restrict__ qs_w2, const float* __restrict__ qs_b2,
                             const float* __restrict__ so_w, const float* __restrict__ so_b,
                             const float* __restrict__ aw_w, const float* __restrict__ aw_b,
                             const float* __restrict__ rh_w1, const float* __restrict__ rh_w2,
                             unsigned short* __restrict__ wvh, unsigned short* __restrict__ wvl,
                             float* __restrict__ pvvp_b,
                             unsigned short* __restrict__ woh, unsigned short* __restrict__ wol,
                             float* __restrict__ oppo_b,
                             unsigned short* __restrict__ wqh, unsigned short* __restrict__ wql,
                             float* __restrict__ pqqs_b,
                             unsigned short* __restrict__ wah, unsigned short* __restrict__ wal,
                             float* __restrict__ qab,
                             unsigned short* __restrict__ wrh, unsigned short* __restrict__ wrl,
                             unsigned short* __restrict__ wtb,
                             float2* __restrict__ azsc) {
    int r = blockIdx.x;
    int d = threadIdx.x; // 0..127
    if (r < 256) {
        float s = 0.f;
        for (int k = 0; k < 128; ++k) s += pv_w[r * 128 + k] * vp_w[k * 128 + d];
        unsigned short h = f2bf(s);
        size_t off = fragoff(r, d, 8, 0);
        wvh[off] = h;
        wvl[off] = f2bf(s - bf2f(h));
    } else if (r == 256) {
        float s = vp_b[d];
        for (int k = 0; k < 128; ++k) s += pv_b[k] * vp_w[k * 128 + d];
        pvvp_b[d] = s;
    } else if (r < 385) {
        int rr = r - 257;
        float s = 0.f;
        for (int k = 0; k < 128; ++k) s += op_w[rr * 128 + k] * po_w[k * 128 + d];
        unsigned short h = f2bf(s);
        size_t off = fragoff(rr, d, 4, 0);
        woh[off] = h;
        wol[off] = f2bf(s - bf2f(h));
    } else if (r == 385) {
        float s = po_b[d];
        for (int k = 0; k < 128; ++k) s += op_b[k] * po_w[k * 128 + d];
        oppo_b[d] = s;
    } else if (r < 450) {
        int rr = r - 386;
        float s = 0.f;
        for (int k = 0; k < 128; ++k) s += pq_w[rr * 128 + k] * qs_w1[k * 128 + d];
        unsigned short h = f2bf(s);
        size_t off = fragoff(rr, d, 2, 0);
        wqh[off] = h;
        wql[off] = f2bf(s - bf2f(h));
    } else if (r == 450) {
        float s = qs_b1[d];
        for (int k = 0; k < 128; ++k) s += pq_b[k] * qs_w1[k * 128 + d];
        pqqs_b[d] = s;
    } else if (r < 459) {
        int w = (r - 451) * 128 + d;
        float az = -PI_F + (float)w * (6.283185307179586f / 1024.0f);
        azsc[w] = make_float2(sinf(az), cosf(az));
    } else if (r < 587) {
        int rr = r - 459;
        if (d < 96) {
            float s = 0.f;
            for (int k = 0; k < 128; ++k) s += qs_w2[rr * 128 + k] * so_w[k * 96 + d];
            unsigned short h = f2bf(s);
            size_t off = fragoff(rr, d, 4, 0);
            wah[off] = h;
            wal[off] = f2bf(s - bf2f(h));
        }
    } else if (r == 587) {
        if (d < 96) {
            float s = so_b[d];
            for (int k = 0; k < 128; ++k) s += qs_b2[k] * so_w[k * 96 + d];
            qab[d] = s;
        }
    } else if (r < 716) {
        int rr = r - 588;
        if (d < 48) {
            float s = 0.f;
            for (int k = 0; k < 128; ++k) s += qs_w2[rr * 128 + k] * aw_w[k * 48 + d];
            unsigned short h = f2bf(s);
            size_t off = fragoff(rr, d, 4, 6);
            wah[off] = h;
            wal[off] = f2bf(s - bf2f(h));
        }
    } else if (r == 716) {
        if (d < 48) {
            float s = aw_b[d];
            for (int k = 0; k < 128; ++k) s += qs_b2[k] * aw_w[k * 48 + d];
            qab[96 + d] = s;
        }
    } else if (r < 1293) {
        // conv weights -> bf16, transposed: wtb[tap][cc4][o][ci]
        int idx = (r - 717) * 128 + d;   // 0 .. 73727
        int ci = idx & 31;
        int o = (idx >> 5) & 63;
        int cc4i = (idx >> 11) & 3;
        int tap = idx >> 13;
        float w = rh_w2[((size_t)tap * 128 + cc4i * 32 + ci) * 64 + o];
        wtb[idx] = f2bf(w);
    } else {
        // rh1 B: rh_w1 rows 0..63, split frag-major, KC=2
        int rr = r - 1293;   // 0..63
        float w = rh_w1[rr * 128 + d];
        unsigned short h = f2bf(w);
        size_t off = fragoff(rr, d, 2, 0);
        wrh[off] = h;
        wrl[off] = f2bf(w - bf2f(h));
    }
}

// ------------- generic fused-split MFMA GEMM (rounds 14-15) ----------------
// C = A @ B + bias (+extras) (+gelu) (+GN stats), A fp32 [M][K] row-major,
// B fragment-major bf16 hi/lo. Block: 256 thr / 4 waves, tile 64m x N.
// EMODE: 1 = ex2[row] (sigf), 2 = ex2[row & 1023] (azsc).
// STATS: GN1 sum/sumsq per col-group j (CPG=16) -> stats1[(b*8+j)*2+..].
template <int KC, int NJ, int EMODE, int GELU, int DUAL, int STATS>
__global__ __launch_bounds__(256) void gemm_mf(
    const float* __restrict__ A,
    const unsigned short* __restrict__ Bh, const unsigned short* __restrict__ Bl,
    const float* __restrict__ bias,
    float* __restrict__ C1, float* __restrict__ C2,
    const float2* __restrict__ ex2, const float* __restrict__ exw,
    float* __restrict__ stats1) {
    constexpr int K = KC * 32;
    __shared__ __align__(16) float T0[32 * 70];
    __shared__ __align__(16) float T1[32 * 70];
    __shared__ float sred[8][2];
    const int tid = threadIdx.x;
    const int wid = tid >> 6;
    const int lane = tid & 63;
    const int mm = lane & 15;
    const int quad = lane >> 4;
    const int m0 = blockIdx.x * 64;
    if (STATS && tid < 16) sred[tid >> 1][tid & 1] = 0.f;

    int srow[2], scol[2];
    const float* sp[2];
#pragma unroll
    for (int i = 0; i < 2; ++i) {
        int f = tid + i * 256;
        srow[i] = f >> 3;
        scol[i] = (f & 7) * 4;
        sp[i] = A + (size_t)(m0 + srow[i]) * K + scol[i];
    }

    f32x4 acc[NJ];
#pragma unroll
    for (int j = 0; j < NJ; ++j) acc[j] = (f32x4){0.f, 0.f, 0.f, 0.f};

    union UV { uint4 u; bf16x8 v; };
    float4 st[2];

#define LOADG(K0)                                                 \
    {                                                             \
        _Pragma("unroll")                                         \
        for (int i_ = 0; i_ < 2; ++i_)                            \
            st[i_] = *(const float4*)(sp[i_] + (K0));             \
    }
#define WRITELDS(TB)                                              \
    {                                                             \
        _Pragma("unroll")                                         \
        for (int i_ = 0; i_ < 2; ++i_) {                          \
            _Pragma("unroll")                                     \
            for (int c_ = 0; c_ < 4; ++c_)                        \
                (TB)[(scol[i_] + c_) * 70 + srow[i_]] = st[i_][c_]; \
        }                                                         \
    }
#define BARRIER()                                                 \
    asm volatile("s_waitcnt lgkmcnt(0)" ::: "memory");            \
    __builtin_amdgcn_sched_barrier(0);                            \
    __builtin_amdgcn_s_barrier();                                 \
    __builtin_amdgcn_sched_barrier(0);

    float* Tc = T0;
    float* Tn = T1;
    LOADG(0);
    WRITELDS(Tc);
    if (KC > 1) LOADG(32);
    BARRIER();

#pragma unroll
    for (int t = 0; t < KC; ++t) {
        bf16x8 ah, al;
        {
            const int nc = wid * 16 + mm;
            float f8[8];
#pragma unroll
            for (int jj = 0; jj < 8; ++jj)
                f8[jj] = Tc[(quad * 8 + jj) * 70 + nc];
            unsigned hh[4], ll[4];
#pragma unroll
            for (int q = 0; q < 4; ++q) {
                unsigned u0 = __float_as_uint(f8[2 * q]);
                unsigned u1 = __float_as_uint(f8[2 * q + 1]);
                hh[q] = __builtin_amdgcn_perm(u1, u0, 0x07060302);  // trunc pair
                float l0 = f8[2 * q] - __uint_as_float(u0 & 0xffff0000u);
                float l1 = f8[2 * q + 1] - __uint_as_float(u1 & 0xffff0000u);
                asm("v_cvt_pk_bf16_f32 %0, %1, %2" : "=v"(ll[q]) : "v"(l0), "v"(l1));
            }
            UV th, tl;
            th.u = make_uint4(hh[0], hh[1], hh[2], hh[3]);
            tl.u = make_uint4(ll[0], ll[1], ll[2], ll[3]);
            ah = th.v;
            al = tl.v;
        }
        if (t < KC - 1) WRITELDS(Tn);
        if (t < KC - 2) LOADG((t + 2) * 32);
        bf16x8 bh[NJ], bl[NJ];
#pragma unroll
        for (int j = 0; j < NJ; ++j) {
            size_t o = ((size_t)(j * KC + t) * 64 + lane) * 8;
            bh[j] = *(const bf16x8*)(Bh + o);
            bl[j] = *(const bf16x8*)(Bl + o);
        }
#pragma unroll
        for (int j = 0; j < NJ; ++j) {
            acc[j] = __builtin_amdgcn_mfma_f32_16x16x32_bf16(ah, bh[j], acc[j], 0, 0, 0);
            acc[j] = __builtin_amdgcn_mfma_f32_16x16x32_bf16(ah, bl[j], acc[j], 0, 0, 0);
            acc[j] = __builtin_amdgcn_mfma_f32_16x16x32_bf16(al, bh[j], acc[j], 0, 0, 0);
        }
        if (t < KC - 1) {
            BARRIER();
            float* tmp = Tc; Tc = Tn; Tn = tmp;
        }
    }
#undef LOADG
#undef WRITELDS
    // epilogue: D row (m) = quad*4 + r, col = j*16 + mm
    float bvj[NJ];
#pragma unroll
    for (int j = 0; j < NJ; ++j) bvj[j] = bias[j * 16 + mm];
    float2 ev[4];
    float e0w[NJ], e1w[NJ];
    if (EMODE) {
#pragma unroll
        for (int r = 0; r < 4; ++r) {
            int row = m0 + wid * 16 + quad * 4 + r;
            ev[r] = (EMODE == 2) ? ex2[row & 1023] : ex2[row];
        }
#pragma unroll
        for (int j = 0; j < NJ; ++j) {
            e0w[j] = exw[j * 16 + mm];
            e1w[j] = exw[128 + j * 16 + mm];
        }
    }
#pragma unroll
    for (int j = 0; j < NJ; ++j) {
        float* Cp;
        int col, ldc;
        if (DUAL && j >= 6) {
            Cp = C2; col = (j - 6) * 16 + mm; ldc = 48;
        } else {
            Cp = C1; col = j * 16 + mm; ldc = DUAL ? 96 : NJ * 16;
        }
        float tsj = 0.f, t2j = 0.f;
#pragma unroll
        for (int r = 0; r < 4; ++r) {
            int row = m0 + wid * 16 + quad * 4 + r;
            float v = acc[j][r] + bvj[j];
            if (EMODE) v += ev[r].x * e0w[j] + ev[r].y * e1w[j];
            if (GELU) v = gelu_f(v);
            if (STATS) { tsj += v; t2j += v * v; }
            Cp[(size_t)row * ldc + col] = v;
        }
        if (STATS) {
#pragma unroll
            for (int s = 1; s < 64; s <<= 1) {
                tsj += __shfl_xor(tsj, s);
                t2j += __shfl_xor(t2j, s);
            }
            if (lane == 0) {
                atomicAdd(&sred[j][0], tsj);
                atomicAdd(&sred[j][1], t2j);
            }
        }
    }
    if (STATS) {
        BARRIER();
        if (tid < 16) {
            int b = m0 >> 15;
            atomicAdd(&stats1[(b * 8 + (tid >> 1)) * 2 + (tid & 1)], sred[tid >> 1][tid & 1]);
        }
    }
#undef BARRIER
}

// ------------- value GEMM: barrier-free wave-private transpose (round 15) --
// V[b][n][d] = sum_k bev[b][k][n] * W[k][d] + bias[d], K=256.
// Block 128n / 4 INDEPENDENT waves; wave owns 32n x 128d with its own
// double-buffered LDS transpose tile (producer==consumer wave -> zero
// barriers; same-wave ds ordering via compiler lgkmcnt). Pitch 34:
// scatter writes and column b32 reads both 2-way (free). B frag-major
// from L2 (8 tiles/wave). Grid 313x2; last block clamps reads, guards
// stores. Per wave per chunk: 2 A-frag splits + 16 B loads + 48 MFMA.
__global__ __launch_bounds__(256) void value_gemm_fused(
    const float* __restrict__ bev,
    const unsigned short* __restrict__ Wh, const unsigned short* __restrict__ Wl,
    const float* __restrict__ bf, float* __restrict__ V) {
    __shared__ __align__(16) float T[4][2][32 * 34];   // 34.8 KB
    const int tid = threadIdx.x;
    const int wid = tid >> 6;
    const int lane = tid & 63;
    const int m = lane & 15;
    const int quad = lane >> 4;
    const int n0 = blockIdx.x * 128 + wid * 32;
    const int b = blockIdx.y;
    const float* src = bev + (size_t)b * 256 * 40000;

    // staging: 4 float4/lane/chunk: f = lane + i*64; k = f>>3, n-col (f&7)*4
    int srow[4], scol[4];
    const float* sp[4];
#pragma unroll
    for (int i = 0; i < 4; ++i) {
        int f = lane + i * 64;
        srow[i] = f >> 3;
        scol[i] = (f & 7) * 4;
        int nl = n0 + scol[i];
        if (nl > 39996) nl = 39996;   // edge clamp (stores guarded)
        sp[i] = src + nl;
    }

    f32x4 acc[2][8];
#pragma unroll
    for (int i = 0; i < 2; ++i)
#pragma unroll
        for (int j = 0; j < 8; ++j) acc[i][j] = (f32x4){0.f, 0.f, 0.f, 0.f};

    size_t bb[8];
#pragma unroll
    for (int j = 0; j < 8; ++j) bb[j] = (size_t)j * 4096 + lane * 8;

    union UV { uint4 u; bf16x8 v; };
    float4 st[4];

#define LOADGV(K0)                                                          \
    {                                                                       \
        _Pragma("unroll")                                                   \
        for (int i_ = 0; i_ < 4; ++i_)                                      \
            st[i_] = *(const float4*)(sp[i_] + (size_t)((K0) + srow[i_]) * 40000); \
    }
#define WRITELDSV(TB)                                                       \
    {                                                                       \
        _Pragma("unroll")                                                   \
        for (int i_ = 0; i_ < 4; ++i_) {                                    \
            float* d_ = (TB) + srow[i_] * 34 + scol[i_];                    \
            *(float2*)(d_ + 0) = make_float2(st[i_].x, st[i_].y);           \
            *(float2*)(d_ + 2) = make_float2(st[i_].z, st[i_].w);           \
        }                                                                   \
    }

    float* Tb0 = &T[wid][0][0];
    float* Tb1 = &T[wid][1][0];
    LOADGV(0);
    for (int t = 0; t < 8; ++t) {
        float* Tc = (t & 1) ? Tb1 : Tb0;
        WRITELDSV(Tc);
        if (t < 7) LOADGV((t + 1) * 32);
        // A fragments: column reads (same wave wrote -> lgkmcnt auto)
        bf16x8 ah[2], al[2];
#pragma unroll
        for (int i = 0; i < 2; ++i) {
            const int nc = i * 16 + m;
            float f8[8];
#pragma unroll
            for (int jj = 0; jj < 8; ++jj)
                f8[jj] = Tc[(quad * 8 + jj) * 34 + nc];
            unsigned hh[4], ll[4];
#pragma unroll
            for (int q = 0; q < 4; ++q) {
                unsigned u0 = __float_as_uint(f8[2 * q]);
                unsigned u1 = __float_as_uint(f8[2 * q + 1]);
                hh[q] = __builtin_amdgcn_perm(u1, u0, 0x07060302);  // trunc pair
                float l0 = f8[2 * q] - __uint_as_float(u0 & 0xffff0000u);
                float l1 = f8[2 * q + 1] - __uint_as_float(u1 & 0xffff0000u);
                asm("v_cvt_pk_bf16_f32 %0, %1, %2" : "=v"(ll[q]) : "v"(l0), "v"(l1));
            }
            UV th, tl;
            th.u = make_uint4(hh[0], hh[1], hh[2], hh[3]);
            tl.u = make_uint4(ll[0], ll[1], ll[2], ll[3]);
            ah[i] = th.v;
            al[i] = tl.v;
        }
        // B fragments (fragment-major, L2-resident)
        bf16x8 bh[8], bl[8];
#pragma unroll
        for (int j = 0; j < 8; ++j) {
            bh[j] = *(const bf16x8*)(Wh + bb[j] + t * 512);
            bl[j] = *(const bf16x8*)(Wl + bb[j] + t * 512);
        }
#pragma unroll
        for (int i = 0; i < 2; ++i)
#pragma unroll
            for (int j = 0; j < 8; ++j) {
                acc[i][j] = __builtin_amdgcn_mfma_f32_16x16x32_bf16(ah[i], bh[j], acc[i][j], 0, 0, 0);
                acc[i][j] = __builtin_amdgcn_mfma_f32_16x16x32_bf16(ah[i], bl[j], acc[i][j], 0, 0, 0);
                acc[i][j] = __builtin_amdgcn_mfma_f32_16x16x32_bf16(al[i], bh[j], acc[i][j], 0, 0, 0);
            }
    }
#undef LOADGV
#undef WRITELDSV
    // epilogue: row n = n0 + i*16 + quad*4 + r, col d = j*16 + m
    float bv[8];
#pragma unroll
    for (int j = 0; j < 8; ++j) bv[j] = bf[j * 16 + m];
#pragma unroll
    for (int i = 0; i < 2; ++i) {
        int nbase = n0 + i * 16 + quad * 4;
#pragma unroll
        for (int r = 0; r < 4; ++r) {
            int n = nbase + r;
            if (n < 40000) {
                float* vp = V + ((size_t)b * 40000 + n) * 128 + m;
#pragma unroll
                for (int j = 0; j < 8; ++j) vp[j * 16] = acc[i][j][r] + bv[j];
            }
        }
    }
}

// ---------------- GN1 apply + GELU -> bf16 ----------------
__global__ __launch_bounds__(256) void gn1_bf16(
    const float* __restrict__ X, const float* __restrict__ stats,
    const float* __restrict__ g1, const float* __restrict__ be1,
    unsigned short* __restrict__ Ob) {
    size_t i4 = (size_t)blockIdx.x * 256 + threadIdx.x;
    size_t base = i4 * 4;
    int c = (int)(base & 127);
    int mrow = (int)(base >> 7);
    int b = mrow >> 15;
    int g = c >> 4;
    float mean = stats[(b * 8 + g) * 2 + 0] * (1.0f / 524288.0f);
    float var = stats[(b * 8 + g) * 2 + 1] * (1.0f / 524288.0f) - mean * mean;
    float rs = 1.0f / sqrtf(var + 1e-5f);
    float4 x = *(const float4*)(X + base);
    float4 gm = *(const float4*)(g1 + c);
    float4 bt = *(const float4*)(be1 + c);
    ushort4 o;
    o.x = f2bf(gelu_f((x.x - mean) * rs * gm.x + bt.x));
    o.y = f2bf(gelu_f((x.y - mean) * rs * gm.y + bt.y));
    o.z = f2bf(gelu_f((x.z - mean) * rs * gm.z + bt.z));
    o.w = f2bf(gelu_f((x.w - mean) * rs * gm.w + bt.w));
    *(ushort4*)(Ob + base) = o;
}

// ---------------- 3x3 circular conv via bf16 MFMA ----------------
__global__ __launch_bounds__(256, 4) void conv3x3_mfma(
    const unsigned short* __restrict__ H1b,  // [2][32][1024][128] bf16
    const unsigned short* __restrict__ Wtb,  // [9][4][64][32] bf16
    float* __restrict__ Y,                   // [2][32][1024][64]
    float* __restrict__ stats2) {
    __shared__ short As_s[66 * 40];      // [xx][ci_chunk] 5.2 KB
    __shared__ short Ws_s[3 * 64 * 40];  // [dx][o][ci_chunk] 15.4 KB
    __shared__ float sred[8][2];
    const int tid = threadIdx.x;
    const int wid = tid >> 6;
    const int lane = tid & 63;
    const int m = lane & 15;
    const int quad = lane >> 4;
    const int x0 = blockIdx.x * 64;
    const int y = blockIdx.y;
    const int b = blockIdx.z;
    if (tid < 16) sred[tid >> 1][tid & 1] = 0.f;
    f32x4 acc[4];
#pragma unroll
    for (int oq = 0; oq < 4; ++oq) acc[oq] = (f32x4){0.f, 0.f, 0.f, 0.f};

    const unsigned short* Hb = H1b + (size_t)b * 32 * 1024 * 128;
    for (int ry = 0; ry < 3; ++ry) {
        const int gy = (y + ry + 31) & 31;
        const unsigned short* Hrow = Hb + (size_t)gy * 1024 * 128;
        for (int cc4 = 0; cc4 < 4; ++cc4) {
            __syncthreads();
            // A: 66 xx-rows x 4 octets of 8 bf16 = 264 16B chunks
            for (int f = tid; f < 264; f += 256) {
                int xx = f >> 2, cq = f & 3;
                int gx = (x0 + xx + 1023) & 1023;
                uint4 v = *(const uint4*)(Hrow + (size_t)gx * 128 + cc4 * 32 + cq * 8);
                *(uint4*)&As_s[xx * 40 + cq * 8] = v;
            }
            // W: 3 dx x 64 o x 4 octets = 768 16B chunks
            for (int f = tid; f < 768; f += 256) {
                int cq = f & 3, o = (f >> 2) & 63, dx = f >> 8;
                int tap = ry * 3 + dx;
                uint4 v = *(const uint4*)(Wtb + ((size_t)(tap * 4 + cc4) * 64 + o) * 32 + cq * 8);
                *(uint4*)&Ws_s[(dx * 64 + o) * 40 + cq * 8] = v;
            }
            __syncthreads();
            const int arow = wid * 16 + m;
#pragma unroll
            for (int dx = 0; dx < 3; ++dx) {
                bf16x8 a = *(const bf16x8*)&As_s[(arow + dx) * 40 + quad * 8];
#pragma unroll
                for (int oq = 0; oq < 4; ++oq) {
                    bf16x8 bfr = *(const bf16x8*)&Ws_s[(dx * 64 + oq * 16 + m) * 40 + quad * 8];
                    acc[oq] = __builtin_amdgcn_mfma_f32_16x16x32_bf16(a, bfr, acc[oq], 0, 0, 0);
                }
            }
        }
    }
    // GN2 stats: lane's frag oq covers o = oq*16 + m -> group oq*2 + (m>>3)
    float sv[4], qv[4];
#pragma unroll
    for (int oq = 0; oq < 4; ++oq) {
        sv[oq] = acc[oq].x + acc[oq].y + acc[oq].z + acc[oq].w;
        qv[oq] = acc[oq].x * acc[oq].x + acc[oq].y * acc[oq].y +
                 acc[oq].z * acc[oq].z + acc[oq].w * acc[oq].w;
    }
    const int masks[5] = {1, 2, 4, 16, 32};  // reduce over all but bit3
#pragma unroll
    for (int mi = 0; mi < 5; ++mi) {
#pragma unroll
        for (int oq = 0; oq < 4; ++oq) {
            sv[oq] += __shfl_xor(sv[oq], masks[mi]);
            qv[oq] += __shfl_xor(qv[oq], masks[mi]);
        }
    }
    if ((lane & 55) == 0) {  // lanes 0, 8
        int gb = (lane >> 3) & 1;
#pragma unroll
        for (int oq = 0; oq < 4; ++oq) {
            atomicAdd(&sred[oq * 2 + gb][0], sv[oq]);
            atomicAdd(&sred[oq * 2 + gb][1], qv[oq]);
        }
    }
    // store: D row = quad*4 + r (px), col = o
    const int pxb = x0 + wid * 16 + quad * 4;
    float* Yb = Y + ((size_t)(b * 32 + y) * 1024 + pxb) * 64;
#pragma unroll
    for (int oq = 0; oq < 4; ++oq) {
        const float av[4] = {acc[oq].x, acc[oq].y, acc[oq].z, acc[oq].w};
#pragma unroll
        for (int r = 0; r < 4; ++r) Yb[(size_t)r * 64 + oq * 16 + m] = av[r];
    }
    __syncthreads();
    if (tid < 16)
        atomicAdd(&stats2[(b * 8 + (tid >> 1)) * 2 + (tid & 1)], sred[tid >> 1][tid & 1]);
}

// ---------------- fused GN2-apply + GELU + rh3 head ----------------
__global__ __launch_bounds__(256) void rh3_kernel(
    const float* __restrict__ H2, const float* __restrict__ stats,
    const float* __restrict__ gamma, const float* __restrict__ beta, float inv_cnt,
    const float* __restrict__ w3, const float* __restrict__ b3,
    const float2* __restrict__ azsc,
    float2* __restrict__ refxy, float2* __restrict__ sigf) {
    const int tid = threadIdx.x;
    const int lane = tid & 15;
    const int m = blockIdx.x * 16 + (tid >> 4);
    const int b = m >> 15;
    const int c = lane * 4;
    const int g = c >> 3;
    float mean = stats[(b * 8 + g) * 2 + 0] * inv_cnt;
    float var = stats[(b * 8 + g) * 2 + 1] * inv_cnt - mean * mean;
    float rs = 1.0f / sqrtf(var + 1e-5f);
    float4 v = *(const float4*)(H2 + (size_t)m * 64 + c);
    float hv[4];
    hv[0] = gelu_f((v.x - mean) * rs * gamma[c + 0] + beta[c + 0]);
    hv[1] = gelu_f((v.y - mean) * rs * gamma[c + 1] + beta[c + 1]);
    hv[2] = gelu_f((v.z - mean) * rs * gamma[c + 2] + beta[c + 2]);
    hv[3] = gelu_f((v.w - mean) * rs * gamma[c + 3] + beta[c + 3]);
    float d0 = 0.f, d1 = 0.f;
#pragma unroll
    for (int k = 0; k < 4; ++k) {
        d0 += hv[k] * w3[(c + k) * 2 + 0];
        d1 += hv[k] * w3[(c + k) * 2 + 1];
    }
#pragma unroll
    for (int s = 1; s < 16; s <<= 1) {
        d0 += __shfl_xor(d0, s, 16);
        d1 += __shfl_xor(d1, s, 16);
    }
    if (lane == 0) {
        float mu = fminf(fmaxf(d0 + b3[0], 0.f), 55.f);
        float ls = fminf(fmaxf(d1 + b3[1], -5.f), 3.f);
        float sg = expf(ls);
        float2 sc = azsc[m & 1023];
        float rx = fminf(fmaxf(mu * sc.y * 0.01f + 0.5f, 0.f), 1.f);
        float ry = fminf(fmaxf(mu * sc.x * 0.01f + 0.5f, 0.f), 1.f);
        refxy[m] = make_float2(rx, ry);
        sigf[m] = make_float2(ls, 1.f / (sg + 1e-6f));
    }
}

// ---------------- MSDA bilinear sampling ----------------
__global__ __launch_bounds__(256) void msda_kernel(
    const float* __restrict__ V, const float2* __restrict__ refxy,
    const float* __restrict__ offs, const float* __restrict__ aw,
    float* __restrict__ out) {
    const int tid = threadIdx.x;
    const int l4 = tid & 3;         // dh quarter
    const int grp = tid >> 2;       // 0..63: 8 m x 8 heads
    const int m = blockIdx.x * 8 + (grp >> 3);
    const int head = grp & 7;
    const int b = m >> 15;
    float2 r = refxy[m];
    const float* lg = aw + (size_t)m * 48 + head * 6;
    float l[6];
#pragma unroll
    for (int p = 0; p < 6; ++p) l[p] = lg[p];
    float mx = l[0];
#pragma unroll
    for (int p = 1; p < 6; ++p) mx = fmaxf(mx, l[p]);
    float s = 0.f;
#pragma unroll
    for (int p = 0; p < 6; ++p) { l[p] = expf(l[p] - mx); s += l[p]; }
    float inv = 1.f / s;
#pragma unroll
    for (int p = 0; p < 6; ++p) l[p] *= inv;   // fold softmax into weights
    const float* of = offs + (size_t)m * 96 + head * 12;
    const float* Vb = V + (size_t)b * 40000 * 128 + head * 16 + l4 * 4;
    const float bx = r.x * 200.f - 0.5f;
    const float by = r.y * 200.f - 0.5f;
    f32x4 acc = (f32x4){0.f, 0.f, 0.f, 0.f};
#pragma unroll
    for (int p = 0; p < 6; ++p) {
        float px = bx + of[p * 2 + 0];
        float py = by + of[p * 2 + 1];
        float fx = floorf(px), fy = floorf(py);
        int x0 = (int)fx, y0 = (int)fy;
        float wx = px - fx, wy = py - fy;
        // clamped addresses (always in range); invalid corners get weight 0
        int xc0 = min(max(x0, 0), 199), xc1 = min(max(x0 + 1, 0), 199);
        int yc0 = min(max(y0, 0), 199), yc1 = min(max(y0 + 1, 0), 199);
        bool vx0 = ((unsigned)x0 < 200u), vx1 = ((unsigned)(x0 + 1) < 200u);
        bool vy0 = ((unsigned)y0 < 200u), vy1 = ((unsigned)(y0 + 1) < 200u);
        const f32x4 v00 = *(const f32x4*)(Vb + ((size_t)(yc0 * 200 + xc0)) * 128);
        const f32x4 v10 = *(const f32x4*)(Vb + ((size_t)(yc0 * 200 + xc1)) * 128);
        const f32x4 v01 = *(const f32x4*)(Vb + ((size_t)(yc1 * 200 + xc0)) * 128);
        const f32x4 v11 = *(const f32x4*)(Vb + ((size_t)(yc1 * 200 + xc1)) * 128);
        float w = l[p];
        float w00 = (vx0 && vy0) ? w * (1.f - wx) * (1.f - wy) : 0.f;
        float w10 = (vx1 && vy0) ? w * wx * (1.f - wy) : 0.f;
        float w01 = (vx0 && vy1) ? w * (1.f - wx) * wy : 0.f;
        float w11 = (vx1 && vy1) ? w * wx * wy : 0.f;
        acc += v00 * w00;
        acc += v10 * w10;
        acc += v01 * w01;
        acc += v11 * w11;
    }
    *(f32x4*)(out + (size_t)m * 128 + head * 16 + l4 * 4) = acc;
}

// ---------------- launch ----------------
extern "C" void kernel_launch(void* const* d_in, const int* in_sizes, int n_in,
                              void* d_out, int out_size, void* d_ws, size_t ws_size,
                              hipStream_t stream) {
    const float* x_rv = (const float*)d_in[0];
    const float* bev = (const float*)d_in[1];
    const float* pq_w = (const float*)d_in[2];
    const float* pq_b = (const float*)d_in[3];
    const float* pv_w = (const float*)d_in[4];
    const float* pv_b = (const float*)d_in[5];
    const float* po_w = (const float*)d_in[6];
    const float* po_b = (const float*)d_in[7];
    const float* qs_w1 = (const float*)d_in[8];
    const float* qs_b1 = (const float*)d_in[9];
    const float* qs_w2 = (const float*)d_in[10];
    const float* qs_b2 = (const float*)d_in[11];
    const float* rh_w1 = (const float*)d_in[12];
    const float* rh_b1 = (const float*)d_in[13];
    const float* rh_g1 = (const float*)d_in[14];
    const float* rh_be1 = (const float*)d_in[15];
    const float* rh_w2 = (const float*)d_in[16];
    const float* rh_g2 = (const float*)d_in[17];
    const float* rh_be2 = (const float*)d_in[18];
    const float* rh_w3 = (const float*)d_in[19];
    const float* rh_b3 = (const float*)d_in[20];
    const float* so_w = (const float*)d_in[21];
    const float* so_b = (const float*)d_in[22];
    const float* aw_w = (const float*)d_in[23];
    const float* aw_b = (const float*)d_in[24];
    const float* vp_w = (const float*)d_in[25];
    const float* vp_b = (const float*)d_in[26];
    const float* op_w = (const float*)d_in[27];
    const float* op_b = (const float*)d_in[28];

    const int M = 65536;

    float* ws = (float*)d_ws;
    float* azsc = ws;    ws += 2048;
    unsigned short* wvh = (unsigned short*)ws; ws += 16384;  // 256x128 frag-major hi
    unsigned short* wvl = (unsigned short*)ws; ws += 16384;
    float* pvvp_b = ws;  ws += 128;
    unsigned short* woh = (unsigned short*)ws; ws += 8192;   // 128x128 frag-major
    unsigned short* wol = (unsigned short*)ws; ws += 8192;
    float* oppo_b = ws;  ws += 128;
    unsigned short* wqh = (unsigned short*)ws; ws += 4096;   // 64x128 frag-major
    unsigned short* wql = (unsigned short*)ws; ws += 4096;
    float* pqqs_b = ws;  ws += 128;
    unsigned short* wah = (unsigned short*)ws; ws += 9216;   // 128x144 frag-major
    unsigned short* wal = (unsigned short*)ws; ws += 9216;
    float* qab = ws;     ws += 144;
    unsigned short* wrh = (unsigned short*)ws; ws += 4096;   // 64x128 frag-major (rh1)
    unsigned short* wrl = (unsigned short*)ws; ws += 4096;
    float* stats = ws;   ws += 64;   // [0:32) GN1, [32:64) GN2
    unsigned short* wtb = (unsigned short*)ws;  ws += 36864;   // 73728 bf16
    unsigned short* h1b = (unsigned short*)ws;  ws += (size_t)M * 64;  // M*128 bf16
    float* Vv = ws;      ws += (size_t)80000 * 128;
    float* h1 = ws;      ws += (size_t)M * 128;
    float* h2 = ws;      ws += (size_t)M * 64;
    float* q1 = ws;      ws += (size_t)M * 128;
    float* refxy = ws;   ws += (size_t)M * 2;
    float* sigf = ws;    ws += (size_t)M * 2;
    size_t need_bytes = (size_t)(ws - (float*)d_ws) * sizeof(float);
    if (ws_size < need_bytes) return;
    float* offs = h1;   // h1 (raw rh1) dead after gn1_bf16
    float* attw = h2;   // h2 dead after rh3
    float* mo = q1;     // q1 dead after offs/attw GEMM

    float2* azsc2 = (float2*)azsc;
    float2* refxy2 = (float2*)refxy;
    float2* sigf2 = (float2*)sigf;

    prep_weights<<<1357, 128, 0, stream>>>(
        pv_w, pv_b, vp_w, vp_b, op_w, op_b, po_w, po_b, pq_w, pq_b,
        qs_w1, qs_b1, qs_w2, qs_b2, so_w, so_b, aw_w, aw_b, rh_w1, rh_w2,
        wvh, wvl, pvvp_b, woh, wol, oppo_b, wqh, wql, pqqs_b,
        wah, wal, qab, wrh, wrl, wtb, azsc2);
    hipMemsetAsync(stats, 0, 64 * sizeof(float), stream);

    // value = bev^T @ (pv_w@vp_w) + fused bias -- barrier-free split MFMA
    value_gemm_fused<<<dim3(313, 2), 256, 0, stream>>>(bev, wvh, wvl, pvvp_b, Vv);

    // h1 = raw rh1 (x_rv @ rh_w1 + az extras + bias); GN1 stats -- split MFMA
    gemm_mf<2, 8, 2, 0, 0, 1><<<M / 64, 256, 0, stream>>>(
        x_rv, wrh, wrl, rh_b1, h1, nullptr, azsc2, rh_w1 + 64 * 128, stats);

    // GN1 apply + gelu -> bf16
    gn1_bf16<<<8192, 256, 0, stream>>>(h1, stats, rh_g1, rh_be1, h1b);

    // conv via bf16 MFMA; GN2 stats in epilogue
    conv3x3_mfma<<<dim3(16, 32, 2), 256, 0, stream>>>(h1b, wtb, h2, stats + 32);

    // fused GN2-apply + gelu + rh3 head
    rh3_kernel<<<4096, 256, 0, stream>>>(h2, stats + 32, rh_g2, rh_be2, 1.0f / 262144.0f,
                                         rh_w3, rh_b3, azsc2, refxy2, sigf2);

    // q1 = gelu(x_rv @ (pq_w@qs_w1a) + sigf extras + bias) -- split MFMA
    gemm_mf<2, 8, 1, 1, 0, 0><<<M / 64, 256, 0, stream>>>(
        x_rv, wqh, wql, pqqs_b, q1, nullptr, sigf2, qs_w1 + 128 * 128, nullptr);

    // offs (96) + attw logits (48) = q1 @ concat-B, dual output -- split MFMA
    gemm_mf<4, 9, 0, 0, 1, 0><<<M / 64, 256, 0, stream>>>(
        q1, wah, wal, qab, offs, attw, nullptr, nullptr, nullptr);

    // MSDA sampling (into q1)
    msda_kernel<<<M / 8, 256, 0, stream>>>(Vv, refxy2, offs, attw, mo);

    // y = mo @ (op_w@po_w) + fused bias -> d_out -- split MFMA
    gemm_mf<4, 8, 0, 0, 0, 0><<<M / 64, 256, 0, stream>>>(
        mo, woh, wol, oppo_b, (float*)d_out, nullptr, nullptr, nullptr, nullptr);
}